// Round 2
// baseline (11864.726 us; speedup 1.0000x reference)
//
#include <hip/hip_runtime.h>
#include <hip/hip_bf16.h>

#define BB 8
#define NN 1024
#define KK 20
#define EPSB 1e-5f

typedef __hip_bfloat16 bf16;

__device__ __forceinline__ float b2f(bf16 v){ return __bfloat162float(v); }
__device__ __forceinline__ float lrelu(float t){ return t >= 0.f ? t : 0.2f*t; }
// dtype-flag-aware input load: flag=1 -> bf16, flag=0 -> fp32
__device__ __forceinline__ float ldin(const void* p, int i, int bf){
  return bf ? __bfloat162float(((const bf16*)p)[i]) : ((const float*)p)[i];
}
__device__ __forceinline__ unsigned f2u_ord(float f){
  unsigned u = __float_as_uint(f);
  return (u & 0x80000000u) ? ~u : (u | 0x80000000u);
}
__device__ __forceinline__ float u2f_ord(unsigned u){
  return (u & 0x80000000u) ? __uint_as_float(u & 0x7fffffffu) : __uint_as_float(~u);
}

// ---------------- dtype detection: fp32 N(0,1) words have exponent ~[90,130];
// packed-bf16 words mostly have exponent >= 236. Count huge-exponent words.
__global__ void detect_kernel(const unsigned* __restrict__ xw, int* __restrict__ flag){
  int t = threadIdx.x;               // 0..63, one wave
  unsigned w = xw[t];
  unsigned e = (w >> 23) & 0xFFu;
  int huge = (e >= 0xD0u) ? 1 : 0;   // |fp32| >= ~2^80: impossible for normal data
  unsigned long long m = __ballot(huge);
  if (t == 0) *flag = (__popcll(m) >= 32) ? 1 : 0;
}

// ---------------- zero init (stats & pool accumulators; ws is poisoned 0xAA each call)
__global__ void zero_kernel(unsigned* __restrict__ p, int n){
  int i = blockIdx.x*256 + threadIdx.x;
  if (i < n) p[i] = 0u;
}

// ---------------- conv0: three 2->2 gated branches, single block (tiny)
__global__ __launch_bounds__(256) void conv0_kernel(
    const void* __restrict__ x,
    const void* __restrict__ w00, const void* __restrict__ g00, const void* __restrict__ b00,
    const void* __restrict__ w01, const void* __restrict__ g01, const void* __restrict__ b01,
    float* __restrict__ xc0, const int* __restrict__ flagp){
  __shared__ float sacc[12][256];
  __shared__ float sA[6], sC[6];
  const int bf = *flagp;
  int tid = threadIdx.x;
  float part[12];
#pragma unroll
  for (int j=0;j<12;j++) part[j]=0.f;
  float wz[4], wy[4];
#pragma unroll
  for (int j=0;j<4;j++){ wz[j]=ldin(w00,j,bf); wy[j]=ldin(w01,j,bf); }
  for (int i = tid; i < BB*NN; i += 256){
    int b = i / NN, n = i % NN;
    float x0 = ldin(x,(b*3+0)*NN + n,bf);
    float x1 = ldin(x,(b*3+1)*NN + n,bf);
    float x2 = ldin(x,(b*3+2)*NN + n,bf);
    float z0 = wz[0]*x0 + wz[1]*x1, z1 = wz[2]*x0 + wz[3]*x1; // bz: ch (0,1), w00
    float y0 = wy[0]*x0 + wy[1]*x2, y1 = wy[2]*x0 + wy[3]*x2; // by: ch (0,2), w01
    float u0 = wy[0]*x1 + wy[1]*x2, u1 = wy[2]*x1 + wy[3]*x2; // bx: ch (1,2), w01
    part[0]+=z0; part[1]+=z0*z0; part[2]+=z1; part[3]+=z1*z1;
    part[4]+=y0; part[5]+=y0*y0; part[6]+=y1; part[7]+=y1*y1;
    part[8]+=u0; part[9]+=u0*u0; part[10]+=u1; part[11]+=u1*u1;
  }
#pragma unroll
  for (int j=0;j<12;j++) sacc[j][tid]=part[j];
  __syncthreads();
  for (int s=128;s;s>>=1){
    if (tid<s){
#pragma unroll
      for (int j=0;j<12;j++) sacc[j][tid]+=sacc[j][tid+s];
    }
    __syncthreads();
  }
  if (tid < 6){
    float m = sacc[2*tid][0] * (1.f/(BB*NN));
    float v = sacc[2*tid+1][0] * (1.f/(BB*NN)) - m*m;
    float g, bv;
    if (tid<2){ g=ldin(g00,tid,bf); bv=ldin(b00,tid,bf); }
    else if (tid<4){ g=ldin(g01,tid-2,bf); bv=ldin(b01,tid-2,bf); }
    else { g=ldin(g01,tid-4,bf); bv=ldin(b01,tid-4,bf); }
    float a = g * rsqrtf(fmaxf(v,0.f) + EPSB);
    sA[tid]=a; sC[tid]=bv - m*a;
  }
  __syncthreads();
  for (int i = tid; i < BB*NN; i += 256){
    int b = i / NN, n = i % NN;
    float x0 = ldin(x,(b*3+0)*NN + n,bf);
    float x1 = ldin(x,(b*3+1)*NN + n,bf);
    float x2 = ldin(x,(b*3+2)*NN + n,bf);
    float z0 = wz[0]*x0 + wz[1]*x1, z1 = wz[2]*x0 + wz[3]*x1;
    float y0 = wy[0]*x0 + wy[1]*x2, y1 = wy[2]*x0 + wy[3]*x2;
    float u0 = wy[0]*x1 + wy[1]*x2, u1 = wy[2]*x1 + wy[3]*x2;
    float* row = xc0 + (size_t)i*16;
    row[0]=x0; row[1]=x1; row[2]=x2;
    // concat order: [x, x_2d_x, x_2d_y, x_2d_z]
    row[3]=lrelu(sA[4]*u0+sC[4])*x0; row[4]=lrelu(sA[5]*u1+sC[5])*x0;
    row[5]=lrelu(sA[2]*y0+sC[2])*x1; row[6]=lrelu(sA[3]*y1+sC[3])*x1;
    row[7]=lrelu(sA[0]*z0+sC[0])*x2; row[8]=lrelu(sA[1]*z1+sC[1])*x2;
    row[9]=0.f; row[10]=0.f; row[11]=0.f; row[12]=0.f; row[13]=0.f; row[14]=0.f; row[15]=0.f;
  }
}

// ---------------- transpose weights (Cout,F) -> (PADF,Cout) fp32, zero pad rows
__global__ void transpose_w_kernel(const void* __restrict__ W, float* __restrict__ WT,
                                   int Cout, int F, int PADF, const int* __restrict__ flagp){
  int t = blockIdx.x*256 + threadIdx.x;
  if (t >= PADF*Cout) return;
  const int bf = *flagp;
  int c = t / Cout, o = t % Cout;
  WT[t] = (c < F) ? ldin(W, o*F + c, bf) : 0.f;
}

// ---------------- per-point squared norm
__global__ void xx_kernel(const float* __restrict__ src, int ld, int coff, int CR,
                          float* __restrict__ xx){
  int i = blockIdx.x*256 + threadIdx.x;
  if (i >= BB*NN) return;
  const float* row = src + (size_t)i*ld + coff;
  float s = 0.f;
  for (int c=0;c<CR;c+=4){
    float4 f = *(const float4*)&row[c];
    s += f.x*f.x + f.y*f.y + f.z*f.z + f.w*f.w;
  }
  xx[i] = s;
}

// ---------------- negdist = 2*X.X^T - xx_i - xx_j, 64x64 tiles
__global__ __launch_bounds__(256) void negdist_kernel(
    const float* __restrict__ src, int ld, int coff, int CR, int pw2,
    const float* __restrict__ xx, float* __restrict__ negD){
  extern __shared__ float lds[];
  float* At = lds;
  float* Bt = lds + 64*CR;
  int b = blockIdx.z, i0 = blockIdx.y*64, j0 = blockIdx.x*64;
  int tid = threadIdx.x;
  for (int t = tid; t < 64*CR; t += 256){
    int r = t / CR, c = t % CR;
    int ci = pw2 ? ((c + 4*r) & (CR-1)) : c;
    At[r*CR + ci] = src[((size_t)(b*NN + i0 + r))*ld + coff + c];
    Bt[r*CR + ci] = src[((size_t)(b*NN + j0 + r))*ld + coff + c];
  }
  __syncthreads();
  int ti = tid >> 4, tj = tid & 15;
  int ri = ti*4, rj = tj*4;
  float acc[4][4];
#pragma unroll
  for (int u=0;u<4;u++)
#pragma unroll
    for (int v=0;v<4;v++) acc[u][v]=0.f;
  for (int c=0;c<CR;c+=4){
    float4 av[4], bv[4];
#pragma unroll
    for (int u=0;u<4;u++){
      int ca = pw2 ? ((c + 4*(ri+u)) & (CR-1)) : c;
      av[u] = *(const float4*)&At[(ri+u)*CR + ca];
      int cb = pw2 ? ((c + 4*(rj+u)) & (CR-1)) : c;
      bv[u] = *(const float4*)&Bt[(rj+u)*CR + cb];
    }
#pragma unroll
    for (int u=0;u<4;u++)
#pragma unroll
      for (int v=0;v<4;v++)
        acc[u][v] += av[u].x*bv[v].x + av[u].y*bv[v].y + av[u].z*bv[v].z + av[u].w*bv[v].w;
  }
  float xi[4], xj[4];
#pragma unroll
  for (int u=0;u<4;u++){ xi[u]=xx[b*NN+i0+ri+u]; xj[u]=xx[b*NN+j0+rj+u]; }
#pragma unroll
  for (int u=0;u<4;u++){
    float4 ov;
    ov.x = 2.f*acc[u][0] - xi[u] - xj[0];
    ov.y = 2.f*acc[u][1] - xi[u] - xj[1];
    ov.z = 2.f*acc[u][2] - xi[u] - xj[2];
    ov.w = 2.f*acc[u][3] - xi[u] - xj[3];
    *(float4*)&negD[((size_t)(b*NN + i0 + ri + u))*NN + j0 + rj] = ov;
  }
}

// ---------------- top-20 (largest negdist), ties -> lower index (matches lax.top_k)
__global__ void topk_kernel(const float* __restrict__ negD, int* __restrict__ idx){
  int i = blockIdx.x*256 + threadIdx.x;
  if (i >= BB*NN) return;
  const float4* row = (const float4*)(negD + (size_t)i*NN);
  float best[KK]; int bi[KK];
#pragma unroll
  for (int k=0;k<KK;k++){ best[k]=-1e30f; bi[k]=0; }
  for (int q=0;q<NN/4;q++){
    float4 v4 = row[q];
    float vals[4] = {v4.x, v4.y, v4.z, v4.w};
#pragma unroll
    for (int e=0;e<4;e++){
      float v = vals[e];
      if (v > best[KK-1]){
        int p = KK-1;
        while (p>0 && best[p-1] < v){
          best[p]=best[p-1]; bi[p]=bi[p-1]; p--;
        }
        best[p]=v; bi[p]=q*4+e;
      }
    }
  }
  for (int k=0;k<KK;k++) idx[(size_t)i*KK+k]=bi[k];
}

// ---------------- edge block GEMM (stats pass / output pass)
template<int CIN,int COUT,int PT,int PADF,bool STATS>
__global__ __launch_bounds__(256) void eb_kernel(
    const float* __restrict__ srcT, int ld, int coff,
    const int* __restrict__ idx, const float* __restrict__ WT,
    float* __restrict__ stats, float* __restrict__ outp, int outoff){
  constexpr int F = 2*CIN;
  constexpr int NBLK = NN/PT;
  __shared__ float feat[PT*KK*PADF];
  int tid = threadIdx.x;
  int b = blockIdx.x / NBLK;
  int n0 = (blockIdx.x % NBLK)*PT;
  // stage features [nbr-cen | cen | zeropad] per (p,k)
  for (int t=tid; t<PT*KK*PADF; t+=256){
    int c = t % PADF;
    int rk = t / PADF;
    int k = rk % KK, p = rk / KK;
    int n = n0 + p;
    float val = 0.f;
    if (c < CIN){
      int m = idx[((size_t)(b*NN+n))*KK + k];
      val = srcT[((size_t)(b*NN+m))*ld + coff + c] - srcT[((size_t)(b*NN+n))*ld + coff + c];
    } else if (c < F){
      val = srcT[((size_t)(b*NN+n))*ld + coff + (c - CIN)];
    }
    feat[t] = val;
  }
  __syncthreads();
  constexpr int G = 256/COUT;
  int o = tid % COUT;
  int grp = tid / COUT;
  float a=0.f, c0=0.f;
  if (!STATS){ a = stats[o]; c0 = stats[COUT+o]; }
  float s1=0.f, s2=0.f;
  for (int p=grp; p<PT; p+=G){
    float h[KK];
#pragma unroll
    for (int k=0;k<KK;k++) h[k]=0.f;
    const float* fb = &feat[p*KK*PADF];
    for (int c=0;c<PADF;c+=4){
      float w0 = WT[(c+0)*COUT+o];
      float w1 = WT[(c+1)*COUT+o];
      float w2 = WT[(c+2)*COUT+o];
      float w3 = WT[(c+3)*COUT+o];
#pragma unroll
      for (int k=0;k<KK;k++){
        float4 f = *(const float4*)&fb[k*PADF + c];
        h[k] = fmaf(f.x,w0,fmaf(f.y,w1,fmaf(f.z,w2,fmaf(f.w,w3,h[k]))));
      }
    }
    if (STATS){
#pragma unroll
      for (int k=0;k<KK;k++){ s1 += h[k]; s2 = fmaf(h[k],h[k],s2); }
    } else {
      float mv = -1e30f;
#pragma unroll
      for (int k=0;k<KK;k++) mv = fmaxf(mv, lrelu(fmaf(a,h[k],c0)));
      outp[((size_t)(b*NN + n0 + p))*512 + outoff + o] = mv;
    }
  }
  if (STATS){
    __syncthreads();
    float* red = feat;
    red[tid] = s1; red[256+tid] = s2;
    __syncthreads();
    if (grp==0){
      float t1=s1, t2=s2;
      for (int g2=1; g2<G; g2++){ t1 += red[g2*COUT+o]; t2 += red[256 + g2*COUT+o]; }
      atomicAdd(&stats[o], t1);
      atomicAdd(&stats[COUT+o], t2);
    }
  }
}

// ---------------- finalize BN stats -> (scale, shift) in place
__global__ void finalize_kernel(float* __restrict__ stats, const void* __restrict__ g,
                                const void* __restrict__ bb, float inv_count, int Cout,
                                const int* __restrict__ flagp){
  int o = blockIdx.x*256 + threadIdx.x;
  if (o >= Cout) return;
  const int bf = *flagp;
  float m = stats[o]*inv_count;
  float v = stats[Cout+o]*inv_count - m*m;
  float a = ldin(g,o,bf)*rsqrtf(fmaxf(v,0.f) + EPSB);
  stats[o] = a;
  stats[Cout+o] = ldin(bb,o,bf) - m*a;
}

// ---------------- conv5 (512->1024) GEMM; stats pass / bn+lrelu+pool pass
template<bool STATS>
__global__ __launch_bounds__(256) void fc5_kernel(
    const float* __restrict__ xcat, const float* __restrict__ WT5,
    float* __restrict__ st5, unsigned* __restrict__ pmax, float* __restrict__ psum){
  constexpr int PT = 16;
  __shared__ float rows[PT*512];
  int tid = threadIdx.x;
  int b = blockIdx.x >> 6;            // 64 blocks per batch
  int n0 = (blockIdx.x & 63) * PT;
  const float* src = xcat + ((size_t)(b*NN + n0))*512;
  for (int t=tid; t<PT*512; t+=256) rows[t] = src[t];
  __syncthreads();
  for (int ot=0; ot<1024; ot+=256){
    int o = ot + tid;
    float h[PT];
#pragma unroll
    for (int r=0;r<PT;r++) h[r]=0.f;
    for (int c=0;c<512;c+=4){
      float w0 = WT5[(size_t)(c+0)*1024+o];
      float w1 = WT5[(size_t)(c+1)*1024+o];
      float w2 = WT5[(size_t)(c+2)*1024+o];
      float w3 = WT5[(size_t)(c+3)*1024+o];
#pragma unroll
      for (int r=0;r<PT;r++){
        float4 f = *(const float4*)&rows[r*512+c];
        h[r] = fmaf(f.x,w0,fmaf(f.y,w1,fmaf(f.z,w2,fmaf(f.w,w3,h[r]))));
      }
    }
    if (STATS){
      float s1=0.f, s2=0.f;
#pragma unroll
      for (int r=0;r<PT;r++){ s1+=h[r]; s2=fmaf(h[r],h[r],s2); }
      atomicAdd(&st5[o], s1);
      atomicAdd(&st5[1024+o], s2);
    } else {
      float a = st5[o], cc = st5[1024+o];
      float mx=-1e30f, sm=0.f;
#pragma unroll
      for (int r=0;r<PT;r++){
        float t = lrelu(fmaf(a,h[r],cc));
        mx = fmaxf(mx, t); sm += t;
      }
      atomicMax(&pmax[b*1024+o], f2u_ord(mx));
      atomicAdd(&psum[b*1024+o], sm);
    }
  }
}

__global__ void pool_finalize_kernel(const unsigned* __restrict__ pmax,
                                     const float* __restrict__ psum,
                                     float* __restrict__ pooled){
  int t = blockIdx.x*256+threadIdx.x;
  if (t >= BB*2048) return;
  int b = t >> 11, j = t & 2047;
  pooled[t] = (j < 1024) ? u2f_ord(pmax[b*1024+j]) : psum[b*1024 + (j-1024)] * (1.f/1024.f);
}

// ---------------- FC layers: one block per output channel; BN over batch of 8
__global__ __launch_bounds__(256) void fc6_kernel(
    const float* __restrict__ pooled, const void* __restrict__ W,
    const void* __restrict__ g, const void* __restrict__ bb, float* __restrict__ y6,
    const int* __restrict__ flagp){
  __shared__ float red[8][256];
  int o = blockIdx.x, tid = threadIdx.x;
  const int bf = *flagp;
  float part[8];
#pragma unroll
  for (int b=0;b<8;b++) part[b]=0.f;
  for (int c=tid;c<2048;c+=256){
    float wv = ldin(W,o*2048+c,bf);
#pragma unroll
    for (int b=0;b<8;b++) part[b] = fmaf(pooled[b*2048+c], wv, part[b]);
  }
#pragma unroll
  for (int b=0;b<8;b++) red[b][tid]=part[b];
  __syncthreads();
  for (int s=128;s;s>>=1){
    if (tid<s){
#pragma unroll
      for (int b=0;b<8;b++) red[b][tid]+=red[b][tid+s];
    }
    __syncthreads();
  }
  if (tid==0){
    float y[8], m=0.f;
#pragma unroll
    for (int b=0;b<8;b++){ y[b]=red[b][0]; m+=y[b]; }
    m *= 0.125f;
    float v=0.f;
#pragma unroll
    for (int b=0;b<8;b++){ float d=y[b]-m; v += d*d; }
    v *= 0.125f;
    float a=ldin(g,o,bf)*rsqrtf(fmaxf(v,0.f)+EPSB), c0=ldin(bb,o,bf)-m*a;
#pragma unroll
    for (int b=0;b<8;b++) y6[b*512+o]=lrelu(fmaf(a,y[b],c0));
  }
}

__global__ __launch_bounds__(256) void fc7_kernel(
    const float* __restrict__ y6, const void* __restrict__ W, const void* __restrict__ bias,
    const void* __restrict__ g, const void* __restrict__ bb, float* __restrict__ y7,
    const int* __restrict__ flagp){
  __shared__ float red[8][256];
  int o = blockIdx.x, tid = threadIdx.x;
  const int bf = *flagp;
  float part[8];
#pragma unroll
  for (int b=0;b<8;b++) part[b]=0.f;
  for (int c=tid;c<512;c+=256){
    float wv = ldin(W,o*512+c,bf);
#pragma unroll
    for (int b=0;b<8;b++) part[b] = fmaf(y6[b*512+c], wv, part[b]);
  }
#pragma unroll
  for (int b=0;b<8;b++) red[b][tid]=part[b];
  __syncthreads();
  for (int s=128;s;s>>=1){
    if (tid<s){
#pragma unroll
      for (int b=0;b<8;b++) red[b][tid]+=red[b][tid+s];
    }
    __syncthreads();
  }
  if (tid==0){
    float bs = ldin(bias,o,bf);
    float y[8], m=0.f;
#pragma unroll
    for (int b=0;b<8;b++){ y[b]=red[b][0]+bs; m+=y[b]; }
    m *= 0.125f;
    float v=0.f;
#pragma unroll
    for (int b=0;b<8;b++){ float d=y[b]-m; v += d*d; }
    v *= 0.125f;
    float a=ldin(g,o,bf)*rsqrtf(fmaxf(v,0.f)+EPSB), c0=ldin(bb,o,bf)-m*a;
#pragma unroll
    for (int b=0;b<8;b++) y7[b*256+o]=lrelu(fmaf(a,y[b],c0));
  }
}

__global__ __launch_bounds__(256) void fc8_kernel(
    const float* __restrict__ y7, const void* __restrict__ W, const void* __restrict__ bias,
    void* __restrict__ out, const int* __restrict__ flagp){
  __shared__ float red[8][256];
  int o = blockIdx.x, tid = threadIdx.x;
  const int bf = *flagp;
  float wv = ldin(W,o*256+tid,bf);
#pragma unroll
  for (int b=0;b<8;b++) red[b][tid] = y7[b*256+tid]*wv;
  __syncthreads();
  for (int s=128;s;s>>=1){
    if (tid<s){
#pragma unroll
      for (int b=0;b<8;b++) red[b][tid]+=red[b][tid+s];
    }
    __syncthreads();
  }
  if (tid==0){
    float bs = ldin(bias,o,bf);
#pragma unroll
    for (int b=0;b<8;b++){
      float r = red[b][0]+bs;
      if (bf) ((bf16*)out)[b*40+o] = __float2bfloat16(r);
      else    ((float*)out)[b*40+o] = r;
    }
  }
}

extern "C" void kernel_launch(void* const* d_in, const int* in_sizes, int n_in,
                              void* d_out, int out_size, void* d_ws, size_t ws_size,
                              hipStream_t stream){
  const void* x    = d_in[0];
  const void* w00  = d_in[1];
  const void* g00  = d_in[2];
  const void* b00  = d_in[3];
  const void* w01  = d_in[4];
  const void* g01  = d_in[5];
  const void* b01  = d_in[6];
  const void* w1   = d_in[7];  const void* g1 = d_in[8];  const void* b1 = d_in[9];
  const void* w2   = d_in[10]; const void* g2 = d_in[11]; const void* b2 = d_in[12];
  const void* w3   = d_in[13]; const void* g3 = d_in[14]; const void* b3 = d_in[15];
  const void* w4   = d_in[16]; const void* g4 = d_in[17]; const void* b4 = d_in[18];
  const void* w5   = d_in[19]; const void* g5 = d_in[20]; const void* b5 = d_in[21];
  const void* w6   = d_in[22]; const void* g6 = d_in[23]; const void* b6 = d_in[24];
  const void* w7   = d_in[25]; const void* bias7 = d_in[26];
  const void* g7   = d_in[27]; const void* b7 = d_in[28];
  const void* w8   = d_in[29]; const void* bias8 = d_in[30];

  float* ws = (float*)d_ws;
  // workspace layout (float offsets)
  size_t o_xc0  = 0;                              // B*N*16
  size_t o_xcat = o_xc0  + (size_t)BB*NN*16;      // B*N*512
  size_t o_negd = o_xcat + (size_t)BB*NN*512;     // B*N*N
  size_t o_xx   = o_negd + (size_t)BB*NN*NN;      // B*N
  size_t o_wt1  = o_xx   + (size_t)BB*NN;         // 20*64
  size_t o_wt2  = o_wt1  + 20*64;                 // 128*64
  size_t o_wt3  = o_wt2  + 128*64;                // 128*128
  size_t o_wt4  = o_wt3  + 128*128;               // 256*256
  size_t o_wt5  = o_wt4  + 256*256;               // 512*1024
  size_t o_st1  = o_wt5  + (size_t)512*1024;      // 128
  size_t o_st2  = o_st1  + 128;                   // 128
  size_t o_st3  = o_st2  + 128;                   // 256
  size_t o_st4  = o_st3  + 256;                   // 512
  size_t o_st5  = o_st4  + 512;                   // 2048
  size_t o_pmax = o_st5  + 2048;                  // 8*1024 (uint)
  size_t o_psum = o_pmax + 8192;                  // 8*1024
  size_t o_pool = o_psum + 8192;                  // 8*2048
  size_t o_y6   = o_pool + 16384;                 // 8*512
  size_t o_y7   = o_y6   + 4096;                  // 8*256
  size_t o_idx  = o_y7   + 2048;                  // B*N*20 ints
  size_t o_flag = o_idx  + (size_t)BB*NN*KK;      // 1 int

  int* idxp = (int*)(ws + o_idx);
  int* flagp = (int*)(ws + o_flag);
  float* negD = ws + o_negd;
  float* xxp  = ws + o_xx;
  float* xc0  = ws + o_xc0;
  float* xcat = ws + o_xcat;

  // dtype detect first (all ldin users depend on it)
  detect_kernel<<<1,64,0,stream>>>((const unsigned*)x, flagp);

  // zero stats + pool accumulators (19456 u32)
  int nz = 128+128+256+512+2048+8192+8192;
  zero_kernel<<<(nz+255)/256, 256, 0, stream>>>((unsigned*)(ws + o_st1), nz);

  conv0_kernel<<<1,256,0,stream>>>(x, w00,g00,b00, w01,g01,b01, xc0, flagp);

  transpose_w_kernel<<<(20*64+255)/256,   256,0,stream>>>(w1, ws+o_wt1, 64, 18, 20, flagp);
  transpose_w_kernel<<<(128*64+255)/256,  256,0,stream>>>(w2, ws+o_wt2, 64, 128, 128, flagp);
  transpose_w_kernel<<<(128*128+255)/256, 256,0,stream>>>(w3, ws+o_wt3, 128, 128, 128, flagp);
  transpose_w_kernel<<<(256*256+255)/256, 256,0,stream>>>(w4, ws+o_wt4, 256, 256, 256, flagp);
  transpose_w_kernel<<<(512*1024+255)/256,256,0,stream>>>(w5, ws+o_wt5, 1024, 512, 512, flagp);

  dim3 ndgrid(NN/64, NN/64, BB);

  // ---- edge block 1: src=xc0 (ld16, C=9, CR=12), Cout=64 -> xcat[:,0:64)
  xx_kernel<<<32,256,0,stream>>>(xc0, 16, 0, 12, xxp);
  negdist_kernel<<<ndgrid,256, 2*64*12*4, stream>>>(xc0, 16, 0, 12, 0, xxp, negD);
  topk_kernel<<<32,256,0,stream>>>(negD, idxp);
  eb_kernel<9,64,16,20,true ><<<BB*(NN/16),256,0,stream>>>(xc0, 16, 0, idxp, ws+o_wt1, ws+o_st1, nullptr, 0);
  finalize_kernel<<<1,256,0,stream>>>(ws+o_st1, g1, b1, 1.f/(BB*NN*KK), 64, flagp);
  eb_kernel<9,64,16,20,false><<<BB*(NN/16),256,0,stream>>>(xc0, 16, 0, idxp, ws+o_wt1, ws+o_st1, xcat, 0);

  // ---- edge block 2: src=xcat[:,0:64) (x1), Cout=64 -> xcat[:,64:128)
  xx_kernel<<<32,256,0,stream>>>(xcat, 512, 0, 64, xxp);
  negdist_kernel<<<ndgrid,256, 2*64*64*4, stream>>>(xcat, 512, 0, 64, 1, xxp, negD);
  topk_kernel<<<32,256,0,stream>>>(negD, idxp);
  eb_kernel<64,64,4,128,true ><<<BB*(NN/4),256,0,stream>>>(xcat, 512, 0, idxp, ws+o_wt2, ws+o_st2, nullptr, 0);
  finalize_kernel<<<1,256,0,stream>>>(ws+o_st2, g2, b2, 1.f/(BB*NN*KK), 64, flagp);
  eb_kernel<64,64,4,128,false><<<BB*(NN/4),256,0,stream>>>(xcat, 512, 0, idxp, ws+o_wt2, ws+o_st2, xcat, 64);

  // ---- edge block 3: src=xcat[:,64:128) (x2), Cout=128 -> xcat[:,128:256)
  xx_kernel<<<32,256,0,stream>>>(xcat, 512, 64, 64, xxp);
  negdist_kernel<<<ndgrid,256, 2*64*64*4, stream>>>(xcat, 512, 64, 64, 1, xxp, negD);
  topk_kernel<<<32,256,0,stream>>>(negD, idxp);
  eb_kernel<64,128,4,128,true ><<<BB*(NN/4),256,0,stream>>>(xcat, 512, 64, idxp, ws+o_wt3, ws+o_st3, nullptr, 0);
  finalize_kernel<<<1,256,0,stream>>>(ws+o_st3, g3, b3, 1.f/(BB*NN*KK), 128, flagp);
  eb_kernel<64,128,4,128,false><<<BB*(NN/4),256,0,stream>>>(xcat, 512, 64, idxp, ws+o_wt3, ws+o_st3, xcat, 128);

  // ---- edge block 4: src=xcat[:,128:256) (x3), Cout=256 -> xcat[:,256:512)
  xx_kernel<<<32,256,0,stream>>>(xcat, 512, 128, 128, xxp);
  negdist_kernel<<<ndgrid,256, 2*64*128*4, stream>>>(xcat, 512, 128, 128, 1, xxp, negD);
  topk_kernel<<<32,256,0,stream>>>(negD, idxp);
  eb_kernel<128,256,2,256,true ><<<BB*(NN/2),256,0,stream>>>(xcat, 512, 128, idxp, ws+o_wt4, ws+o_st4, nullptr, 0);
  finalize_kernel<<<1,256,0,stream>>>(ws+o_st4, g4, b4, 1.f/(BB*NN*KK), 256, flagp);
  eb_kernel<128,256,2,256,false><<<BB*(NN/2),256,0,stream>>>(xcat, 512, 128, idxp, ws+o_wt4, ws+o_st4, xcat, 256);

  // ---- conv5 (512 -> 1024) + BN + lrelu + global max/mean pool
  fc5_kernel<true ><<<BB*(NN/16),256,0,stream>>>(xcat, ws+o_wt5, ws+o_st5, (unsigned*)(ws+o_pmax), ws+o_psum);
  finalize_kernel<<<4,256,0,stream>>>(ws+o_st5, g5, b5, 1.f/(BB*NN), 1024, flagp);
  fc5_kernel<false><<<BB*(NN/16),256,0,stream>>>(xcat, ws+o_wt5, ws+o_st5, (unsigned*)(ws+o_pmax), ws+o_psum);
  pool_finalize_kernel<<<(BB*2048+255)/256,256,0,stream>>>((unsigned*)(ws+o_pmax), ws+o_psum, ws+o_pool);

  // ---- FC head
  fc6_kernel<<<512,256,0,stream>>>(ws+o_pool, w6, g6, b6, ws+o_y6, flagp);
  fc7_kernel<<<256,256,0,stream>>>(ws+o_y6, w7, bias7, g7, b7, ws+o_y7, flagp);
  fc8_kernel<<<40,256,0,stream>>>(ws+o_y7, w8, bias8, d_out, flagp);
}

// Round 3
// 2355.176 us; speedup vs baseline: 5.0377x; 5.0377x over previous
//
#include <hip/hip_runtime.h>
#include <hip/hip_bf16.h>

#define BB 8
#define NN 1024
#define KK 20
#define EPSB 1e-5f

typedef __hip_bfloat16 bf16;

__device__ __forceinline__ float b2f(bf16 v){ return __bfloat162float(v); }
__device__ __forceinline__ float lrelu(float t){ return t >= 0.f ? t : 0.2f*t; }
// dtype-flag-aware input load: flag=1 -> bf16, flag=0 -> fp32
__device__ __forceinline__ float ldin(const void* p, int i, int bf){
  return bf ? __bfloat162float(((const bf16*)p)[i]) : ((const float*)p)[i];
}
__device__ __forceinline__ unsigned f2u_ord(float f){
  unsigned u = __float_as_uint(f);
  return (u & 0x80000000u) ? ~u : (u | 0x80000000u);
}
__device__ __forceinline__ float u2f_ord(unsigned u){
  return (u & 0x80000000u) ? __uint_as_float(u & 0x7fffffffu) : __uint_as_float(~u);
}

// ---------------- dtype detection: fp32 N(0,1) words have exponent ~[90,130];
// packed-bf16 words mostly have exponent >= 236. Count huge-exponent words.
__global__ void detect_kernel(const unsigned* __restrict__ xw, int* __restrict__ flag){
  int t = threadIdx.x;               // 0..63, one wave
  unsigned w = xw[t];
  unsigned e = (w >> 23) & 0xFFu;
  int huge = (e >= 0xD0u) ? 1 : 0;   // |fp32| >= ~2^80: impossible for normal data
  unsigned long long m = __ballot(huge);
  if (t == 0) *flag = (__popcll(m) >= 32) ? 1 : 0;
}

// ---------------- zero init (stats & pool accumulators; ws is poisoned 0xAA each call)
__global__ void zero_kernel(unsigned* __restrict__ p, int n){
  int i = blockIdx.x*256 + threadIdx.x;
  if (i < n) p[i] = 0u;
}

// ---------------- conv0: three 2->2 gated branches, single block (tiny)
__global__ __launch_bounds__(256) void conv0_kernel(
    const void* __restrict__ x,
    const void* __restrict__ w00, const void* __restrict__ g00, const void* __restrict__ b00,
    const void* __restrict__ w01, const void* __restrict__ g01, const void* __restrict__ b01,
    float* __restrict__ xc0, const int* __restrict__ flagp){
  __shared__ float sacc[12][256];
  __shared__ float sA[6], sC[6];
  const int bf = *flagp;
  int tid = threadIdx.x;
  float part[12];
#pragma unroll
  for (int j=0;j<12;j++) part[j]=0.f;
  float wz[4], wy[4];
#pragma unroll
  for (int j=0;j<4;j++){ wz[j]=ldin(w00,j,bf); wy[j]=ldin(w01,j,bf); }
  for (int i = tid; i < BB*NN; i += 256){
    int b = i / NN, n = i % NN;
    float x0 = ldin(x,(b*3+0)*NN + n,bf);
    float x1 = ldin(x,(b*3+1)*NN + n,bf);
    float x2 = ldin(x,(b*3+2)*NN + n,bf);
    float z0 = wz[0]*x0 + wz[1]*x1, z1 = wz[2]*x0 + wz[3]*x1; // bz: ch (0,1), w00
    float y0 = wy[0]*x0 + wy[1]*x2, y1 = wy[2]*x0 + wy[3]*x2; // by: ch (0,2), w01
    float u0 = wy[0]*x1 + wy[1]*x2, u1 = wy[2]*x1 + wy[3]*x2; // bx: ch (1,2), w01
    part[0]+=z0; part[1]+=z0*z0; part[2]+=z1; part[3]+=z1*z1;
    part[4]+=y0; part[5]+=y0*y0; part[6]+=y1; part[7]+=y1*y1;
    part[8]+=u0; part[9]+=u0*u0; part[10]+=u1; part[11]+=u1*u1;
  }
#pragma unroll
  for (int j=0;j<12;j++) sacc[j][tid]=part[j];
  __syncthreads();
  for (int s=128;s;s>>=1){
    if (tid<s){
#pragma unroll
      for (int j=0;j<12;j++) sacc[j][tid]+=sacc[j][tid+s];
    }
    __syncthreads();
  }
  if (tid < 6){
    float m = sacc[2*tid][0] * (1.f/(BB*NN));
    float v = sacc[2*tid+1][0] * (1.f/(BB*NN)) - m*m;
    float g, bv;
    if (tid<2){ g=ldin(g00,tid,bf); bv=ldin(b00,tid,bf); }
    else if (tid<4){ g=ldin(g01,tid-2,bf); bv=ldin(b01,tid-2,bf); }
    else { g=ldin(g01,tid-4,bf); bv=ldin(b01,tid-4,bf); }
    float a = g * rsqrtf(fmaxf(v,0.f) + EPSB);
    sA[tid]=a; sC[tid]=bv - m*a;
  }
  __syncthreads();
  for (int i = tid; i < BB*NN; i += 256){
    int b = i / NN, n = i % NN;
    float x0 = ldin(x,(b*3+0)*NN + n,bf);
    float x1 = ldin(x,(b*3+1)*NN + n,bf);
    float x2 = ldin(x,(b*3+2)*NN + n,bf);
    float z0 = wz[0]*x0 + wz[1]*x1, z1 = wz[2]*x0 + wz[3]*x1;
    float y0 = wy[0]*x0 + wy[1]*x2, y1 = wy[2]*x0 + wy[3]*x2;
    float u0 = wy[0]*x1 + wy[1]*x2, u1 = wy[2]*x1 + wy[3]*x2;
    float* row = xc0 + (size_t)i*16;
    row[0]=x0; row[1]=x1; row[2]=x2;
    // concat order: [x, x_2d_x, x_2d_y, x_2d_z]
    row[3]=lrelu(sA[4]*u0+sC[4])*x0; row[4]=lrelu(sA[5]*u1+sC[5])*x0;
    row[5]=lrelu(sA[2]*y0+sC[2])*x1; row[6]=lrelu(sA[3]*y1+sC[3])*x1;
    row[7]=lrelu(sA[0]*z0+sC[0])*x2; row[8]=lrelu(sA[1]*z1+sC[1])*x2;
    row[9]=0.f; row[10]=0.f; row[11]=0.f; row[12]=0.f; row[13]=0.f; row[14]=0.f; row[15]=0.f;
  }
}

// ---------------- transpose weights (Cout,F) -> (PADF,Cout) fp32, zero pad rows
__global__ void transpose_w_kernel(const void* __restrict__ W, float* __restrict__ WT,
                                   int Cout, int F, int PADF, const int* __restrict__ flagp){
  int t = blockIdx.x*256 + threadIdx.x;
  if (t >= PADF*Cout) return;
  const int bf = *flagp;
  int c = t / Cout, o = t % Cout;
  WT[t] = (c < F) ? ldin(W, o*F + c, bf) : 0.f;
}

// ---------------- per-point squared norm
__global__ void xx_kernel(const float* __restrict__ src, int ld, int coff, int CR,
                          float* __restrict__ xx){
  int i = blockIdx.x*256 + threadIdx.x;
  if (i >= BB*NN) return;
  const float* row = src + (size_t)i*ld + coff;
  float s = 0.f;
  for (int c=0;c<CR;c+=4){
    float4 f = *(const float4*)&row[c];
    s += f.x*f.x + f.y*f.y + f.z*f.z + f.w*f.w;
  }
  xx[i] = s;
}

// ---------------- negdist = 2*X.X^T - xx_i - xx_j, 64x64 tiles
// XOR swizzle on 16B groups keyed by (row>>2): B-rows step by 4, so tj=0..15
// lands on 16 distinct groups -> <=2-way bank aliasing (free). sw=1 requires CR pow2.
__global__ __launch_bounds__(256) void negdist_kernel(
    const float* __restrict__ src, int ld, int coff, int CR, int sw,
    const float* __restrict__ xx, float* __restrict__ negD){
  extern __shared__ float lds[];
  float* At = lds;
  float* Bt = lds + 64*CR;
  int b = blockIdx.z, i0 = blockIdx.y*64, j0 = blockIdx.x*64;
  int tid = threadIdx.x;
  int g4m = (CR>>2) - 1;
  for (int t = tid; t < 64*CR; t += 256){
    int r = t / CR, c = t % CR;
    int ci = sw ? (((((c>>2) ^ (r>>2)) & g4m)<<2) | (c&3)) : c;
    At[r*CR + ci] = src[((size_t)(b*NN + i0 + r))*ld + coff + c];
    Bt[r*CR + ci] = src[((size_t)(b*NN + j0 + r))*ld + coff + c];
  }
  __syncthreads();
  int ti = tid >> 4, tj = tid & 15;
  int ri = ti*4, rj = tj*4;
  float acc[4][4];
#pragma unroll
  for (int u=0;u<4;u++)
#pragma unroll
    for (int v=0;v<4;v++) acc[u][v]=0.f;
  for (int c=0;c<CR;c+=4){
    float4 av[4], bv[4];
#pragma unroll
    for (int u=0;u<4;u++){
      int ra = ri+u;
      int ca = sw ? ((((c>>2) ^ (ra>>2)) & g4m)<<2) : c;
      av[u] = *(const float4*)&At[ra*CR + ca];
      int rb = rj+u;
      int cb = sw ? ((((c>>2) ^ (rb>>2)) & g4m)<<2) : c;
      bv[u] = *(const float4*)&Bt[rb*CR + cb];
    }
#pragma unroll
    for (int u=0;u<4;u++)
#pragma unroll
      for (int v=0;v<4;v++)
        acc[u][v] += av[u].x*bv[v].x + av[u].y*bv[v].y + av[u].z*bv[v].z + av[u].w*bv[v].w;
  }
  float xi[4], xj[4];
#pragma unroll
  for (int u=0;u<4;u++){ xi[u]=xx[b*NN+i0+ri+u]; xj[u]=xx[b*NN+j0+rj+u]; }
#pragma unroll
  for (int u=0;u<4;u++){
    float4 ov;
    ov.x = 2.f*acc[u][0] - xi[u] - xj[0];
    ov.y = 2.f*acc[u][1] - xi[u] - xj[1];
    ov.z = 2.f*acc[u][2] - xi[u] - xj[2];
    ov.w = 2.f*acc[u][3] - xi[u] - xj[3];
    *(float4*)&negD[((size_t)(b*NN + i0 + ri + u))*NN + j0 + rj] = ov;
  }
}

// ---------------- top-20: one wave per row; values in registers; k iterations of
// wave-argmax (64-bit key = ordered-value | (1023-idx) for lower-index tie-break).
__global__ __launch_bounds__(256) void topk_kernel(const float* __restrict__ negD,
                                                   int* __restrict__ idx){
  int row_id = (blockIdx.x*256 + threadIdx.x) >> 6;
  int lane = threadIdx.x & 63;
  if (row_id >= BB*NN) return;
  const float* row = negD + (size_t)row_id*NN;
  // v[j*4+e] = row[j*256 + lane*4 + e]; slot order == increasing global index per lane
  float v[16];
#pragma unroll
  for (int j=0;j<4;j++){
    float4 f = *(const float4*)&row[j*256 + lane*4];
    v[j*4+0]=f.x; v[j*4+1]=f.y; v[j*4+2]=f.z; v[j*4+3]=f.w;
  }
  int* orow = idx + (size_t)row_id*KK;
  for (int k=0;k<KK;k++){
    // lane-local argmax (strict > keeps earliest slot = lowest index)
    float bv = v[0]; int bs = 0;
#pragma unroll
    for (int s=1;s<16;s++){ if (v[s] > bv){ bv = v[s]; bs = s; } }
    int bidx = (bs>>2)*256 + lane*4 + (bs&3);
    unsigned long long key = ((unsigned long long)f2u_ord(bv) << 32) | (unsigned)(1023 - bidx);
#pragma unroll
    for (int off=32; off; off>>=1){
      unsigned long long o = __shfl_xor(key, off, 64);
      if (o > key) key = o;
    }
    int widx = 1023 - (int)(key & 0xFFFFFFFFu);
    if (lane == 0) orow[k] = widx;
    // disable winner (unrolled selects; no dynamic register indexing)
    bool mine = (((widx >> 2) & 63) == lane);
    int wslot = ((widx >> 8) << 2) | (widx & 3);
#pragma unroll
    for (int s=0;s<16;s++){
      if (mine && s == wslot) v[s] = -1e30f;
    }
  }
}

// ---------------- edge block GEMM (stats pass / output pass)
template<int CIN,int COUT,int PT,int PADF,bool STATS>
__global__ __launch_bounds__(256) void eb_kernel(
    const float* __restrict__ srcT, int ld, int coff,
    const int* __restrict__ idx, const float* __restrict__ WT,
    float* __restrict__ stats, float* __restrict__ outp, int outoff){
  constexpr int F = 2*CIN;
  constexpr int NBLK = NN/PT;
  __shared__ float feat[PT*KK*PADF];
  int tid = threadIdx.x;
  int b = blockIdx.x / NBLK;
  int n0 = (blockIdx.x % NBLK)*PT;
  // stage features [nbr-cen | cen | zeropad] per (p,k)
  for (int t=tid; t<PT*KK*PADF; t+=256){
    int c = t % PADF;
    int rk = t / PADF;
    int k = rk % KK, p = rk / KK;
    int n = n0 + p;
    float val = 0.f;
    if (c < CIN){
      int m = idx[((size_t)(b*NN+n))*KK + k];
      val = srcT[((size_t)(b*NN+m))*ld + coff + c] - srcT[((size_t)(b*NN+n))*ld + coff + c];
    } else if (c < F){
      val = srcT[((size_t)(b*NN+n))*ld + coff + (c - CIN)];
    }
    feat[t] = val;
  }
  __syncthreads();
  constexpr int G = 256/COUT;
  int o = tid % COUT;
  int grp = tid / COUT;
  float a=0.f, c0=0.f;
  if (!STATS){ a = stats[o]; c0 = stats[COUT+o]; }
  float s1=0.f, s2=0.f;
  for (int p=grp; p<PT; p+=G){
    float h[KK];
#pragma unroll
    for (int k=0;k<KK;k++) h[k]=0.f;
    const float* fb = &feat[p*KK*PADF];
    for (int c=0;c<PADF;c+=4){
      float w0 = WT[(c+0)*COUT+o];
      float w1 = WT[(c+1)*COUT+o];
      float w2 = WT[(c+2)*COUT+o];
      float w3 = WT[(c+3)*COUT+o];
#pragma unroll
      for (int k=0;k<KK;k++){
        float4 f = *(const float4*)&fb[k*PADF + c];
        h[k] = fmaf(f.x,w0,fmaf(f.y,w1,fmaf(f.z,w2,fmaf(f.w,w3,h[k]))));
      }
    }
    if (STATS){
#pragma unroll
      for (int k=0;k<KK;k++){ s1 += h[k]; s2 = fmaf(h[k],h[k],s2); }
    } else {
      float mv = -1e30f;
#pragma unroll
      for (int k=0;k<KK;k++) mv = fmaxf(mv, lrelu(fmaf(a,h[k],c0)));
      outp[((size_t)(b*NN + n0 + p))*512 + outoff + o] = mv;
    }
  }
  if (STATS){
    __syncthreads();
    float* red = feat;
    red[tid] = s1; red[256+tid] = s2;
    __syncthreads();
    if (grp==0){
      float t1=s1, t2=s2;
      for (int g2=1; g2<G; g2++){ t1 += red[g2*COUT+o]; t2 += red[256 + g2*COUT+o]; }
      atomicAdd(&stats[o], t1);
      atomicAdd(&stats[COUT+o], t2);
    }
  }
}

// ---------------- finalize BN stats -> (scale, shift) in place
__global__ void finalize_kernel(float* __restrict__ stats, const void* __restrict__ g,
                                const void* __restrict__ bb, float inv_count, int Cout,
                                const int* __restrict__ flagp){
  int o = blockIdx.x*256 + threadIdx.x;
  if (o >= Cout) return;
  const int bf = *flagp;
  float m = stats[o]*inv_count;
  float v = stats[Cout+o]*inv_count - m*m;
  float a = ldin(g,o,bf)*rsqrtf(fmaxf(v,0.f) + EPSB);
  stats[o] = a;
  stats[Cout+o] = ldin(bb,o,bf) - m*a;
}

// ---------------- conv5 (512->1024) GEMM; stats pass / bn+lrelu+pool pass
template<bool STATS>
__global__ __launch_bounds__(256) void fc5_kernel(
    const float* __restrict__ xcat, const float* __restrict__ WT5,
    float* __restrict__ st5, unsigned* __restrict__ pmax, float* __restrict__ psum){
  constexpr int PT = 16;
  __shared__ float rows[PT*512];
  int tid = threadIdx.x;
  int b = blockIdx.x >> 6;            // 64 blocks per batch
  int n0 = (blockIdx.x & 63) * PT;
  const float* src = xcat + ((size_t)(b*NN + n0))*512;
  for (int t=tid; t<PT*512; t+=256) rows[t] = src[t];
  __syncthreads();
  for (int ot=0; ot<1024; ot+=256){
    int o = ot + tid;
    float h[PT];
#pragma unroll
    for (int r=0;r<PT;r++) h[r]=0.f;
    for (int c=0;c<512;c+=4){
      float w0 = WT5[(size_t)(c+0)*1024+o];
      float w1 = WT5[(size_t)(c+1)*1024+o];
      float w2 = WT5[(size_t)(c+2)*1024+o];
      float w3 = WT5[(size_t)(c+3)*1024+o];
#pragma unroll
      for (int r=0;r<PT;r++){
        float4 f = *(const float4*)&rows[r*512+c];
        h[r] = fmaf(f.x,w0,fmaf(f.y,w1,fmaf(f.z,w2,fmaf(f.w,w3,h[r]))));
      }
    }
    if (STATS){
      float s1=0.f, s2=0.f;
#pragma unroll
      for (int r=0;r<PT;r++){ s1+=h[r]; s2=fmaf(h[r],h[r],s2); }
      atomicAdd(&st5[o], s1);
      atomicAdd(&st5[1024+o], s2);
    } else {
      float a = st5[o], cc = st5[1024+o];
      float mx=-1e30f, sm=0.f;
#pragma unroll
      for (int r=0;r<PT;r++){
        float t = lrelu(fmaf(a,h[r],cc));
        mx = fmaxf(mx, t); sm += t;
      }
      atomicMax(&pmax[b*1024+o], f2u_ord(mx));
      atomicAdd(&psum[b*1024+o], sm);
    }
  }
}

__global__ void pool_finalize_kernel(const unsigned* __restrict__ pmax,
                                     const float* __restrict__ psum,
                                     float* __restrict__ pooled){
  int t = blockIdx.x*256+threadIdx.x;
  if (t >= BB*2048) return;
  int b = t >> 11, j = t & 2047;
  pooled[t] = (j < 1024) ? u2f_ord(pmax[b*1024+j]) : psum[b*1024 + (j-1024)] * (1.f/1024.f);
}

// ---------------- FC layers: one block per output channel; BN over batch of 8
__global__ __launch_bounds__(256) void fc6_kernel(
    const float* __restrict__ pooled, const void* __restrict__ W,
    const void* __restrict__ g, const void* __restrict__ bb, float* __restrict__ y6,
    const int* __restrict__ flagp){
  __shared__ float red[8][256];
  int o = blockIdx.x, tid = threadIdx.x;
  const int bf = *flagp;
  float part[8];
#pragma unroll
  for (int b=0;b<8;b++) part[b]=0.f;
  for (int c=tid;c<2048;c+=256){
    float wv = ldin(W,o*2048+c,bf);
#pragma unroll
    for (int b=0;b<8;b++) part[b] = fmaf(pooled[b*2048+c], wv, part[b]);
  }
#pragma unroll
  for (int b=0;b<8;b++) red[b][tid]=part[b];
  __syncthreads();
  for (int s=128;s;s>>=1){
    if (tid<s){
#pragma unroll
      for (int b=0;b<8;b++) red[b][tid]+=red[b][tid+s];
    }
    __syncthreads();
  }
  if (tid==0){
    float y[8], m=0.f;
#pragma unroll
    for (int b=0;b<8;b++){ y[b]=red[b][0]; m+=y[b]; }
    m *= 0.125f;
    float v=0.f;
#pragma unroll
    for (int b=0;b<8;b++){ float d=y[b]-m; v += d*d; }
    v *= 0.125f;
    float a=ldin(g,o,bf)*rsqrtf(fmaxf(v,0.f)+EPSB), c0=ldin(bb,o,bf)-m*a;
#pragma unroll
    for (int b=0;b<8;b++) y6[b*512+o]=lrelu(fmaf(a,y[b],c0));
  }
}

__global__ __launch_bounds__(256) void fc7_kernel(
    const float* __restrict__ y6, const void* __restrict__ W, const void* __restrict__ bias,
    const void* __restrict__ g, const void* __restrict__ bb, float* __restrict__ y7,
    const int* __restrict__ flagp){
  __shared__ float red[8][256];
  int o = blockIdx.x, tid = threadIdx.x;
  const int bf = *flagp;
  float part[8];
#pragma unroll
  for (int b=0;b<8;b++) part[b]=0.f;
  for (int c=tid;c<512;c+=256){
    float wv = ldin(W,o*512+c,bf);
#pragma unroll
    for (int b=0;b<8;b++) part[b] = fmaf(y6[b*512+c], wv, part[b]);
  }
#pragma unroll
  for (int b=0;b<8;b++) red[b][tid]=part[b];
  __syncthreads();
  for (int s=128;s;s>>=1){
    if (tid<s){
#pragma unroll
      for (int b=0;b<8;b++) red[b][tid]+=red[b][tid+s];
    }
    __syncthreads();
  }
  if (tid==0){
    float bs = ldin(bias,o,bf);
    float y[8], m=0.f;
#pragma unroll
    for (int b=0;b<8;b++){ y[b]=red[b][0]+bs; m+=y[b]; }
    m *= 0.125f;
    float v=0.f;
#pragma unroll
    for (int b=0;b<8;b++){ float d=y[b]-m; v += d*d; }
    v *= 0.125f;
    float a=ldin(g,o,bf)*rsqrtf(fmaxf(v,0.f)+EPSB), c0=ldin(bb,o,bf)-m*a;
#pragma unroll
    for (int b=0;b<8;b++) y7[b*256+o]=lrelu(fmaf(a,y[b],c0));
  }
}

__global__ __launch_bounds__(256) void fc8_kernel(
    const float* __restrict__ y7, const void* __restrict__ W, const void* __restrict__ bias,
    void* __restrict__ out, const int* __restrict__ flagp){
  __shared__ float red[8][256];
  int o = blockIdx.x, tid = threadIdx.x;
  const int bf = *flagp;
  float wv = ldin(W,o*256+tid,bf);
#pragma unroll
  for (int b=0;b<8;b++) red[b][tid] = y7[b*256+tid]*wv;
  __syncthreads();
  for (int s=128;s;s>>=1){
    if (tid<s){
#pragma unroll
      for (int b=0;b<8;b++) red[b][tid]+=red[b][tid+s];
    }
    __syncthreads();
  }
  if (tid==0){
    float bs = ldin(bias,o,bf);
#pragma unroll
    for (int b=0;b<8;b++){
      float r = red[b][0]+bs;
      if (bf) ((bf16*)out)[b*40+o] = __float2bfloat16(r);
      else    ((float*)out)[b*40+o] = r;
    }
  }
}

extern "C" void kernel_launch(void* const* d_in, const int* in_sizes, int n_in,
                              void* d_out, int out_size, void* d_ws, size_t ws_size,
                              hipStream_t stream){
  const void* x    = d_in[0];
  const void* w00  = d_in[1];
  const void* g00  = d_in[2];
  const void* b00  = d_in[3];
  const void* w01  = d_in[4];
  const void* g01  = d_in[5];
  const void* b01  = d_in[6];
  const void* w1   = d_in[7];  const void* g1 = d_in[8];  const void* b1 = d_in[9];
  const void* w2   = d_in[10]; const void* g2 = d_in[11]; const void* b2 = d_in[12];
  const void* w3   = d_in[13]; const void* g3 = d_in[14]; const void* b3 = d_in[15];
  const void* w4   = d_in[16]; const void* g4 = d_in[17]; const void* b4 = d_in[18];
  const void* w5   = d_in[19]; const void* g5 = d_in[20]; const void* b5 = d_in[21];
  const void* w6   = d_in[22]; const void* g6 = d_in[23]; const void* b6 = d_in[24];
  const void* w7   = d_in[25]; const void* bias7 = d_in[26];
  const void* g7   = d_in[27]; const void* b7 = d_in[28];
  const void* w8   = d_in[29]; const void* bias8 = d_in[30];

  float* ws = (float*)d_ws;
  // workspace layout (float offsets)
  size_t o_xc0  = 0;                              // B*N*16
  size_t o_xcat = o_xc0  + (size_t)BB*NN*16;      // B*N*512
  size_t o_negd = o_xcat + (size_t)BB*NN*512;     // B*N*N
  size_t o_xx   = o_negd + (size_t)BB*NN*NN;      // B*N
  size_t o_wt1  = o_xx   + (size_t)BB*NN;         // 20*64
  size_t o_wt2  = o_wt1  + 20*64;                 // 128*64
  size_t o_wt3  = o_wt2  + 128*64;                // 128*128
  size_t o_wt4  = o_wt3  + 128*128;               // 256*256
  size_t o_wt5  = o_wt4  + 256*256;               // 512*1024
  size_t o_st1  = o_wt5  + (size_t)512*1024;      // 128
  size_t o_st2  = o_st1  + 128;                   // 128
  size_t o_st3  = o_st2  + 128;                   // 256
  size_t o_st4  = o_st3  + 256;                   // 512
  size_t o_st5  = o_st4  + 512;                   // 2048
  size_t o_pmax = o_st5  + 2048;                  // 8*1024 (uint)
  size_t o_psum = o_pmax + 8192;                  // 8*1024
  size_t o_pool = o_psum + 8192;                  // 8*2048
  size_t o_y6   = o_pool + 16384;                 // 8*512
  size_t o_y7   = o_y6   + 4096;                  // 8*256
  size_t o_idx  = o_y7   + 2048;                  // B*N*20 ints
  size_t o_flag = o_idx  + (size_t)BB*NN*KK;      // 1 int

  int* idxp = (int*)(ws + o_idx);
  int* flagp = (int*)(ws + o_flag);
  float* negD = ws + o_negd;
  float* xxp  = ws + o_xx;
  float* xc0  = ws + o_xc0;
  float* xcat = ws + o_xcat;

  // dtype detect first (all ldin users depend on it)
  detect_kernel<<<1,64,0,stream>>>((const unsigned*)x, flagp);

  // zero stats + pool accumulators (19456 u32)
  int nz = 128+128+256+512+2048+8192+8192;
  zero_kernel<<<(nz+255)/256, 256, 0, stream>>>((unsigned*)(ws + o_st1), nz);

  conv0_kernel<<<1,256,0,stream>>>(x, w00,g00,b00, w01,g01,b01, xc0, flagp);

  transpose_w_kernel<<<(20*64+255)/256,   256,0,stream>>>(w1, ws+o_wt1, 64, 18, 20, flagp);
  transpose_w_kernel<<<(128*64+255)/256,  256,0,stream>>>(w2, ws+o_wt2, 64, 128, 128, flagp);
  transpose_w_kernel<<<(128*128+255)/256, 256,0,stream>>>(w3, ws+o_wt3, 128, 128, 128, flagp);
  transpose_w_kernel<<<(256*256+255)/256, 256,0,stream>>>(w4, ws+o_wt4, 256, 256, 256, flagp);
  transpose_w_kernel<<<(512*1024+255)/256,256,0,stream>>>(w5, ws+o_wt5, 1024, 512, 512, flagp);

  dim3 ndgrid(NN/64, NN/64, BB);

  // ---- edge block 1: src=xc0 (ld16, C=9, CR=12), Cout=64 -> xcat[:,0:64)
  xx_kernel<<<32,256,0,stream>>>(xc0, 16, 0, 12, xxp);
  negdist_kernel<<<ndgrid,256, 2*64*12*4, stream>>>(xc0, 16, 0, 12, 0, xxp, negD);
  topk_kernel<<<BB*NN/4,256,0,stream>>>(negD, idxp);
  eb_kernel<9,64,16,20,true ><<<BB*(NN/16),256,0,stream>>>(xc0, 16, 0, idxp, ws+o_wt1, ws+o_st1, nullptr, 0);
  finalize_kernel<<<1,256,0,stream>>>(ws+o_st1, g1, b1, 1.f/(BB*NN*KK), 64, flagp);
  eb_kernel<9,64,16,20,false><<<BB*(NN/16),256,0,stream>>>(xc0, 16, 0, idxp, ws+o_wt1, ws+o_st1, xcat, 0);

  // ---- edge block 2: src=xcat[:,0:64) (x1), Cout=64 -> xcat[:,64:128)
  xx_kernel<<<32,256,0,stream>>>(xcat, 512, 0, 64, xxp);
  negdist_kernel<<<ndgrid,256, 2*64*64*4, stream>>>(xcat, 512, 0, 64, 1, xxp, negD);
  topk_kernel<<<BB*NN/4,256,0,stream>>>(negD, idxp);
  eb_kernel<64,64,4,128,true ><<<BB*(NN/4),256,0,stream>>>(xcat, 512, 0, idxp, ws+o_wt2, ws+o_st2, nullptr, 0);
  finalize_kernel<<<1,256,0,stream>>>(ws+o_st2, g2, b2, 1.f/(BB*NN*KK), 64, flagp);
  eb_kernel<64,64,4,128,false><<<BB*(NN/4),256,0,stream>>>(xcat, 512, 0, idxp, ws+o_wt2, ws+o_st2, xcat, 64);

  // ---- edge block 3: src=xcat[:,64:128) (x2), Cout=128 -> xcat[:,128:256)
  xx_kernel<<<32,256,0,stream>>>(xcat, 512, 64, 64, xxp);
  negdist_kernel<<<ndgrid,256, 2*64*64*4, stream>>>(xcat, 512, 64, 64, 1, xxp, negD);
  topk_kernel<<<BB*NN/4,256,0,stream>>>(negD, idxp);
  eb_kernel<64,128,4,128,true ><<<BB*(NN/4),256,0,stream>>>(xcat, 512, 64, idxp, ws+o_wt3, ws+o_st3, nullptr, 0);
  finalize_kernel<<<1,256,0,stream>>>(ws+o_st3, g3, b3, 1.f/(BB*NN*KK), 128, flagp);
  eb_kernel<64,128,4,128,false><<<BB*(NN/4),256,0,stream>>>(xcat, 512, 64, idxp, ws+o_wt3, ws+o_st3, xcat, 128);

  // ---- edge block 4: src=xcat[:,128:256) (x3), Cout=256 -> xcat[:,256:512)
  xx_kernel<<<32,256,0,stream>>>(xcat, 512, 128, 128, xxp);
  negdist_kernel<<<ndgrid,256, 2*64*128*4, stream>>>(xcat, 512, 128, 128, 1, xxp, negD);
  topk_kernel<<<BB*NN/4,256,0,stream>>>(negD, idxp);
  eb_kernel<128,256,2,256,true ><<<BB*(NN/2),256,0,stream>>>(xcat, 512, 128, idxp, ws+o_wt4, ws+o_st4, nullptr, 0);
  finalize_kernel<<<1,256,0,stream>>>(ws+o_st4, g4, b4, 1.f/(BB*NN*KK), 256, flagp);
  eb_kernel<128,256,2,256,false><<<BB*(NN/2),256,0,stream>>>(xcat, 512, 128, idxp, ws+o_wt4, ws+o_st4, xcat, 256);

  // ---- conv5 (512 -> 1024) + BN + lrelu + global max/mean pool
  fc5_kernel<true ><<<BB*(NN/16),256,0,stream>>>(xcat, ws+o_wt5, ws+o_st5, (unsigned*)(ws+o_pmax), ws+o_psum);
  finalize_kernel<<<4,256,0,stream>>>(ws+o_st5, g5, b5, 1.f/(BB*NN), 1024, flagp);
  fc5_kernel<false><<<BB*(NN/16),256,0,stream>>>(xcat, ws+o_wt5, ws+o_st5, (unsigned*)(ws+o_pmax), ws+o_psum);
  pool_finalize_kernel<<<(BB*2048+255)/256,256,0,stream>>>((unsigned*)(ws+o_pmax), ws+o_psum, ws+o_pool);

  // ---- FC head
  fc6_kernel<<<512,256,0,stream>>>(ws+o_pool, w6, g6, b6, ws+o_y6, flagp);
  fc7_kernel<<<256,256,0,stream>>>(ws+o_y6, w7, bias7, g7, b7, ws+o_y7, flagp);
  fc8_kernel<<<40,256,0,stream>>>(ws+o_y7, w8, bias8, d_out, flagp);
}

// Round 5
// 1222.818 us; speedup vs baseline: 9.7028x; 1.9260x over previous
//
#include <hip/hip_runtime.h>
#include <hip/hip_bf16.h>

#define BB 8
#define NN 1024
#define KK 20
#define EPSB 1e-5f

typedef __hip_bfloat16 bf16;

__device__ __forceinline__ float lrelu(float t){ return t >= 0.f ? t : 0.2f*t; }
// dtype-flag-aware input load: flag=1 -> bf16, flag=0 -> fp32
__device__ __forceinline__ float ldin(const void* p, int i, int bf){
  return bf ? __bfloat162float(((const bf16*)p)[i]) : ((const float*)p)[i];
}
__device__ __forceinline__ unsigned f2u_ord(float f){
  unsigned u = __float_as_uint(f);
  return (u & 0x80000000u) ? ~u : (u | 0x80000000u);
}
__device__ __forceinline__ float u2f_ord(unsigned u){
  return (u & 0x80000000u) ? __uint_as_float(u & 0x7fffffffu) : __uint_as_float(~u);
}

// ---------------- dtype detection (fp32 words of N(0,1) data never have exp>=0xD0)
__global__ void detect_kernel(const unsigned* __restrict__ xw, int* __restrict__ flag){
  int t = threadIdx.x;
  unsigned w = xw[t];
  unsigned e = (w >> 23) & 0xFFu;
  unsigned long long m = __ballot(e >= 0xD0u);
  if (t == 0) *flag = (__popcll(m) >= 32) ? 1 : 0;
}

__global__ void zero_kernel(unsigned* __restrict__ p, int n){
  int i = blockIdx.x*256 + threadIdx.x;
  if (i < n) p[i] = 0u;
}

// ---------------- conv0: three 2->2 gated branches, single block (tiny)
__global__ __launch_bounds__(256) void conv0_kernel(
    const void* __restrict__ x,
    const void* __restrict__ w00, const void* __restrict__ g00, const void* __restrict__ b00,
    const void* __restrict__ w01, const void* __restrict__ g01, const void* __restrict__ b01,
    float* __restrict__ xc0, const int* __restrict__ flagp){
  __shared__ float sacc[12][256];
  __shared__ float sA[6], sC[6];
  const int bf = *flagp;
  int tid = threadIdx.x;
  float part[12];
#pragma unroll
  for (int j=0;j<12;j++) part[j]=0.f;
  float wz[4], wy[4];
#pragma unroll
  for (int j=0;j<4;j++){ wz[j]=ldin(w00,j,bf); wy[j]=ldin(w01,j,bf); }
  for (int i = tid; i < BB*NN; i += 256){
    int b = i / NN, n = i % NN;
    float x0 = ldin(x,(b*3+0)*NN + n,bf);
    float x1 = ldin(x,(b*3+1)*NN + n,bf);
    float x2 = ldin(x,(b*3+2)*NN + n,bf);
    float z0 = wz[0]*x0 + wz[1]*x1, z1 = wz[2]*x0 + wz[3]*x1;
    float y0 = wy[0]*x0 + wy[1]*x2, y1 = wy[2]*x0 + wy[3]*x2;
    float u0 = wy[0]*x1 + wy[1]*x2, u1 = wy[2]*x1 + wy[3]*x2;
    part[0]+=z0; part[1]+=z0*z0; part[2]+=z1; part[3]+=z1*z1;
    part[4]+=y0; part[5]+=y0*y0; part[6]+=y1; part[7]+=y1*y1;
    part[8]+=u0; part[9]+=u0*u0; part[10]+=u1; part[11]+=u1*u1;
  }
#pragma unroll
  for (int j=0;j<12;j++) sacc[j][tid]=part[j];
  __syncthreads();
  for (int s=128;s;s>>=1){
    if (tid<s){
#pragma unroll
      for (int j=0;j<12;j++) sacc[j][tid]+=sacc[j][tid+s];
    }
    __syncthreads();
  }
  if (tid < 6){
    float m = sacc[2*tid][0] * (1.f/(BB*NN));
    float v = sacc[2*tid+1][0] * (1.f/(BB*NN)) - m*m;
    float g, bv;
    if (tid<2){ g=ldin(g00,tid,bf); bv=ldin(b00,tid,bf); }
    else if (tid<4){ g=ldin(g01,tid-2,bf); bv=ldin(b01,tid-2,bf); }
    else { g=ldin(g01,tid-4,bf); bv=ldin(b01,tid-4,bf); }
    float a = g * rsqrtf(fmaxf(v,0.f) + EPSB);
    sA[tid]=a; sC[tid]=bv - m*a;
  }
  __syncthreads();
  for (int i = tid; i < BB*NN; i += 256){
    int b = i / NN, n = i % NN;
    float x0 = ldin(x,(b*3+0)*NN + n,bf);
    float x1 = ldin(x,(b*3+1)*NN + n,bf);
    float x2 = ldin(x,(b*3+2)*NN + n,bf);
    float z0 = wz[0]*x0 + wz[1]*x1, z1 = wz[2]*x0 + wz[3]*x1;
    float y0 = wy[0]*x0 + wy[1]*x2, y1 = wy[2]*x0 + wy[3]*x2;
    float u0 = wy[0]*x1 + wy[1]*x2, u1 = wy[2]*x1 + wy[3]*x2;
    float* row = xc0 + (size_t)i*16;
    row[0]=x0; row[1]=x1; row[2]=x2;
    row[3]=lrelu(sA[4]*u0+sC[4])*x0; row[4]=lrelu(sA[5]*u1+sC[5])*x0;
    row[5]=lrelu(sA[2]*y0+sC[2])*x1; row[6]=lrelu(sA[3]*y1+sC[3])*x1;
    row[7]=lrelu(sA[0]*z0+sC[0])*x2; row[8]=lrelu(sA[1]*z1+sC[1])*x2;
    row[9]=0.f; row[10]=0.f; row[11]=0.f; row[12]=0.f; row[13]=0.f; row[14]=0.f; row[15]=0.f;
  }
}

// ---------------- build WdT[c][o] = W[o][c], WcdT[c][o] = W[o][CIN+c]-W[o][c]; pad c<CINP
__global__ void wuv_kernel(const void* __restrict__ W, float* __restrict__ WdT,
                           float* __restrict__ WcdT, int CIN, int CINP, int COUT,
                           const int* __restrict__ flagp){
  int t = blockIdx.x*256 + threadIdx.x;
  if (t >= CINP*COUT) return;
  const int bf = *flagp;
  int c = t / COUT, o = t % COUT;
  if (c < CIN){
    float wd = ldin(W, o*(2*CIN)+c, bf);
    float wc = ldin(W, o*(2*CIN)+CIN+c, bf);
    WdT[t] = wd; WcdT[t] = wc - wd;
  } else {
    WdT[t] = 0.f; WcdT[t] = 0.f;
  }
}

// ---------------- transpose w5 (Cout,F) -> (F,Cout) fp32
__global__ void transpose_w_kernel(const void* __restrict__ W, float* __restrict__ WT,
                                   int Cout, int F, int PADF, const int* __restrict__ flagp){
  int t = blockIdx.x*256 + threadIdx.x;
  if (t >= PADF*Cout) return;
  const int bf = *flagp;
  int c = t / Cout, o = t % Cout;
  WT[t] = (c < F) ? ldin(W, o*F + c, bf) : 0.f;
}

// ---------------- per-point squared norm
__global__ void xx_kernel(const float* __restrict__ src, int ld, int coff, int CR,
                          float* __restrict__ xx){
  int i = blockIdx.x*256 + threadIdx.x;
  if (i >= BB*NN) return;
  const float* row = src + (size_t)i*ld + coff;
  float s = 0.f;
  for (int c=0;c<CR;c+=4){
    float4 f = *(const float4*)&row[c];
    s += f.x*f.x + f.y*f.y + f.z*f.z + f.w*f.w;
  }
  xx[i] = s;
}

// ---------------- negdist = 2*X.X^T - xx_i - xx_j, 64x64 tiles (fp32)
__global__ __launch_bounds__(256) void negdist_kernel(
    const float* __restrict__ src, int ld, int coff, int CR, int sw,
    const float* __restrict__ xx, float* __restrict__ negD){
  extern __shared__ float lds[];
  float* At = lds;
  float* Bt = lds + 64*CR;
  int b = blockIdx.z, i0 = blockIdx.y*64, j0 = blockIdx.x*64;
  int tid = threadIdx.x;
  int g4m = (CR>>2) - 1;
  for (int t = tid; t < 64*CR; t += 256){
    int r = t / CR, c = t % CR;
    int ci = sw ? (((((c>>2) ^ (r>>2)) & g4m)<<2) | (c&3)) : c;
    At[r*CR + ci] = src[((size_t)(b*NN + i0 + r))*ld + coff + c];
    Bt[r*CR + ci] = src[((size_t)(b*NN + j0 + r))*ld + coff + c];
  }
  __syncthreads();
  int ti = tid >> 4, tj = tid & 15;
  int ri = ti*4, rj = tj*4;
  float acc[4][4];
#pragma unroll
  for (int u=0;u<4;u++)
#pragma unroll
    for (int v=0;v<4;v++) acc[u][v]=0.f;
  for (int c=0;c<CR;c+=4){
    float4 av[4], bv[4];
#pragma unroll
    for (int u=0;u<4;u++){
      int ra = ri+u;
      int ca = sw ? ((((c>>2) ^ (ra>>2)) & g4m)<<2) : c;
      av[u] = *(const float4*)&At[ra*CR + ca];
      int rb = rj+u;
      int cb = sw ? ((((c>>2) ^ (rb>>2)) & g4m)<<2) : c;
      bv[u] = *(const float4*)&Bt[rb*CR + cb];
    }
#pragma unroll
    for (int u=0;u<4;u++)
#pragma unroll
      for (int v=0;v<4;v++)
        acc[u][v] += av[u].x*bv[v].x + av[u].y*bv[v].y + av[u].z*bv[v].z + av[u].w*bv[v].w;
  }
  float xi[4], xj[4];
#pragma unroll
  for (int u=0;u<4;u++){ xi[u]=xx[b*NN+i0+ri+u]; xj[u]=xx[b*NN+j0+rj+u]; }
#pragma unroll
  for (int u=0;u<4;u++){
    float4 ov;
    ov.x = 2.f*acc[u][0] - xi[u] - xj[0];
    ov.y = 2.f*acc[u][1] - xi[u] - xj[1];
    ov.z = 2.f*acc[u][2] - xi[u] - xj[2];
    ov.w = 2.f*acc[u][3] - xi[u] - xj[3];
    *(float4*)&negD[((size_t)(b*NN + i0 + ri + u))*NN + j0 + rj] = ov;
  }
}

// ---------------- top-20: one wave per row; registers + 64-lane butterfly argmax
__global__ __launch_bounds__(256) void topk_kernel(const float* __restrict__ negD,
                                                   int* __restrict__ idx){
  int row_id = (blockIdx.x*256 + threadIdx.x) >> 6;
  int lane = threadIdx.x & 63;
  if (row_id >= BB*NN) return;
  const float* row = negD + (size_t)row_id*NN;
  float v[16];
#pragma unroll
  for (int j=0;j<4;j++){
    float4 f = *(const float4*)&row[j*256 + lane*4];
    v[j*4+0]=f.x; v[j*4+1]=f.y; v[j*4+2]=f.z; v[j*4+3]=f.w;
  }
  int* orow = idx + (size_t)row_id*KK;
  for (int k=0;k<KK;k++){
    float bv = v[0]; int bs = 0;
#pragma unroll
    for (int s=1;s<16;s++){ if (v[s] > bv){ bv = v[s]; bs = s; } }
    int bidx = (bs>>2)*256 + lane*4 + (bs&3);
    unsigned long long key = ((unsigned long long)f2u_ord(bv) << 32) | (unsigned)(1023 - bidx);
#pragma unroll
    for (int off=32; off; off>>=1){
      unsigned long long o = __shfl_xor(key, off, 64);
      if (o > key) key = o;
    }
    int widx = 1023 - (int)(key & 0xFFFFFFFFu);
    if (lane == 0) orow[k] = widx;
    bool mine = (((widx >> 2) & 63) == lane);
    int wslot = ((widx >> 8) << 2) | (widx & 3);
#pragma unroll
    for (int s=0;s<16;s++){
      if (mine && s == wslot) v[s] = -1e30f;
    }
  }
}

// ---------------- u/v GEMM: ut[n][o]=Wd.x[n], vt[n][o]=(Wc-Wd).x[n]  (fp32 exact)
// PT=16 points/block; threads: o = tid%COUT, group handles PT*COUT/256 points.
template<int CINP,int COUT>
__global__ __launch_bounds__(256) void uvgemm_kernel(
    const float* __restrict__ srcT, int ld, int coff,
    const float* __restrict__ WdT, const float* __restrict__ WcdT,
    float* __restrict__ ut, float* __restrict__ vt){
  constexpr int PT=16, G = 256/COUT, NP = PT/G;
  __shared__ float xs[PT*CINP];
  int tid = threadIdx.x;
  int base = blockIdx.x*PT;                 // global point index
  for (int t=tid; t<PT*CINP; t+=256){
    int p = t / CINP, c = t % CINP;
    xs[t] = srcT[(size_t)(base+p)*ld + coff + c];
  }
  __syncthreads();
  int o = tid % COUT, grp = tid / COUT;
  float u[NP], v[NP];
#pragma unroll
  for (int pp=0;pp<NP;pp++){ u[pp]=0.f; v[pp]=0.f; }
  for (int c=0;c<CINP;c+=4){
    float wd0 = WdT[(c+0)*COUT+o], wc0 = WcdT[(c+0)*COUT+o];
    float wd1 = WdT[(c+1)*COUT+o], wc1 = WcdT[(c+1)*COUT+o];
    float wd2 = WdT[(c+2)*COUT+o], wc2 = WcdT[(c+2)*COUT+o];
    float wd3 = WdT[(c+3)*COUT+o], wc3 = WcdT[(c+3)*COUT+o];
#pragma unroll
    for (int pp=0;pp<NP;pp++){
      float4 xv = *(const float4*)&xs[(grp+pp*G)*CINP + c];
      u[pp] = fmaf(xv.x,wd0,fmaf(xv.y,wd1,fmaf(xv.z,wd2,fmaf(xv.w,wd3,u[pp]))));
      v[pp] = fmaf(xv.x,wc0,fmaf(xv.y,wc1,fmaf(xv.z,wc2,fmaf(xv.w,wc3,v[pp]))));
    }
  }
#pragma unroll
  for (int pp=0;pp<NP;pp++){
    int p = grp + pp*G;
    ut[(size_t)(base+p)*COUT + o] = u[pp];
    vt[(size_t)(base+p)*COUT + o] = v[pp];
  }
}

// ---------------- gather pass: h[n,k,o] = ut[m(n,k)][o] + vt[n][o]
// track hmax/hmin over k per (n,o); accumulate BN stats (sum h, sum h^2).
template<int COUT>
__global__ __launch_bounds__(256) void ebgather_kernel(
    const int* __restrict__ idx, const float* __restrict__ ut, const float* __restrict__ vt,
    float* __restrict__ hmaxb, float* __restrict__ hminb, float* __restrict__ stats){
  constexpr int CH = COUT/64, NPG = 4;
  int w = threadIdx.x >> 6, lane = threadIdx.x & 63;
  int n0 = (blockIdx.x*4 + w)*NPG;          // global point index
  float s1[CH], s2[CH];
#pragma unroll
  for (int ch=0;ch<CH;ch++){ s1[ch]=0.f; s2[ch]=0.f; }
  for (int pp=0;pp<NPG;pp++){
    int n = n0 + pp;
    int b = n >> 10;
    const int* irow = idx + (size_t)n*KK;
    float vr[CH], hx[CH], hn[CH];
#pragma unroll
    for (int ch=0;ch<CH;ch++){
      vr[ch] = vt[(size_t)n*COUT + ch*64 + lane];
      hx[ch] = -1e30f; hn[ch] = 1e30f;
    }
    for (int k=0;k<KK;k++){
      int m = irow[k];
      const float* urow = ut + (size_t)(b*NN + m)*COUT;
#pragma unroll
      for (int ch=0;ch<CH;ch++){
        float h = urow[ch*64+lane] + vr[ch];
        hx[ch] = fmaxf(hx[ch], h);
        hn[ch] = fminf(hn[ch], h);
        s1[ch] += h;
        s2[ch] = fmaf(h,h,s2[ch]);
      }
    }
#pragma unroll
    for (int ch=0;ch<CH;ch++){
      hmaxb[(size_t)n*COUT + ch*64 + lane] = hx[ch];
      hminb[(size_t)n*COUT + ch*64 + lane] = hn[ch];
    }
  }
#pragma unroll
  for (int ch=0;ch<CH;ch++){
    atomicAdd(&stats[ch*64+lane], s1[ch]);
    atomicAdd(&stats[COUT + ch*64+lane], s2[ch]);
  }
}

// ---------------- apply: out = lrelu(a*(a>=0?hmax:hmin)+c)  (max commutes thru monotone)
template<int COUT>
__global__ __launch_bounds__(256) void ebapply_kernel(
    const float* __restrict__ hmaxb, const float* __restrict__ hminb,
    const float* __restrict__ stats, float* __restrict__ outp, int outoff){
  int t = blockIdx.x*256 + threadIdx.x;
  if (t >= BB*NN*COUT) return;
  int n = t / COUT, o = t % COUT;
  float a = stats[o], c = stats[COUT+o];
  float h = (a >= 0.f) ? hmaxb[t] : hminb[t];
  outp[(size_t)n*512 + outoff + o] = lrelu(fmaf(a,h,c));
}

// ---------------- finalize BN stats -> (scale, shift) in place
__global__ void finalize_kernel(float* __restrict__ stats, const void* __restrict__ g,
                                const void* __restrict__ bb, float inv_count, int Cout,
                                const int* __restrict__ flagp){
  int o = blockIdx.x*256 + threadIdx.x;
  if (o >= Cout) return;
  const int bf = *flagp;
  float m = stats[o]*inv_count;
  float v = stats[Cout+o]*inv_count - m*m;
  float a = ldin(g,o,bf)*rsqrtf(fmaxf(v,0.f) + EPSB);
  stats[o] = a;
  stats[Cout+o] = ldin(bb,o,bf) - m*a;
}

// ---------------- conv5 (512->1024) GEMM fp32; stats pass / bn+lrelu+pool pass
template<bool STATS>
__global__ __launch_bounds__(256) void fc5_kernel(
    const float* __restrict__ xcat, const float* __restrict__ WT5,
    float* __restrict__ st5, unsigned* __restrict__ pmax, float* __restrict__ psum){
  constexpr int PT = 16;
  __shared__ float rows[PT*512];
  int tid = threadIdx.x;
  int b = blockIdx.x >> 6;
  int n0 = (blockIdx.x & 63) * PT;
  const float* src = xcat + ((size_t)(b*NN + n0))*512;
  for (int t=tid; t<PT*512; t+=256) rows[t] = src[t];
  __syncthreads();
  for (int ot=0; ot<1024; ot+=256){
    int o = ot + tid;
    float h[PT];
#pragma unroll
    for (int r=0;r<PT;r++) h[r]=0.f;
    for (int c=0;c<512;c+=4){
      float w0 = WT5[(size_t)(c+0)*1024+o];
      float w1 = WT5[(size_t)(c+1)*1024+o];
      float w2 = WT5[(size_t)(c+2)*1024+o];
      float w3 = WT5[(size_t)(c+3)*1024+o];
#pragma unroll
      for (int r=0;r<PT;r++){
        float4 f = *(const float4*)&rows[r*512+c];
        h[r] = fmaf(f.x,w0,fmaf(f.y,w1,fmaf(f.z,w2,fmaf(f.w,w3,h[r]))));
      }
    }
    if (STATS){
      float s1=0.f, s2=0.f;
#pragma unroll
      for (int r=0;r<PT;r++){ s1+=h[r]; s2=fmaf(h[r],h[r],s2); }
      atomicAdd(&st5[o], s1);
      atomicAdd(&st5[1024+o], s2);
    } else {
      float a = st5[o], cc = st5[1024+o];
      float mx=-1e30f, sm=0.f;
#pragma unroll
      for (int r=0;r<PT;r++){
        float t = lrelu(fmaf(a,h[r],cc));
        mx = fmaxf(mx, t); sm += t;
      }
      atomicMax(&pmax[b*1024+o], f2u_ord(mx));
      atomicAdd(&psum[b*1024+o], sm);
    }
  }
}

__global__ void pool_finalize_kernel(const unsigned* __restrict__ pmax,
                                     const float* __restrict__ psum,
                                     float* __restrict__ pooled){
  int t = blockIdx.x*256+threadIdx.x;
  if (t >= BB*2048) return;
  int b = t >> 11, j = t & 2047;
  pooled[t] = (j < 1024) ? u2f_ord(pmax[b*1024+j]) : psum[b*1024 + (j-1024)] * (1.f/1024.f);
}

// ---------------- FC head
__global__ __launch_bounds__(256) void fc6_kernel(
    const float* __restrict__ pooled, const void* __restrict__ W,
    const void* __restrict__ g, const void* __restrict__ bb, float* __restrict__ y6,
    const int* __restrict__ flagp){
  __shared__ float red[8][256];
  int o = blockIdx.x, tid = threadIdx.x;
  const int bf = *flagp;
  float part[8];
#pragma unroll
  for (int b=0;b<8;b++) part[b]=0.f;
  for (int c=tid;c<2048;c+=256){
    float wv = ldin(W,o*2048+c,bf);
#pragma unroll
    for (int b=0;b<8;b++) part[b] = fmaf(pooled[b*2048+c], wv, part[b]);
  }
#pragma unroll
  for (int b=0;b<8;b++) red[b][tid]=part[b];
  __syncthreads();
  for (int s=128;s;s>>=1){
    if (tid<s){
#pragma unroll
      for (int b=0;b<8;b++) red[b][tid]+=red[b][tid+s];
    }
    __syncthreads();
  }
  if (tid==0){
    float y[8], m=0.f;
#pragma unroll
    for (int b=0;b<8;b++){ y[b]=red[b][0]; m+=y[b]; }
    m *= 0.125f;
    float v=0.f;
#pragma unroll
    for (int b=0;b<8;b++){ float d=y[b]-m; v += d*d; }
    v *= 0.125f;
    float a=ldin(g,o,bf)*rsqrtf(fmaxf(v,0.f)+EPSB), c0=ldin(bb,o,bf)-m*a;
#pragma unroll
    for (int b=0;b<8;b++) y6[b*512+o]=lrelu(fmaf(a,y[b],c0));
  }
}

__global__ __launch_bounds__(256) void fc7_kernel(
    const float* __restrict__ y6, const void* __restrict__ W, const void* __restrict__ bias,
    const void* __restrict__ g, const void* __restrict__ bb, float* __restrict__ y7,
    const int* __restrict__ flagp){
  __shared__ float red[8][256];
  int o = blockIdx.x, tid = threadIdx.x;
  const int bf = *flagp;
  float part[8];
#pragma unroll
  for (int b=0;b<8;b++) part[b]=0.f;
  for (int c=tid;c<512;c+=256){
    float wv = ldin(W,o*512+c,bf);
#pragma unroll
    for (int b=0;b<8;b++) part[b] = fmaf(y6[b*512+c], wv, part[b]);
  }
#pragma unroll
  for (int b=0;b<8;b++) red[b][tid]=part[b];
  __syncthreads();
  for (int s=128;s;s>>=1){
    if (tid<s){
#pragma unroll
      for (int b=0;b<8;b++) red[b][tid]+=red[b][tid+s];
    }
    __syncthreads();
  }
  if (tid==0){
    float bs = ldin(bias,o,bf);
    float y[8], m=0.f;
#pragma unroll
    for (int b=0;b<8;b++){ y[b]=red[b][0]+bs; m+=y[b]; }
    m *= 0.125f;
    float v=0.f;
#pragma unroll
    for (int b=0;b<8;b++){ float d=y[b]-m; v += d*d; }
    v *= 0.125f;
    float a=ldin(g,o,bf)*rsqrtf(fmaxf(v,0.f)+EPSB), c0=ldin(bb,o,bf)-m*a;
#pragma unroll
    for (int b=0;b<8;b++) y7[b*256+o]=lrelu(fmaf(a,y[b],c0));
  }
}

__global__ __launch_bounds__(256) void fc8_kernel(
    const float* __restrict__ y7, const void* __restrict__ W, const void* __restrict__ bias,
    void* __restrict__ out, const int* __restrict__ flagp){
  __shared__ float red[8][256];
  int o = blockIdx.x, tid = threadIdx.x;
  const int bf = *flagp;
  float wv = ldin(W,o*256+tid,bf);
#pragma unroll
  for (int b=0;b<8;b++) red[b][tid] = y7[b*256+tid]*wv;
  __syncthreads();
  for (int s=128;s;s>>=1){
    if (tid<s){
#pragma unroll
      for (int b=0;b<8;b++) red[b][tid]+=red[b][tid+s];
    }
    __syncthreads();
  }
  if (tid==0){
    float bs = ldin(bias,o,bf);
#pragma unroll
    for (int b=0;b<8;b++){
      float r = red[b][0]+bs;
      if (bf) ((bf16*)out)[b*40+o] = __float2bfloat16(r);
      else    ((float*)out)[b*40+o] = r;
    }
  }
}

extern "C" void kernel_launch(void* const* d_in, const int* in_sizes, int n_in,
                              void* d_out, int out_size, void* d_ws, size_t ws_size,
                              hipStream_t stream){
  const void* x    = d_in[0];
  const void* w00  = d_in[1];
  const void* g00  = d_in[2];
  const void* b00  = d_in[3];
  const void* w01  = d_in[4];
  const void* g01  = d_in[5];
  const void* b01  = d_in[6];
  const void* w1   = d_in[7];  const void* g1 = d_in[8];  const void* b1 = d_in[9];
  const void* w2   = d_in[10]; const void* g2 = d_in[11]; const void* b2 = d_in[12];
  const void* w3   = d_in[13]; const void* g3 = d_in[14]; const void* b3 = d_in[15];
  const void* w4   = d_in[16]; const void* g4 = d_in[17]; const void* b4 = d_in[18];
  const void* w5   = d_in[19]; const void* g5 = d_in[20]; const void* b5 = d_in[21];
  const void* w6   = d_in[22]; const void* g6 = d_in[23]; const void* b6 = d_in[24];
  const void* w7   = d_in[25]; const void* bias7 = d_in[26];
  const void* g7   = d_in[27]; const void* b7 = d_in[28];
  const void* w8   = d_in[29]; const void* bias8 = d_in[30];

  float* ws = (float*)d_ws;
  // workspace layout (float offsets)
  size_t o_xc0  = 0;                              // B*N*16
  size_t o_xcat = o_xc0  + (size_t)BB*NN*16;      // B*N*512
  size_t o_negd = o_xcat + (size_t)BB*NN*512;     // B*N*N (also u/v/hmax/hmin after topk)
  size_t o_xx   = o_negd + (size_t)BB*NN*NN;      // B*N
  size_t o_w1d  = o_xx   + (size_t)BB*NN;         // 12*64
  size_t o_w1c  = o_w1d  + 12*64;
  size_t o_w2d  = o_w1c  + 12*64;                 // 64*64
  size_t o_w2c  = o_w2d  + 64*64;
  size_t o_w3d  = o_w2c  + 64*64;                 // 64*128
  size_t o_w3c  = o_w3d  + 64*128;
  size_t o_w4d  = o_w3c  + 64*128;                // 128*256
  size_t o_w4c  = o_w4d  + 128*256;
  size_t o_wt5  = o_w4c  + 128*256;               // 512*1024
  size_t o_st1  = o_wt5  + (size_t)512*1024;      // 128
  size_t o_st2  = o_st1  + 128;                   // 128
  size_t o_st3  = o_st2  + 128;                   // 256
  size_t o_st4  = o_st3  + 256;                   // 512
  size_t o_st5  = o_st4  + 512;                   // 2048
  size_t o_pmax = o_st5  + 2048;                  // 8*1024 (uint)
  size_t o_psum = o_pmax + 8192;                  // 8*1024
  size_t o_pool = o_psum + 8192;                  // 8*2048
  size_t o_y6   = o_pool + 16384;                 // 8*512
  size_t o_y7   = o_y6   + 4096;                  // 8*256
  size_t o_idx  = o_y7   + 2048;                  // B*N*20 ints
  size_t o_flag = o_idx  + (size_t)BB*NN*KK;      // 1 int

  // u/v/hmax/hmin overlay the (dead-after-topk) negD region: 4 * B*N*256 == B*N*N
  size_t o_u    = o_negd;
  size_t o_v    = o_negd + (size_t)BB*NN*256;
  size_t o_hmax = o_negd + (size_t)2*BB*NN*256;
  size_t o_hmin = o_negd + (size_t)3*BB*NN*256;

  int* idxp = (int*)(ws + o_idx);
  int* flagp = (int*)(ws + o_flag);
  float* negD = ws + o_negd;
  float* xxp  = ws + o_xx;
  float* xc0  = ws + o_xc0;
  float* xcat = ws + o_xcat;
  float* up   = ws + o_u;
  float* vp   = ws + o_v;
  float* hxp  = ws + o_hmax;
  float* hnp  = ws + o_hmin;

  detect_kernel<<<1,64,0,stream>>>((const unsigned*)x, flagp);

  int nz = 128+128+256+512+2048+8192+8192;
  zero_kernel<<<(nz+255)/256, 256, 0, stream>>>((unsigned*)(ws + o_st1), nz);

  conv0_kernel<<<1,256,0,stream>>>(x, w00,g00,b00, w01,g01,b01, xc0, flagp);

  wuv_kernel<<<(12*64+255)/256,  256,0,stream>>>(w1, ws+o_w1d, ws+o_w1c,   9,  12,  64, flagp);
  wuv_kernel<<<(64*64+255)/256,  256,0,stream>>>(w2, ws+o_w2d, ws+o_w2c,  64,  64,  64, flagp);
  wuv_kernel<<<(64*128+255)/256, 256,0,stream>>>(w3, ws+o_w3d, ws+o_w3c,  64,  64, 128, flagp);
  wuv_kernel<<<(128*256+255)/256,256,0,stream>>>(w4, ws+o_w4d, ws+o_w4c, 128, 128, 256, flagp);
  transpose_w_kernel<<<(512*1024+255)/256,256,0,stream>>>(w5, ws+o_wt5, 1024, 512, 512, flagp);

  dim3 ndgrid(NN/64, NN/64, BB);
  const int UVG = BB*NN/16;    // 512 blocks
  const int GG  = BB*NN/16;    // 512 blocks (4 waves x 4 points)

  // ---- edge block 1: src=xc0 (ld16, C=9), Cout=64 -> xcat[:,0:64)
  xx_kernel<<<32,256,0,stream>>>(xc0, 16, 0, 12, xxp);
  negdist_kernel<<<ndgrid,256, 2*64*12*4, stream>>>(xc0, 16, 0, 12, 0, xxp, negD);
  topk_kernel<<<BB*NN/4,256,0,stream>>>(negD, idxp);
  uvgemm_kernel<12,64><<<UVG,256,0,stream>>>(xc0, 16, 0, ws+o_w1d, ws+o_w1c, up, vp);
  ebgather_kernel<64><<<GG,256,0,stream>>>(idxp, up, vp, hxp, hnp, ws+o_st1);
  finalize_kernel<<<1,256,0,stream>>>(ws+o_st1, g1, b1, 1.f/(BB*NN*KK), 64, flagp);
  ebapply_kernel<64><<<BB*NN*64/256,256,0,stream>>>(hxp, hnp, ws+o_st1, xcat, 0);

  // ---- edge block 2: src=x1, Cout=64 -> xcat[:,64:128)
  xx_kernel<<<32,256,0,stream>>>(xcat, 512, 0, 64, xxp);
  negdist_kernel<<<ndgrid,256, 2*64*64*4, stream>>>(xcat, 512, 0, 64, 1, xxp, negD);
  topk_kernel<<<BB*NN/4,256,0,stream>>>(negD, idxp);
  uvgemm_kernel<64,64><<<UVG,256,0,stream>>>(xcat, 512, 0, ws+o_w2d, ws+o_w2c, up, vp);
  ebgather_kernel<64><<<GG,256,0,stream>>>(idxp, up, vp, hxp, hnp, ws+o_st2);
  finalize_kernel<<<1,256,0,stream>>>(ws+o_st2, g2, b2, 1.f/(BB*NN*KK), 64, flagp);
  ebapply_kernel<64><<<BB*NN*64/256,256,0,stream>>>(hxp, hnp, ws+o_st2, xcat, 64);

  // ---- edge block 3: src=x2, Cout=128 -> xcat[:,128:256)
  xx_kernel<<<32,256,0,stream>>>(xcat, 512, 64, 64, xxp);
  negdist_kernel<<<ndgrid,256, 2*64*64*4, stream>>>(xcat, 512, 64, 64, 1, xxp, negD);
  topk_kernel<<<BB*NN/4,256,0,stream>>>(negD, idxp);
  uvgemm_kernel<64,128><<<UVG,256,0,stream>>>(xcat, 512, 64, ws+o_w3d, ws+o_w3c, up, vp);
  ebgather_kernel<128><<<GG,256,0,stream>>>(idxp, up, vp, hxp, hnp, ws+o_st3);
  finalize_kernel<<<1,256,0,stream>>>(ws+o_st3, g3, b3, 1.f/(BB*NN*KK), 128, flagp);
  ebapply_kernel<128><<<BB*NN*128/256,256,0,stream>>>(hxp, hnp, ws+o_st3, xcat, 128);

  // ---- edge block 4: src=x3, Cout=256 -> xcat[:,256:512)
  xx_kernel<<<32,256,0,stream>>>(xcat, 512, 128, 128, xxp);
  negdist_kernel<<<ndgrid,256, 2*64*128*4, stream>>>(xcat, 512, 128, 128, 1, xxp, negD);
  topk_kernel<<<BB*NN/4,256,0,stream>>>(negD, idxp);
  uvgemm_kernel<128,256><<<UVG,256,0,stream>>>(xcat, 512, 128, ws+o_w4d, ws+o_w4c, up, vp);
  ebgather_kernel<256><<<GG,256,0,stream>>>(idxp, up, vp, hxp, hnp, ws+o_st4);
  finalize_kernel<<<1,256,0,stream>>>(ws+o_st4, g4, b4, 1.f/(BB*NN*KK), 256, flagp);
  ebapply_kernel<256><<<BB*NN*256/256,256,0,stream>>>(hxp, hnp, ws+o_st4, xcat, 256);

  // ---- conv5 (512 -> 1024) + BN + lrelu + global max/mean pool
  fc5_kernel<true ><<<BB*(NN/16),256,0,stream>>>(xcat, ws+o_wt5, ws+o_st5, (unsigned*)(ws+o_pmax), ws+o_psum);
  finalize_kernel<<<4,256,0,stream>>>(ws+o_st5, g5, b5, 1.f/(BB*NN), 1024, flagp);
  fc5_kernel<false><<<BB*(NN/16),256,0,stream>>>(xcat, ws+o_wt5, ws+o_st5, (unsigned*)(ws+o_pmax), ws+o_psum);
  pool_finalize_kernel<<<(BB*2048+255)/256,256,0,stream>>>((unsigned*)(ws+o_pmax), ws+o_psum, ws+o_pool);

  // ---- FC head
  fc6_kernel<<<512,256,0,stream>>>(ws+o_pool, w6, g6, b6, ws+o_y6, flagp);
  fc7_kernel<<<256,256,0,stream>>>(ws+o_y6, w7, bias7, g7, b7, ws+o_y7, flagp);
  fc8_kernel<<<40,256,0,stream>>>(ws+o_y7, w8, bias8, d_out, flagp);
}

// Round 6
// 903.150 us; speedup vs baseline: 13.1371x; 1.3539x over previous
//
#include <hip/hip_runtime.h>
#include <hip/hip_bf16.h>

#define BB 8
#define NN 1024
#define KK 20
#define EPSB 1e-5f

typedef __hip_bfloat16 bf16;
typedef __attribute__((ext_vector_type(8))) short sbf8;   // 8 bf16 = 4 VGPRs
typedef __attribute__((ext_vector_type(4))) float f32x4;

__device__ __forceinline__ float lrelu(float t){ return t >= 0.f ? t : 0.2f*t; }
// dtype-flag-aware input load: flag=1 -> bf16, flag=0 -> fp32
__device__ __forceinline__ float ldin(const void* p, int i, int bf){
  return bf ? __bfloat162float(((const bf16*)p)[i]) : ((const float*)p)[i];
}
__device__ __forceinline__ unsigned short f2bf(float f){   // RNE fp32->bf16 bits
  unsigned u = __float_as_uint(f);
  return (unsigned short)((u + 0x7FFFu + ((u>>16)&1u)) >> 16);
}
__device__ __forceinline__ unsigned f2u_ord(float f){
  unsigned u = __float_as_uint(f);
  return (u & 0x80000000u) ? ~u : (u | 0x80000000u);
}
__device__ __forceinline__ float u2f_ord(unsigned u){
  return (u & 0x80000000u) ? __uint_as_float(u & 0x7fffffffu) : __uint_as_float(~u);
}

// ---------------- dtype detection (fp32 words of N(0,1) data never have exp>=0xD0)
__global__ void detect_kernel(const unsigned* __restrict__ xw, int* __restrict__ flag){
  int t = threadIdx.x;
  unsigned w = xw[t];
  unsigned e = (w >> 23) & 0xFFu;
  unsigned long long m = __ballot(e >= 0xD0u);
  if (t == 0) *flag = (__popcll(m) >= 32) ? 1 : 0;
}

__global__ void zero_kernel(unsigned* __restrict__ p, int n){
  int i = blockIdx.x*256 + threadIdx.x;
  if (i < n) p[i] = 0u;
}

// ---------------- conv0: three 2->2 gated branches, single block (tiny)
__global__ __launch_bounds__(256) void conv0_kernel(
    const void* __restrict__ x,
    const void* __restrict__ w00, const void* __restrict__ g00, const void* __restrict__ b00,
    const void* __restrict__ w01, const void* __restrict__ g01, const void* __restrict__ b01,
    float* __restrict__ xc0, const int* __restrict__ flagp){
  __shared__ float sacc[12][256];
  __shared__ float sA[6], sC[6];
  const int bf = *flagp;
  int tid = threadIdx.x;
  float part[12];
#pragma unroll
  for (int j=0;j<12;j++) part[j]=0.f;
  float wz[4], wy[4];
#pragma unroll
  for (int j=0;j<4;j++){ wz[j]=ldin(w00,j,bf); wy[j]=ldin(w01,j,bf); }
  for (int i = tid; i < BB*NN; i += 256){
    int b = i / NN, n = i % NN;
    float x0 = ldin(x,(b*3+0)*NN + n,bf);
    float x1 = ldin(x,(b*3+1)*NN + n,bf);
    float x2 = ldin(x,(b*3+2)*NN + n,bf);
    float z0 = wz[0]*x0 + wz[1]*x1, z1 = wz[2]*x0 + wz[3]*x1;
    float y0 = wy[0]*x0 + wy[1]*x2, y1 = wy[2]*x0 + wy[3]*x2;
    float u0 = wy[0]*x1 + wy[1]*x2, u1 = wy[2]*x1 + wy[3]*x2;
    part[0]+=z0; part[1]+=z0*z0; part[2]+=z1; part[3]+=z1*z1;
    part[4]+=y0; part[5]+=y0*y0; part[6]+=y1; part[7]+=y1*y1;
    part[8]+=u0; part[9]+=u0*u0; part[10]+=u1; part[11]+=u1*u1;
  }
#pragma unroll
  for (int j=0;j<12;j++) sacc[j][tid]=part[j];
  __syncthreads();
  for (int s=128;s;s>>=1){
    if (tid<s){
#pragma unroll
      for (int j=0;j<12;j++) sacc[j][tid]+=sacc[j][tid+s];
    }
    __syncthreads();
  }
  if (tid < 6){
    float m = sacc[2*tid][0] * (1.f/(BB*NN));
    float v = sacc[2*tid+1][0] * (1.f/(BB*NN)) - m*m;
    float g, bv;
    if (tid<2){ g=ldin(g00,tid,bf); bv=ldin(b00,tid,bf); }
    else if (tid<4){ g=ldin(g01,tid-2,bf); bv=ldin(b01,tid-2,bf); }
    else { g=ldin(g01,tid-4,bf); bv=ldin(b01,tid-4,bf); }
    float a = g * rsqrtf(fmaxf(v,0.f) + EPSB);
    sA[tid]=a; sC[tid]=bv - m*a;
  }
  __syncthreads();
  for (int i = tid; i < BB*NN; i += 256){
    int b = i / NN, n = i % NN;
    float x0 = ldin(x,(b*3+0)*NN + n,bf);
    float x1 = ldin(x,(b*3+1)*NN + n,bf);
    float x2 = ldin(x,(b*3+2)*NN + n,bf);
    float z0 = wz[0]*x0 + wz[1]*x1, z1 = wz[2]*x0 + wz[3]*x1;
    float y0 = wy[0]*x0 + wy[1]*x2, y1 = wy[2]*x0 + wy[3]*x2;
    float u0 = wy[0]*x1 + wy[1]*x2, u1 = wy[2]*x1 + wy[3]*x2;
    float* row = xc0 + (size_t)i*16;
    row[0]=x0; row[1]=x1; row[2]=x2;
    row[3]=lrelu(sA[4]*u0+sC[4])*x0; row[4]=lrelu(sA[5]*u1+sC[5])*x0;
    row[5]=lrelu(sA[2]*y0+sC[2])*x1; row[6]=lrelu(sA[3]*y1+sC[3])*x1;
    row[7]=lrelu(sA[0]*z0+sC[0])*x2; row[8]=lrelu(sA[1]*z1+sC[1])*x2;
    row[9]=0.f; row[10]=0.f; row[11]=0.f; row[12]=0.f; row[13]=0.f; row[14]=0.f; row[15]=0.f;
  }
}

// ---------------- build WdT[c][o] = W[o][c], WcdT[c][o] = W[o][CIN+c]-W[o][c]; pad c<CINP
__global__ void wuv_kernel(const void* __restrict__ W, float* __restrict__ WdT,
                           float* __restrict__ WcdT, int CIN, int CINP, int COUT,
                           const int* __restrict__ flagp){
  int t = blockIdx.x*256 + threadIdx.x;
  if (t >= CINP*COUT) return;
  const int bf = *flagp;
  int c = t / COUT, o = t % COUT;
  if (c < CIN){
    float wd = ldin(W, o*(2*CIN)+c, bf);
    float wc = ldin(W, o*(2*CIN)+CIN+c, bf);
    WdT[t] = wd; WcdT[t] = wc - wd;
  } else {
    WdT[t] = 0.f; WcdT[t] = 0.f;
  }
}

// ---------------- pack w5 (1024,512) -> bf16 same layout [o][c]
__global__ void wb5prep_kernel(const void* __restrict__ W, unsigned short* __restrict__ wb,
                               const int* __restrict__ flagp){
  int t = blockIdx.x*256 + threadIdx.x;
  if (t >= 1024*512) return;
  wb[t] = f2bf(ldin(W, t, *flagp));
}

// ---------------- per-point squared norm
__global__ void xx_kernel(const float* __restrict__ src, int ld, int coff, int CR,
                          float* __restrict__ xx){
  int i = blockIdx.x*256 + threadIdx.x;
  if (i >= BB*NN) return;
  const float* row = src + (size_t)i*ld + coff;
  float s = 0.f;
  for (int c=0;c<CR;c+=4){
    float4 f = *(const float4*)&row[c];
    s += f.x*f.x + f.y*f.y + f.z*f.z + f.w*f.w;
  }
  xx[i] = s;
}

// ---------------- negdist = 2*X.X^T - xx_i - xx_j, 64x64 tiles (fp32)
__global__ __launch_bounds__(256) void negdist_kernel(
    const float* __restrict__ src, int ld, int coff, int CR, int sw,
    const float* __restrict__ xx, float* __restrict__ negD){
  extern __shared__ float lds[];
  float* At = lds;
  float* Bt = lds + 64*CR;
  int b = blockIdx.z, i0 = blockIdx.y*64, j0 = blockIdx.x*64;
  int tid = threadIdx.x;
  int g4m = (CR>>2) - 1;
  for (int t = tid; t < 64*CR; t += 256){
    int r = t / CR, c = t % CR;
    int ci = sw ? (((((c>>2) ^ (r>>2)) & g4m)<<2) | (c&3)) : c;
    At[r*CR + ci] = src[((size_t)(b*NN + i0 + r))*ld + coff + c];
    Bt[r*CR + ci] = src[((size_t)(b*NN + j0 + r))*ld + coff + c];
  }
  __syncthreads();
  int ti = tid >> 4, tj = tid & 15;
  int ri = ti*4, rj = tj*4;
  float acc[4][4];
#pragma unroll
  for (int u=0;u<4;u++)
#pragma unroll
    for (int v=0;v<4;v++) acc[u][v]=0.f;
  for (int c=0;c<CR;c+=4){
    float4 av[4], bv[4];
#pragma unroll
    for (int u=0;u<4;u++){
      int ra = ri+u;
      int ca = sw ? ((((c>>2) ^ (ra>>2)) & g4m)<<2) : c;
      av[u] = *(const float4*)&At[ra*CR + ca];
      int rb = rj+u;
      int cb = sw ? ((((c>>2) ^ (rb>>2)) & g4m)<<2) : c;
      bv[u] = *(const float4*)&Bt[rb*CR + cb];
    }
#pragma unroll
    for (int u=0;u<4;u++)
#pragma unroll
      for (int v=0;v<4;v++)
        acc[u][v] += av[u].x*bv[v].x + av[u].y*bv[v].y + av[u].z*bv[v].z + av[u].w*bv[v].w;
  }
  float xi[4], xj[4];
#pragma unroll
  for (int u=0;u<4;u++){ xi[u]=xx[b*NN+i0+ri+u]; xj[u]=xx[b*NN+j0+rj+u]; }
#pragma unroll
  for (int u=0;u<4;u++){
    float4 ov;
    ov.x = 2.f*acc[u][0] - xi[u] - xj[0];
    ov.y = 2.f*acc[u][1] - xi[u] - xj[1];
    ov.z = 2.f*acc[u][2] - xi[u] - xj[2];
    ov.w = 2.f*acc[u][3] - xi[u] - xj[3];
    *(float4*)&negD[((size_t)(b*NN + i0 + ri + u))*NN + j0 + rj] = ov;
  }
}

// ---------------- top-20: one wave per row; registers + 64-lane butterfly argmax
__global__ __launch_bounds__(256) void topk_kernel(const float* __restrict__ negD,
                                                   int* __restrict__ idx){
  int row_id = (blockIdx.x*256 + threadIdx.x) >> 6;
  int lane = threadIdx.x & 63;
  if (row_id >= BB*NN) return;
  const float* row = negD + (size_t)row_id*NN;
  float v[16];
#pragma unroll
  for (int j=0;j<4;j++){
    float4 f = *(const float4*)&row[j*256 + lane*4];
    v[j*4+0]=f.x; v[j*4+1]=f.y; v[j*4+2]=f.z; v[j*4+3]=f.w;
  }
  int* orow = idx + (size_t)row_id*KK;
  for (int k=0;k<KK;k++){
    float bv = v[0]; int bs = 0;
#pragma unroll
    for (int s=1;s<16;s++){ if (v[s] > bv){ bv = v[s]; bs = s; } }
    int bidx = (bs>>2)*256 + lane*4 + (bs&3);
    unsigned long long key = ((unsigned long long)f2u_ord(bv) << 32) | (unsigned)(1023 - bidx);
#pragma unroll
    for (int off=32; off; off>>=1){
      unsigned long long o = __shfl_xor(key, off, 64);
      if (o > key) key = o;
    }
    int widx = 1023 - (int)(key & 0xFFFFFFFFu);
    if (lane == 0) orow[k] = widx;
    bool mine = (((widx >> 2) & 63) == lane);
    int wslot = ((widx >> 8) << 2) | (widx & 3);
#pragma unroll
    for (int s=0;s<16;s++){
      if (mine && s == wslot) v[s] = -1e30f;
    }
  }
}

// ---------------- u/v GEMM: ut[n][o]=Wd.x[n], vt[n][o]=(Wc-Wd).x[n]  (fp32 exact)
template<int CINP,int COUT>
__global__ __launch_bounds__(256) void uvgemm_kernel(
    const float* __restrict__ srcT, int ld, int coff,
    const float* __restrict__ WdT, const float* __restrict__ WcdT,
    float* __restrict__ ut, float* __restrict__ vt){
  constexpr int PT=16, G = 256/COUT, NP = PT/G;
  __shared__ float xs[PT*CINP];
  int tid = threadIdx.x;
  int base = blockIdx.x*PT;                 // global point index
  for (int t=tid; t<PT*CINP; t+=256){
    int p = t / CINP, c = t % CINP;
    xs[t] = srcT[(size_t)(base+p)*ld + coff + c];
  }
  __syncthreads();
  int o = tid % COUT, grp = tid / COUT;
  float u[NP], v[NP];
#pragma unroll
  for (int pp=0;pp<NP;pp++){ u[pp]=0.f; v[pp]=0.f; }
  for (int c=0;c<CINP;c+=4){
    float wd0 = WdT[(c+0)*COUT+o], wc0 = WcdT[(c+0)*COUT+o];
    float wd1 = WdT[(c+1)*COUT+o], wc1 = WcdT[(c+1)*COUT+o];
    float wd2 = WdT[(c+2)*COUT+o], wc2 = WcdT[(c+2)*COUT+o];
    float wd3 = WdT[(c+3)*COUT+o], wc3 = WcdT[(c+3)*COUT+o];
#pragma unroll
    for (int pp=0;pp<NP;pp++){
      float4 xv = *(const float4*)&xs[(grp+pp*G)*CINP + c];
      u[pp] = fmaf(xv.x,wd0,fmaf(xv.y,wd1,fmaf(xv.z,wd2,fmaf(xv.w,wd3,u[pp]))));
      v[pp] = fmaf(xv.x,wc0,fmaf(xv.y,wc1,fmaf(xv.z,wc2,fmaf(xv.w,wc3,v[pp]))));
    }
  }
#pragma unroll
  for (int pp=0;pp<NP;pp++){
    int p = grp + pp*G;
    ut[(size_t)(base+p)*COUT + o] = u[pp];
    vt[(size_t)(base+p)*COUT + o] = v[pp];
  }
}

// ---------------- gather pass: h[n,k,o] = ut[m(n,k)][o] + vt[n][o]
template<int COUT>
__global__ __launch_bounds__(256) void ebgather_kernel(
    const int* __restrict__ idx, const float* __restrict__ ut, const float* __restrict__ vt,
    float* __restrict__ hmaxb, float* __restrict__ hminb, float* __restrict__ stats){
  constexpr int CH = COUT/64, NPG = 4;
  int w = threadIdx.x >> 6, lane = threadIdx.x & 63;
  int n0 = (blockIdx.x*4 + w)*NPG;          // global point index
  float s1[CH], s2[CH];
#pragma unroll
  for (int ch=0;ch<CH;ch++){ s1[ch]=0.f; s2[ch]=0.f; }
  for (int pp=0;pp<NPG;pp++){
    int n = n0 + pp;
    int b = n >> 10;
    const int* irow = idx + (size_t)n*KK;
    float vr[CH], hx[CH], hn[CH];
#pragma unroll
    for (int ch=0;ch<CH;ch++){
      vr[ch] = vt[(size_t)n*COUT + ch*64 + lane];
      hx[ch] = -1e30f; hn[ch] = 1e30f;
    }
    for (int k=0;k<KK;k++){
      int m = irow[k];
      const float* urow = ut + (size_t)(b*NN + m)*COUT;
#pragma unroll
      for (int ch=0;ch<CH;ch++){
        float h = urow[ch*64+lane] + vr[ch];
        hx[ch] = fmaxf(hx[ch], h);
        hn[ch] = fminf(hn[ch], h);
        s1[ch] += h;
        s2[ch] = fmaf(h,h,s2[ch]);
      }
    }
#pragma unroll
    for (int ch=0;ch<CH;ch++){
      hmaxb[(size_t)n*COUT + ch*64 + lane] = hx[ch];
      hminb[(size_t)n*COUT + ch*64 + lane] = hn[ch];
    }
  }
#pragma unroll
  for (int ch=0;ch<CH;ch++){
    atomicAdd(&stats[ch*64+lane], s1[ch]);
    atomicAdd(&stats[COUT + ch*64+lane], s2[ch]);
  }
}

// ---------------- apply: out = lrelu(a*(a>=0?hmax:hmin)+c)
template<int COUT>
__global__ __launch_bounds__(256) void ebapply_kernel(
    const float* __restrict__ hmaxb, const float* __restrict__ hminb,
    const float* __restrict__ stats, float* __restrict__ outp, int outoff){
  int t = blockIdx.x*256 + threadIdx.x;
  if (t >= BB*NN*COUT) return;
  int n = t / COUT, o = t % COUT;
  float a = stats[o], c = stats[COUT+o];
  float h = (a >= 0.f) ? hmaxb[t] : hminb[t];
  outp[(size_t)n*512 + outoff + o] = lrelu(fmaf(a,h,c));
}

// ---------------- finalize BN stats -> (scale, shift) in place
__global__ void finalize_kernel(float* __restrict__ stats, const void* __restrict__ g,
                                const void* __restrict__ bb, float inv_count, int Cout,
                                const int* __restrict__ flagp){
  int o = blockIdx.x*256 + threadIdx.x;
  if (o >= Cout) return;
  const int bf = *flagp;
  float m = stats[o]*inv_count;
  float v = stats[Cout+o]*inv_count - m*m;
  float a = ldin(g,o,bf)*rsqrtf(fmaxf(v,0.f) + EPSB);
  stats[o] = a;
  stats[Cout+o] = ldin(bb,o,bf) - m*a;
}

// ---------------- conv5 via MFMA bf16: single pass, writes h fp32 [B*N][1024] + BN stats.
// Block: 16 points, 4 waves x 256 channels. A staged bf16 LDS w/ XOR-swizzled 16B groups.
__global__ __launch_bounds__(256) void fc5_mfma(
    const float* __restrict__ xcat, const unsigned short* __restrict__ wb5,
    float* __restrict__ st5, float* __restrict__ hbuf){
  __shared__ unsigned As[16*256];            // 16 rows x 512 bf16
  int tid = threadIdx.x;
  int n0g = blockIdx.x*16;                   // global point row in [0, B*N)
  for (int t = tid; t < 16*256; t += 256){
    int r = t >> 8, d = t & 255;             // d: u32 col (2 bf16)
    float2 xv = *(const float2*)&xcat[(size_t)(n0g + r)*512 + d*2];
    unsigned pk = (unsigned)f2bf(xv.x) | ((unsigned)f2bf(xv.y) << 16);
    int gs = (d >> 2) ^ r;                   // 16B-group swizzle
    As[r*256 + (gs<<2) + (d&3)] = pk;
  }
  __syncthreads();
  int w = tid>>6, lane = tid&63, col = lane&15, quad = lane>>4;
  // A-frags: lane -> row m=col, k=ks*32+quad*8 (held across all channel tiles)
  sbf8 afr[16];
#pragma unroll
  for (int ks=0; ks<16; ks++){
    int gs = (ks*4 + quad) ^ col;
    afr[ks] = *(const sbf8*)((const unsigned short*)As + col*512 + gs*8);
  }
#pragma unroll 1
  for (int i=0;i<16;i++){
    int obase = (w*16 + i)*16;
    f32x4 acc = {0.f,0.f,0.f,0.f};
#pragma unroll
    for (int ks=0; ks<16; ks++){
      sbf8 bfr = *(const sbf8*)(wb5 + (size_t)(obase+col)*512 + ks*32 + quad*8);
      acc = __builtin_amdgcn_mfma_f32_16x16x32_bf16(afr[ks], bfr, acc, 0, 0, 0);
    }
    // BN stats: sum over the block's 16 points (D rows)
    float s1 = acc.x+acc.y+acc.z+acc.w;
    float s2 = acc.x*acc.x + acc.y*acc.y + acc.z*acc.z + acc.w*acc.w;
    s1 += __shfl_xor(s1,16,64); s2 += __shfl_xor(s2,16,64);
    s1 += __shfl_xor(s1,32,64); s2 += __shfl_xor(s2,32,64);
    if (lane < 16){
      atomicAdd(&st5[obase+lane], s1);
      atomicAdd(&st5[1024+obase+lane], s2);
    }
    // store h: n-major [n][o]; 16 consecutive lanes -> 64B contiguous
    float vr[4] = {acc.x, acc.y, acc.z, acc.w};
#pragma unroll
    for (int r=0;r<4;r++)
      hbuf[(size_t)(n0g + quad*4 + r)*1024 + obase + col] = vr[r];
  }
}

// ---------------- pool over n: max & mean of lrelu(a*h+c); h n-major
__global__ __launch_bounds__(256) void pool5_kernel(
    const float* __restrict__ hbuf, const float* __restrict__ st5,
    unsigned* __restrict__ pmax, float* __restrict__ psum){
  int b = blockIdx.x >> 5;                   // 8 batches x 32 n-splits
  int ns = blockIdx.x & 31;
  int o4 = threadIdx.x*4;
  float4 a = *(const float4*)&st5[o4];
  float4 c = *(const float4*)&st5[1024+o4];
  float mx0=-1e30f,mx1=-1e30f,mx2=-1e30f,mx3=-1e30f;
  float sm0=0.f,sm1=0.f,sm2=0.f,sm3=0.f;
  for (int n = ns*32; n < ns*32+32; n++){
    float4 h = *(const float4*)&hbuf[(size_t)(b*NN + n)*1024 + o4];
    float t0 = lrelu(fmaf(a.x,h.x,c.x));
    float t1 = lrelu(fmaf(a.y,h.y,c.y));
    float t2 = lrelu(fmaf(a.z,h.z,c.z));
    float t3 = lrelu(fmaf(a.w,h.w,c.w));
    mx0=fmaxf(mx0,t0); mx1=fmaxf(mx1,t1); mx2=fmaxf(mx2,t2); mx3=fmaxf(mx3,t3);
    sm0+=t0; sm1+=t1; sm2+=t2; sm3+=t3;
  }
  atomicMax(&pmax[b*1024+o4+0], f2u_ord(mx0));
  atomicMax(&pmax[b*1024+o4+1], f2u_ord(mx1));
  atomicMax(&pmax[b*1024+o4+2], f2u_ord(mx2));
  atomicMax(&pmax[b*1024+o4+3], f2u_ord(mx3));
  atomicAdd(&psum[b*1024+o4+0], sm0);
  atomicAdd(&psum[b*1024+o4+1], sm1);
  atomicAdd(&psum[b*1024+o4+2], sm2);
  atomicAdd(&psum[b*1024+o4+3], sm3);
}

__global__ void pool_finalize_kernel(const unsigned* __restrict__ pmax,
                                     const float* __restrict__ psum,
                                     float* __restrict__ pooled){
  int t = blockIdx.x*256+threadIdx.x;
  if (t >= BB*2048) return;
  int b = t >> 11, j = t & 2047;
  pooled[t] = (j < 1024) ? u2f_ord(pmax[b*1024+j]) : psum[b*1024 + (j-1024)] * (1.f/1024.f);
}

// ---------------- FC head
__global__ __launch_bounds__(256) void fc6_kernel(
    const float* __restrict__ pooled, const void* __restrict__ W,
    const void* __restrict__ g, const void* __restrict__ bb, float* __restrict__ y6,
    const int* __restrict__ flagp){
  __shared__ float red[8][256];
  int o = blockIdx.x, tid = threadIdx.x;
  const int bf = *flagp;
  float part[8];
#pragma unroll
  for (int b=0;b<8;b++) part[b]=0.f;
  for (int c=tid;c<2048;c+=256){
    float wv = ldin(W,o*2048+c,bf);
#pragma unroll
    for (int b=0;b<8;b++) part[b] = fmaf(pooled[b*2048+c], wv, part[b]);
  }
#pragma unroll
  for (int b=0;b<8;b++) red[b][tid]=part[b];
  __syncthreads();
  for (int s=128;s;s>>=1){
    if (tid<s){
#pragma unroll
      for (int b=0;b<8;b++) red[b][tid]+=red[b][tid+s];
    }
    __syncthreads();
  }
  if (tid==0){
    float y[8], m=0.f;
#pragma unroll
    for (int b=0;b<8;b++){ y[b]=red[b][0]; m+=y[b]; }
    m *= 0.125f;
    float v=0.f;
#pragma unroll
    for (int b=0;b<8;b++){ float d=y[b]-m; v += d*d; }
    v *= 0.125f;
    float a=ldin(g,o,bf)*rsqrtf(fmaxf(v,0.f)+EPSB), c0=ldin(bb,o,bf)-m*a;
#pragma unroll
    for (int b=0;b<8;b++) y6[b*512+o]=lrelu(fmaf(a,y[b],c0));
  }
}

__global__ __launch_bounds__(256) void fc7_kernel(
    const float* __restrict__ y6, const void* __restrict__ W, const void* __restrict__ bias,
    const void* __restrict__ g, const void* __restrict__ bb, float* __restrict__ y7,
    const int* __restrict__ flagp){
  __shared__ float red[8][256];
  int o = blockIdx.x, tid = threadIdx.x;
  const int bf = *flagp;
  float part[8];
#pragma unroll
  for (int b=0;b<8;b++) part[b]=0.f;
  for (int c=tid;c<512;c+=256){
    float wv = ldin(W,o*512+c,bf);
#pragma unroll
    for (int b=0;b<8;b++) part[b] = fmaf(y6[b*512+c], wv, part[b]);
  }
#pragma unroll
  for (int b=0;b<8;b++) red[b][tid]=part[b];
  __syncthreads();
  for (int s=128;s;s>>=1){
    if (tid<s){
#pragma unroll
      for (int b=0;b<8;b++) red[b][tid]+=red[b][tid+s];
    }
    __syncthreads();
  }
  if (tid==0){
    float bs = ldin(bias,o,bf);
    float y[8], m=0.f;
#pragma unroll
    for (int b=0;b<8;b++){ y[b]=red[b][0]+bs; m+=y[b]; }
    m *= 0.125f;
    float v=0.f;
#pragma unroll
    for (int b=0;b<8;b++){ float d=y[b]-m; v += d*d; }
    v *= 0.125f;
    float a=ldin(g,o,bf)*rsqrtf(fmaxf(v,0.f)+EPSB), c0=ldin(bb,o,bf)-m*a;
#pragma unroll
    for (int b=0;b<8;b++) y7[b*256+o]=lrelu(fmaf(a,y[b],c0));
  }
}

__global__ __launch_bounds__(256) void fc8_kernel(
    const float* __restrict__ y7, const void* __restrict__ W, const void* __restrict__ bias,
    void* __restrict__ out, const int* __restrict__ flagp){
  __shared__ float red[8][256];
  int o = blockIdx.x, tid = threadIdx.x;
  const int bf = *flagp;
  float wv = ldin(W,o*256+tid,bf);
#pragma unroll
  for (int b=0;b<8;b++) red[b][tid] = y7[b*256+tid]*wv;
  __syncthreads();
  for (int s=128;s;s>>=1){
    if (tid<s){
#pragma unroll
      for (int b=0;b<8;b++) red[b][tid]+=red[b][tid+s];
    }
    __syncthreads();
  }
  if (tid==0){
    float bs = ldin(bias,o,bf);
#pragma unroll
    for (int b=0;b<8;b++){
      float r = red[b][0]+bs;
      if (bf) ((bf16*)out)[b*40+o] = __float2bfloat16(r);
      else    ((float*)out)[b*40+o] = r;
    }
  }
}

extern "C" void kernel_launch(void* const* d_in, const int* in_sizes, int n_in,
                              void* d_out, int out_size, void* d_ws, size_t ws_size,
                              hipStream_t stream){
  const void* x    = d_in[0];
  const void* w00  = d_in[1];
  const void* g00  = d_in[2];
  const void* b00  = d_in[3];
  const void* w01  = d_in[4];
  const void* g01  = d_in[5];
  const void* b01  = d_in[6];
  const void* w1   = d_in[7];  const void* g1 = d_in[8];  const void* b1 = d_in[9];
  const void* w2   = d_in[10]; const void* g2 = d_in[11]; const void* b2 = d_in[12];
  const void* w3   = d_in[13]; const void* g3 = d_in[14]; const void* b3 = d_in[15];
  const void* w4   = d_in[16]; const void* g4 = d_in[17]; const void* b4 = d_in[18];
  const void* w5   = d_in[19]; const void* g5 = d_in[20]; const void* b5 = d_in[21];
  const void* w6   = d_in[22]; const void* g6 = d_in[23]; const void* b6 = d_in[24];
  const void* w7   = d_in[25]; const void* bias7 = d_in[26];
  const void* g7   = d_in[27]; const void* b7 = d_in[28];
  const void* w8   = d_in[29]; const void* bias8 = d_in[30];

  float* ws = (float*)d_ws;
  // workspace layout (float offsets)
  size_t o_xc0  = 0;                              // B*N*16
  size_t o_xcat = o_xc0  + (size_t)BB*NN*16;      // B*N*512
  size_t o_negd = o_xcat + (size_t)BB*NN*512;     // B*N*N (u/v/hmax/hmin, then h5)
  size_t o_xx   = o_negd + (size_t)BB*NN*NN;      // B*N
  size_t o_w1d  = o_xx   + (size_t)BB*NN;         // 12*64
  size_t o_w1c  = o_w1d  + 12*64;
  size_t o_w2d  = o_w1c  + 12*64;                 // 64*64
  size_t o_w2c  = o_w2d  + 64*64;
  size_t o_w3d  = o_w2c  + 64*64;                 // 64*128
  size_t o_w3c  = o_w3d  + 64*128;
  size_t o_w4d  = o_w3c  + 64*128;                // 128*256
  size_t o_w4c  = o_w4d  + 128*256;
  size_t o_wb5  = o_w4c  + 128*256;               // 1024*512 bf16 = 262144 floats
  size_t o_st1  = o_wb5  + 262144;                // 128
  size_t o_st2  = o_st1  + 128;                   // 128
  size_t o_st3  = o_st2  + 128;                   // 256
  size_t o_st4  = o_st3  + 256;                   // 512
  size_t o_st5  = o_st4  + 512;                   // 2048
  size_t o_pmax = o_st5  + 2048;                  // 8*1024 (uint)
  size_t o_psum = o_pmax + 8192;                  // 8*1024
  size_t o_pool = o_psum + 8192;                  // 8*2048
  size_t o_y6   = o_pool + 16384;                 // 8*512
  size_t o_y7   = o_y6   + 4096;                  // 8*256
  size_t o_idx  = o_y7   + 2048;                  // B*N*20 ints
  size_t o_flag = o_idx  + (size_t)BB*NN*KK;      // 1 int

  // overlays on the negD region (dead after topk):
  size_t o_u    = o_negd;
  size_t o_v    = o_negd + (size_t)BB*NN*256;
  size_t o_hmax = o_negd + (size_t)2*BB*NN*256;
  size_t o_hmin = o_negd + (size_t)3*BB*NN*256;
  size_t o_h5   = o_negd;                         // B*N*1024 (after eb4 apply)

  int* idxp = (int*)(ws + o_idx);
  int* flagp = (int*)(ws + o_flag);
  float* negD = ws + o_negd;
  float* xxp  = ws + o_xx;
  float* xc0  = ws + o_xc0;
  float* xcat = ws + o_xcat;
  float* up   = ws + o_u;
  float* vp   = ws + o_v;
  float* hxp  = ws + o_hmax;
  float* hnp  = ws + o_hmin;
  unsigned short* wb5 = (unsigned short*)(ws + o_wb5);

  detect_kernel<<<1,64,0,stream>>>((const unsigned*)x, flagp);

  int nz = 128+128+256+512+2048+8192+8192;
  zero_kernel<<<(nz+255)/256, 256, 0, stream>>>((unsigned*)(ws + o_st1), nz);

  conv0_kernel<<<1,256,0,stream>>>(x, w00,g00,b00, w01,g01,b01, xc0, flagp);

  wuv_kernel<<<(12*64+255)/256,  256,0,stream>>>(w1, ws+o_w1d, ws+o_w1c,   9,  12,  64, flagp);
  wuv_kernel<<<(64*64+255)/256,  256,0,stream>>>(w2, ws+o_w2d, ws+o_w2c,  64,  64,  64, flagp);
  wuv_kernel<<<(64*128+255)/256, 256,0,stream>>>(w3, ws+o_w3d, ws+o_w3c,  64,  64, 128, flagp);
  wuv_kernel<<<(128*256+255)/256,256,0,stream>>>(w4, ws+o_w4d, ws+o_w4c, 128, 128, 256, flagp);
  wb5prep_kernel<<<(1024*512+255)/256,256,0,stream>>>(w5, wb5, flagp);

  dim3 ndgrid(NN/64, NN/64, BB);
  const int UVG = BB*NN/16;    // 512 blocks
  const int GG  = BB*NN/16;    // 512 blocks (4 waves x 4 points)

  // ---- edge block 1: src=xc0 (ld16, C=9), Cout=64 -> xcat[:,0:64)
  xx_kernel<<<32,256,0,stream>>>(xc0, 16, 0, 12, xxp);
  negdist_kernel<<<ndgrid,256, 2*64*12*4, stream>>>(xc0, 16, 0, 12, 0, xxp, negD);
  topk_kernel<<<BB*NN/4,256,0,stream>>>(negD, idxp);
  uvgemm_kernel<12,64><<<UVG,256,0,stream>>>(xc0, 16, 0, ws+o_w1d, ws+o_w1c, up, vp);
  ebgather_kernel<64><<<GG,256,0,stream>>>(idxp, up, vp, hxp, hnp, ws+o_st1);
  finalize_kernel<<<1,256,0,stream>>>(ws+o_st1, g1, b1, 1.f/(BB*NN*KK), 64, flagp);
  ebapply_kernel<64><<<BB*NN*64/256,256,0,stream>>>(hxp, hnp, ws+o_st1, xcat, 0);

  // ---- edge block 2: src=x1, Cout=64 -> xcat[:,64:128)
  xx_kernel<<<32,256,0,stream>>>(xcat, 512, 0, 64, xxp);
  negdist_kernel<<<ndgrid,256, 2*64*64*4, stream>>>(xcat, 512, 0, 64, 1, xxp, negD);
  topk_kernel<<<BB*NN/4,256,0,stream>>>(negD, idxp);
  uvgemm_kernel<64,64><<<UVG,256,0,stream>>>(xcat, 512, 0, ws+o_w2d, ws+o_w2c, up, vp);
  ebgather_kernel<64><<<GG,256,0,stream>>>(idxp, up, vp, hxp, hnp, ws+o_st2);
  finalize_kernel<<<1,256,0,stream>>>(ws+o_st2, g2, b2, 1.f/(BB*NN*KK), 64, flagp);
  ebapply_kernel<64><<<BB*NN*64/256,256,0,stream>>>(hxp, hnp, ws+o_st2, xcat, 64);

  // ---- edge block 3: src=x2, Cout=128 -> xcat[:,128:256)
  xx_kernel<<<32,256,0,stream>>>(xcat, 512, 64, 64, xxp);
  negdist_kernel<<<ndgrid,256, 2*64*64*4, stream>>>(xcat, 512, 64, 64, 1, xxp, negD);
  topk_kernel<<<BB*NN/4,256,0,stream>>>(negD, idxp);
  uvgemm_kernel<64,128><<<UVG,256,0,stream>>>(xcat, 512, 64, ws+o_w3d, ws+o_w3c, up, vp);
  ebgather_kernel<128><<<GG,256,0,stream>>>(idxp, up, vp, hxp, hnp, ws+o_st3);
  finalize_kernel<<<1,256,0,stream>>>(ws+o_st3, g3, b3, 1.f/(BB*NN*KK), 128, flagp);
  ebapply_kernel<128><<<BB*NN*128/256,256,0,stream>>>(hxp, hnp, ws+o_st3, xcat, 128);

  // ---- edge block 4: src=x3, Cout=256 -> xcat[:,256:512)
  xx_kernel<<<32,256,0,stream>>>(xcat, 512, 128, 128, xxp);
  negdist_kernel<<<ndgrid,256, 2*64*128*4, stream>>>(xcat, 512, 128, 128, 1, xxp, negD);
  topk_kernel<<<BB*NN/4,256,0,stream>>>(negD, idxp);
  uvgemm_kernel<128,256><<<UVG,256,0,stream>>>(xcat, 512, 128, ws+o_w4d, ws+o_w4c, up, vp);
  ebgather_kernel<256><<<GG,256,0,stream>>>(idxp, up, vp, hxp, hnp, ws+o_st4);
  finalize_kernel<<<1,256,0,stream>>>(ws+o_st4, g4, b4, 1.f/(BB*NN*KK), 256, flagp);
  ebapply_kernel<256><<<BB*NN*256/256,256,0,stream>>>(hxp, hnp, ws+o_st4, xcat, 256);

  // ---- conv5 (512 -> 1024) MFMA single pass + BN + lrelu + pool
  fc5_mfma<<<BB*NN/16,256,0,stream>>>(xcat, wb5, ws+o_st5, ws+o_h5);
  finalize_kernel<<<4,256,0,stream>>>(ws+o_st5, g5, b5, 1.f/(BB*NN), 1024, flagp);
  pool5_kernel<<<BB*32,256,0,stream>>>(ws+o_h5, ws+o_st5, (unsigned*)(ws+o_pmax), ws+o_psum);
  pool_finalize_kernel<<<(BB*2048+255)/256,256,0,stream>>>((unsigned*)(ws+o_pmax), ws+o_psum, ws+o_pool);

  // ---- FC head
  fc6_kernel<<<512,256,0,stream>>>(ws+o_pool, w6, g6, b6, ws+o_y6, flagp);
  fc7_kernel<<<256,256,0,stream>>>(ws+o_y6, w7, bias7, g7, b7, ws+o_y7, flagp);
  fc8_kernel<<<40,256,0,stream>>>(ws+o_y7, w8, bias8, d_out, flagp);
}

// Round 7
// 864.179 us; speedup vs baseline: 13.7295x; 1.0451x over previous
//
#include <hip/hip_runtime.h>
#include <hip/hip_bf16.h>

#define BB 8
#define NN 1024
#define KK 20
#define EPSB 1e-5f

typedef __hip_bfloat16 bf16;
typedef __attribute__((ext_vector_type(8))) short sbf8;   // 8 bf16 = 4 VGPRs
typedef __attribute__((ext_vector_type(4))) float f32x4;

__device__ __forceinline__ float lrelu(float t){ return t >= 0.f ? t : 0.2f*t; }
// dtype-flag-aware input load: flag=1 -> bf16, flag=0 -> fp32
__device__ __forceinline__ float ldin(const void* p, int i, int bf){
  return bf ? __bfloat162float(((const bf16*)p)[i]) : ((const float*)p)[i];
}
__device__ __forceinline__ unsigned short f2bf(float f){   // RNE fp32->bf16 bits
  unsigned u = __float_as_uint(f);
  return (unsigned short)((u + 0x7FFFu + ((u>>16)&1u)) >> 16);
}
__device__ __forceinline__ unsigned f2u_ord(float f){
  unsigned u = __float_as_uint(f);
  return (u & 0x80000000u) ? ~u : (u | 0x80000000u);
}
__device__ __forceinline__ float u2f_ord(unsigned u){
  return (u & 0x80000000u) ? __uint_as_float(u & 0x7fffffffu) : __uint_as_float(~u);
}

// ---------------- dtype detection (fp32 words of N(0,1) data never have exp>=0xD0)
__global__ void detect_kernel(const unsigned* __restrict__ xw, int* __restrict__ flag){
  int t = threadIdx.x;
  unsigned w = xw[t];
  unsigned e = (w >> 23) & 0xFFu;
  unsigned long long m = __ballot(e >= 0xD0u);
  if (t == 0) *flag = (__popcll(m) >= 32) ? 1 : 0;
}

__global__ void zero_kernel(unsigned* __restrict__ p, int n){
  int i = blockIdx.x*256 + threadIdx.x;
  if (i < n) p[i] = 0u;
}

// ---------------- conv0: three 2->2 gated branches, single block (tiny)
__global__ __launch_bounds__(256) void conv0_kernel(
    const void* __restrict__ x,
    const void* __restrict__ w00, const void* __restrict__ g00, const void* __restrict__ b00,
    const void* __restrict__ w01, const void* __restrict__ g01, const void* __restrict__ b01,
    float* __restrict__ xc0, const int* __restrict__ flagp){
  __shared__ float sacc[12][256];
  __shared__ float sA[6], sC[6];
  const int bf = *flagp;
  int tid = threadIdx.x;
  float part[12];
#pragma unroll
  for (int j=0;j<12;j++) part[j]=0.f;
  float wz[4], wy[4];
#pragma unroll
  for (int j=0;j<4;j++){ wz[j]=ldin(w00,j,bf); wy[j]=ldin(w01,j,bf); }
  for (int i = tid; i < BB*NN; i += 256){
    int b = i / NN, n = i % NN;
    float x0 = ldin(x,(b*3+0)*NN + n,bf);
    float x1 = ldin(x,(b*3+1)*NN + n,bf);
    float x2 = ldin(x,(b*3+2)*NN + n,bf);
    float z0 = wz[0]*x0 + wz[1]*x1, z1 = wz[2]*x0 + wz[3]*x1;
    float y0 = wy[0]*x0 + wy[1]*x2, y1 = wy[2]*x0 + wy[3]*x2;
    float u0 = wy[0]*x1 + wy[1]*x2, u1 = wy[2]*x1 + wy[3]*x2;
    part[0]+=z0; part[1]+=z0*z0; part[2]+=z1; part[3]+=z1*z1;
    part[4]+=y0; part[5]+=y0*y0; part[6]+=y1; part[7]+=y1*y1;
    part[8]+=u0; part[9]+=u0*u0; part[10]+=u1; part[11]+=u1*u1;
  }
#pragma unroll
  for (int j=0;j<12;j++) sacc[j][tid]=part[j];
  __syncthreads();
  for (int s=128;s;s>>=1){
    if (tid<s){
#pragma unroll
      for (int j=0;j<12;j++) sacc[j][tid]+=sacc[j][tid+s];
    }
    __syncthreads();
  }
  if (tid < 6){
    float m = sacc[2*tid][0] * (1.f/(BB*NN));
    float v = sacc[2*tid+1][0] * (1.f/(BB*NN)) - m*m;
    float g, bv;
    if (tid<2){ g=ldin(g00,tid,bf); bv=ldin(b00,tid,bf); }
    else if (tid<4){ g=ldin(g01,tid-2,bf); bv=ldin(b01,tid-2,bf); }
    else { g=ldin(g01,tid-4,bf); bv=ldin(b01,tid-4,bf); }
    float a = g * rsqrtf(fmaxf(v,0.f) + EPSB);
    sA[tid]=a; sC[tid]=bv - m*a;
  }
  __syncthreads();
  for (int i = tid; i < BB*NN; i += 256){
    int b = i / NN, n = i % NN;
    float x0 = ldin(x,(b*3+0)*NN + n,bf);
    float x1 = ldin(x,(b*3+1)*NN + n,bf);
    float x2 = ldin(x,(b*3+2)*NN + n,bf);
    float z0 = wz[0]*x0 + wz[1]*x1, z1 = wz[2]*x0 + wz[3]*x1;
    float y0 = wy[0]*x0 + wy[1]*x2, y1 = wy[2]*x0 + wy[3]*x2;
    float u0 = wy[0]*x1 + wy[1]*x2, u1 = wy[2]*x1 + wy[3]*x2;
    float* row = xc0 + (size_t)i*16;
    row[0]=x0; row[1]=x1; row[2]=x2;
    row[3]=lrelu(sA[4]*u0+sC[4])*x0; row[4]=lrelu(sA[5]*u1+sC[5])*x0;
    row[5]=lrelu(sA[2]*y0+sC[2])*x1; row[6]=lrelu(sA[3]*y1+sC[3])*x1;
    row[7]=lrelu(sA[0]*z0+sC[0])*x2; row[8]=lrelu(sA[1]*z1+sC[1])*x2;
    row[9]=0.f; row[10]=0.f; row[11]=0.f; row[12]=0.f; row[13]=0.f; row[14]=0.f; row[15]=0.f;
  }
}

// ---------------- build WdT[c][o] = W[o][c], WcdT[c][o] = W[o][CIN+c]-W[o][c]; pad c<CINP
__global__ void wuv_kernel(const void* __restrict__ W, float* __restrict__ WdT,
                           float* __restrict__ WcdT, int CIN, int CINP, int COUT,
                           const int* __restrict__ flagp){
  int t = blockIdx.x*256 + threadIdx.x;
  if (t >= CINP*COUT) return;
  const int bf = *flagp;
  int c = t / COUT, o = t % COUT;
  if (c < CIN){
    float wd = ldin(W, o*(2*CIN)+c, bf);
    float wc = ldin(W, o*(2*CIN)+CIN+c, bf);
    WdT[t] = wd; WcdT[t] = wc - wd;
  } else {
    WdT[t] = 0.f; WcdT[t] = 0.f;
  }
}

// ---------------- pack w5 (1024,512) -> bf16 same layout [o][c]
__global__ void wb5prep_kernel(const void* __restrict__ W, unsigned short* __restrict__ wb,
                               const int* __restrict__ flagp){
  int t = blockIdx.x*256 + threadIdx.x;
  if (t >= 1024*512) return;
  wb[t] = f2bf(ldin(W, t, *flagp));
}

// ---------------- fused negdist (with on-the-fly row norms): 128x128 tiles, 8x8 acc
// negD[i][j] = 2*<x_i,x_j> - |x_i|^2 - |x_j|^2.  K chunked at KCH=min(64, padded CR).
// LDS 16B groups XOR-swizzled by (row>>3)&GM: B-reads 2-way (free), A-reads broadcast.
__global__ __launch_bounds__(256) void knndist_kernel(
    const float* __restrict__ src, int ld, int coff, int CR,
    float* __restrict__ negD){
  extern __shared__ float lds[];
  const int KCH = (CR >= 64) ? 64 : 16;     // CR=12 -> 16 (xc0 cols 9..15 are zero)
  const int NG  = KCH >> 2;                 // 16B groups per row
  const int GM  = NG - 1;
  float* At = lds;
  float* Bt = lds + 128*KCH;
  float* xn = Bt + 128*KCH;                 // [0..127]=A norms, [128..255]=B norms
  int b = blockIdx.z, i0 = blockIdx.y*128, j0 = blockIdx.x*128;
  int tid = threadIdx.x;
  int ti = tid >> 4, tj = tid & 15;
  int gsa = ti & GM, gsb = tj & GM;
  float acc[8][8];
#pragma unroll
  for (int u=0;u<8;u++)
#pragma unroll
    for (int v=0;v<8;v++) acc[u][v]=0.f;
  float mynorm = 0.f;
  int nch = (CR + KCH - 1)/KCH;             // 1 (CR<=64) or 2 (CR=128)
  for (int ch=0; ch<nch; ch++){
    int c0 = ch*KCH;
    __syncthreads();
    // stage A (128 x KCH) and B (128 x KCH), float4 granularity
    for (int t = tid; t < 2*128*NG; t += 256){
      int half = (t >= 128*NG);
      int tt = half ? t - 128*NG : t;
      int r = tt / NG, g = tt % NG;
      int base = half ? j0 : i0;
      float4 f = *(const float4*)&src[(size_t)(b*NN + base + r)*ld + coff + c0 + g*4];
      int gs = g ^ ((r>>3) & GM);
      float* dst = (half ? Bt : At) + r*KCH + gs*4;
      *(float4*)dst = f;
    }
    __syncthreads();
    // row norms from staged data (order-independent over the permuted row)
    {
      int r = tid & 127;
      const float* rowp = ((tid < 128) ? At : Bt) + r*KCH;
      float s = 0.f;
      for (int g=0; g<NG; g++){
        float4 f = *(const float4*)&rowp[g*4];
        s += f.x*f.x + f.y*f.y + f.z*f.z + f.w*f.w;
      }
      mynorm += s;
    }
    // main 8x8 FMA
    for (int g=0; g<NG; g++){
      float4 av[8];
#pragma unroll
      for (int u=0;u<8;u++)
        av[u] = *(const float4*)&At[(ti*8+u)*KCH + ((g ^ gsa)<<2)];
#pragma unroll
      for (int v=0;v<8;v++){
        float4 bv = *(const float4*)&Bt[(tj*8+v)*KCH + ((g ^ gsb)<<2)];
#pragma unroll
        for (int u=0;u<8;u++)
          acc[u][v] += av[u].x*bv.x + av[u].y*bv.y + av[u].z*bv.z + av[u].w*bv.w;
      }
    }
  }
  __syncthreads();
  xn[(tid < 128 ? 0 : 128) + (tid & 127)] = mynorm;
  __syncthreads();
  float xi[8], xj[8];
#pragma unroll
  for (int u=0;u<8;u++){ xi[u] = xn[ti*8+u]; xj[u] = xn[128 + tj*8+u]; }
#pragma unroll
  for (int u=0;u<8;u++){
    float* orow = &negD[((size_t)(b*NN + i0 + ti*8 + u))*NN + j0 + tj*8];
#pragma unroll
    for (int vg=0; vg<2; vg++){
      float4 ov;
      ov.x = 2.f*acc[u][vg*4+0] - xi[u] - xj[vg*4+0];
      ov.y = 2.f*acc[u][vg*4+1] - xi[u] - xj[vg*4+1];
      ov.z = 2.f*acc[u][vg*4+2] - xi[u] - xj[vg*4+2];
      ov.w = 2.f*acc[u][vg*4+3] - xi[u] - xj[vg*4+3];
      *(float4*)&orow[vg*4] = ov;
    }
  }
}

// ---------------- top-20: one wave per row; registers + 64-lane butterfly argmax
__global__ __launch_bounds__(256) void topk_kernel(const float* __restrict__ negD,
                                                   int* __restrict__ idx){
  int row_id = (blockIdx.x*256 + threadIdx.x) >> 6;
  int lane = threadIdx.x & 63;
  if (row_id >= BB*NN) return;
  const float* row = negD + (size_t)row_id*NN;
  float v[16];
#pragma unroll
  for (int j=0;j<4;j++){
    float4 f = *(const float4*)&row[j*256 + lane*4];
    v[j*4+0]=f.x; v[j*4+1]=f.y; v[j*4+2]=f.z; v[j*4+3]=f.w;
  }
  int* orow = idx + (size_t)row_id*KK;
  for (int k=0;k<KK;k++){
    float bv = v[0]; int bs = 0;
#pragma unroll
    for (int s=1;s<16;s++){ if (v[s] > bv){ bv = v[s]; bs = s; } }
    int bidx = (bs>>2)*256 + lane*4 + (bs&3);
    unsigned long long key = ((unsigned long long)f2u_ord(bv) << 32) | (unsigned)(1023 - bidx);
#pragma unroll
    for (int off=32; off; off>>=1){
      unsigned long long o = __shfl_xor(key, off, 64);
      if (o > key) key = o;
    }
    int widx = 1023 - (int)(key & 0xFFFFFFFFu);
    if (lane == 0) orow[k] = widx;
    bool mine = (((widx >> 2) & 63) == lane);
    int wslot = ((widx >> 8) << 2) | (widx & 3);
#pragma unroll
    for (int s=0;s<16;s++){
      if (mine && s == wslot) v[s] = -1e30f;
    }
  }
}

// ---------------- u/v GEMM: ut[n][o]=Wd.x[n], vt[n][o]=(Wc-Wd).x[n]  (fp32 exact)
template<int CINP,int COUT>
__global__ __launch_bounds__(256) void uvgemm_kernel(
    const float* __restrict__ srcT, int ld, int coff,
    const float* __restrict__ WdT, const float* __restrict__ WcdT,
    float* __restrict__ ut, float* __restrict__ vt){
  constexpr int PT=16, G = 256/COUT, NP = PT/G;
  __shared__ float xs[PT*CINP];
  int tid = threadIdx.x;
  int base = blockIdx.x*PT;                 // global point index
  for (int t=tid; t<PT*CINP; t+=256){
    int p = t / CINP, c = t % CINP;
    xs[t] = srcT[(size_t)(base+p)*ld + coff + c];
  }
  __syncthreads();
  int o = tid % COUT, grp = tid / COUT;
  float u[NP], v[NP];
#pragma unroll
  for (int pp=0;pp<NP;pp++){ u[pp]=0.f; v[pp]=0.f; }
  for (int c=0;c<CINP;c+=4){
    float wd0 = WdT[(c+0)*COUT+o], wc0 = WcdT[(c+0)*COUT+o];
    float wd1 = WdT[(c+1)*COUT+o], wc1 = WcdT[(c+1)*COUT+o];
    float wd2 = WdT[(c+2)*COUT+o], wc2 = WcdT[(c+2)*COUT+o];
    float wd3 = WdT[(c+3)*COUT+o], wc3 = WcdT[(c+3)*COUT+o];
#pragma unroll
    for (int pp=0;pp<NP;pp++){
      float4 xv = *(const float4*)&xs[(grp+pp*G)*CINP + c];
      u[pp] = fmaf(xv.x,wd0,fmaf(xv.y,wd1,fmaf(xv.z,wd2,fmaf(xv.w,wd3,u[pp]))));
      v[pp] = fmaf(xv.x,wc0,fmaf(xv.y,wc1,fmaf(xv.z,wc2,fmaf(xv.w,wc3,v[pp]))));
    }
  }
#pragma unroll
  for (int pp=0;pp<NP;pp++){
    int p = grp + pp*G;
    ut[(size_t)(base+p)*COUT + o] = u[pp];
    vt[(size_t)(base+p)*COUT + o] = v[pp];
  }
}

// ---------------- gather pass: h[n,k,o] = ut[m(n,k)][o] + vt[n][o]
template<int COUT>
__global__ __launch_bounds__(256) void ebgather_kernel(
    const int* __restrict__ idx, const float* __restrict__ ut, const float* __restrict__ vt,
    float* __restrict__ hmaxb, float* __restrict__ hminb, float* __restrict__ stats){
  constexpr int CH = COUT/64, NPG = 4;
  int w = threadIdx.x >> 6, lane = threadIdx.x & 63;
  int n0 = (blockIdx.x*4 + w)*NPG;          // global point index
  float s1[CH], s2[CH];
#pragma unroll
  for (int ch=0;ch<CH;ch++){ s1[ch]=0.f; s2[ch]=0.f; }
  for (int pp=0;pp<NPG;pp++){
    int n = n0 + pp;
    int b = n >> 10;
    const int* irow = idx + (size_t)n*KK;
    float vr[CH], hx[CH], hn[CH];
#pragma unroll
    for (int ch=0;ch<CH;ch++){
      vr[ch] = vt[(size_t)n*COUT + ch*64 + lane];
      hx[ch] = -1e30f; hn[ch] = 1e30f;
    }
    for (int k=0;k<KK;k++){
      int m = irow[k];
      const float* urow = ut + (size_t)(b*NN + m)*COUT;
#pragma unroll
      for (int ch=0;ch<CH;ch++){
        float h = urow[ch*64+lane] + vr[ch];
        hx[ch] = fmaxf(hx[ch], h);
        hn[ch] = fminf(hn[ch], h);
        s1[ch] += h;
        s2[ch] = fmaf(h,h,s2[ch]);
      }
    }
#pragma unroll
    for (int ch=0;ch<CH;ch++){
      hmaxb[(size_t)n*COUT + ch*64 + lane] = hx[ch];
      hminb[(size_t)n*COUT + ch*64 + lane] = hn[ch];
    }
  }
#pragma unroll
  for (int ch=0;ch<CH;ch++){
    atomicAdd(&stats[ch*64+lane], s1[ch]);
    atomicAdd(&stats[COUT + ch*64+lane], s2[ch]);
  }
}

// ---------------- apply: out = lrelu(a*(a>=0?hmax:hmin)+c)
template<int COUT>
__global__ __launch_bounds__(256) void ebapply_kernel(
    const float* __restrict__ hmaxb, const float* __restrict__ hminb,
    const float* __restrict__ stats, float* __restrict__ outp, int outoff){
  int t = blockIdx.x*256 + threadIdx.x;
  if (t >= BB*NN*COUT) return;
  int n = t / COUT, o = t % COUT;
  float a = stats[o], c = stats[COUT+o];
  float h = (a >= 0.f) ? hmaxb[t] : hminb[t];
  outp[(size_t)n*512 + outoff + o] = lrelu(fmaf(a,h,c));
}

// ---------------- finalize BN stats -> (scale, shift) in place
__global__ void finalize_kernel(float* __restrict__ stats, const void* __restrict__ g,
                                const void* __restrict__ bb, float inv_count, int Cout,
                                const int* __restrict__ flagp){
  int o = blockIdx.x*256 + threadIdx.x;
  if (o >= Cout) return;
  const int bf = *flagp;
  float m = stats[o]*inv_count;
  float v = stats[Cout+o]*inv_count - m*m;
  float a = ldin(g,o,bf)*rsqrtf(fmaxf(v,0.f) + EPSB);
  stats[o] = a;
  stats[Cout+o] = ldin(bb,o,bf) - m*a;
}

// ---------------- conv5 via MFMA bf16: single pass, writes h fp32 [B*N][1024] + BN stats.
__global__ __launch_bounds__(256) void fc5_mfma(
    const float* __restrict__ xcat, const unsigned short* __restrict__ wb5,
    float* __restrict__ st5, float* __restrict__ hbuf){
  __shared__ unsigned As[16*256];            // 16 rows x 512 bf16
  int tid = threadIdx.x;
  int n0g = blockIdx.x*16;                   // global point row in [0, B*N)
  for (int t = tid; t < 16*256; t += 256){
    int r = t >> 8, d = t & 255;             // d: u32 col (2 bf16)
    float2 xv = *(const float2*)&xcat[(size_t)(n0g + r)*512 + d*2];
    unsigned pk = (unsigned)f2bf(xv.x) | ((unsigned)f2bf(xv.y) << 16);
    int gs = (d >> 2) ^ r;                   // 16B-group swizzle
    As[r*256 + (gs<<2) + (d&3)] = pk;
  }
  __syncthreads();
  int w = tid>>6, lane = tid&63, col = lane&15, quad = lane>>4;
  sbf8 afr[16];
#pragma unroll
  for (int ks=0; ks<16; ks++){
    int gs = (ks*4 + quad) ^ col;
    afr[ks] = *(const sbf8*)((const unsigned short*)As + col*512 + gs*8);
  }
#pragma unroll 1
  for (int i=0;i<16;i++){
    int obase = (w*16 + i)*16;
    f32x4 acc = {0.f,0.f,0.f,0.f};
#pragma unroll
    for (int ks=0; ks<16; ks++){
      sbf8 bfr = *(const sbf8*)(wb5 + (size_t)(obase+col)*512 + ks*32 + quad*8);
      acc = __builtin_amdgcn_mfma_f32_16x16x32_bf16(afr[ks], bfr, acc, 0, 0, 0);
    }
    float s1 = acc.x+acc.y+acc.z+acc.w;
    float s2 = acc.x*acc.x + acc.y*acc.y + acc.z*acc.z + acc.w*acc.w;
    s1 += __shfl_xor(s1,16,64); s2 += __shfl_xor(s2,16,64);
    s1 += __shfl_xor(s1,32,64); s2 += __shfl_xor(s2,32,64);
    if (lane < 16){
      atomicAdd(&st5[obase+lane], s1);
      atomicAdd(&st5[1024+obase+lane], s2);
    }
    float vr[4] = {acc.x, acc.y, acc.z, acc.w};
#pragma unroll
    for (int r=0;r<4;r++)
      hbuf[(size_t)(n0g + quad*4 + r)*1024 + obase + col] = vr[r];
  }
}

// ---------------- pool over n: max & mean of lrelu(a*h+c); h n-major
__global__ __launch_bounds__(256) void pool5_kernel(
    const float* __restrict__ hbuf, const float* __restrict__ st5,
    unsigned* __restrict__ pmax, float* __restrict__ psum){
  int b = blockIdx.x >> 5;                   // 8 batches x 32 n-splits
  int ns = blockIdx.x & 31;
  int o4 = threadIdx.x*4;
  float4 a = *(const float4*)&st5[o4];
  float4 c = *(const float4*)&st5[1024+o4];
  float mx0=-1e30f,mx1=-1e30f,mx2=-1e30f,mx3=-1e30f;
  float sm0=0.f,sm1=0.f,sm2=0.f,sm3=0.f;
  for (int n = ns*32; n < ns*32+32; n++){
    float4 h = *(const float4*)&hbuf[(size_t)(b*NN + n)*1024 + o4];
    float t0 = lrelu(fmaf(a.x,h.x,c.x));
    float t1 = lrelu(fmaf(a.y,h.y,c.y));
    float t2 = lrelu(fmaf(a.z,h.z,c.z));
    float t3 = lrelu(fmaf(a.w,h.w,c.w));
    mx0=fmaxf(mx0,t0); mx1=fmaxf(mx1,t1); mx2=fmaxf(mx2,t2); mx3=fmaxf(mx3,t3);
    sm0+=t0; sm1+=t1; sm2+=t2; sm3+=t3;
  }
  atomicMax(&pmax[b*1024+o4+0], f2u_ord(mx0));
  atomicMax(&pmax[b*1024+o4+1], f2u_ord(mx1));
  atomicMax(&pmax[b*1024+o4+2], f2u_ord(mx2));
  atomicMax(&pmax[b*1024+o4+3], f2u_ord(mx3));
  atomicAdd(&psum[b*1024+o4+0], sm0);
  atomicAdd(&psum[b*1024+o4+1], sm1);
  atomicAdd(&psum[b*1024+o4+2], sm2);
  atomicAdd(&psum[b*1024+o4+3], sm3);
}

__global__ void pool_finalize_kernel(const unsigned* __restrict__ pmax,
                                     const float* __restrict__ psum,
                                     float* __restrict__ pooled){
  int t = blockIdx.x*256+threadIdx.x;
  if (t >= BB*2048) return;
  int b = t >> 11, j = t & 2047;
  pooled[t] = (j < 1024) ? u2f_ord(pmax[b*1024+j]) : psum[b*1024 + (j-1024)] * (1.f/1024.f);
}

// ---------------- FC head
__global__ __launch_bounds__(256) void fc6_kernel(
    const float* __restrict__ pooled, const void* __restrict__ W,
    const void* __restrict__ g, const void* __restrict__ bb, float* __restrict__ y6,
    const int* __restrict__ flagp){
  __shared__ float red[8][256];
  int o = blockIdx.x, tid = threadIdx.x;
  const int bf = *flagp;
  float part[8];
#pragma unroll
  for (int b=0;b<8;b++) part[b]=0.f;
  for (int c=tid;c<2048;c+=256){
    float wv = ldin(W,o*2048+c,bf);
#pragma unroll
    for (int b=0;b<8;b++) part[b] = fmaf(pooled[b*2048+c], wv, part[b]);
  }
#pragma unroll
  for (int b=0;b<8;b++) red[b][tid]=part[b];
  __syncthreads();
  for (int s=128;s;s>>=1){
    if (tid<s){
#pragma unroll
      for (int b=0;b<8;b++) red[b][tid]+=red[b][tid+s];
    }
    __syncthreads();
  }
  if (tid==0){
    float y[8], m=0.f;
#pragma unroll
    for (int b=0;b<8;b++){ y[b]=red[b][0]; m+=y[b]; }
    m *= 0.125f;
    float v=0.f;
#pragma unroll
    for (int b=0;b<8;b++){ float d=y[b]-m; v += d*d; }
    v *= 0.125f;
    float a=ldin(g,o,bf)*rsqrtf(fmaxf(v,0.f)+EPSB), c0=ldin(bb,o,bf)-m*a;
#pragma unroll
    for (int b=0;b<8;b++) y6[b*512+o]=lrelu(fmaf(a,y[b],c0));
  }
}

__global__ __launch_bounds__(256) void fc7_kernel(
    const float* __restrict__ y6, const void* __restrict__ W, const void* __restrict__ bias,
    const void* __restrict__ g, const void* __restrict__ bb, float* __restrict__ y7,
    const int* __restrict__ flagp){
  __shared__ float red[8][256];
  int o = blockIdx.x, tid = threadIdx.x;
  const int bf = *flagp;
  float part[8];
#pragma unroll
  for (int b=0;b<8;b++) part[b]=0.f;
  for (int c=tid;c<512;c+=256){
    float wv = ldin(W,o*512+c,bf);
#pragma unroll
    for (int b=0;b<8;b++) part[b] = fmaf(y6[b*512+c], wv, part[b]);
  }
#pragma unroll
  for (int b=0;b<8;b++) red[b][tid]=part[b];
  __syncthreads();
  for (int s=128;s;s>>=1){
    if (tid<s){
#pragma unroll
      for (int b=0;b<8;b++) red[b][tid]+=red[b][tid+s];
    }
    __syncthreads();
  }
  if (tid==0){
    float bs = ldin(bias,o,bf);
    float y[8], m=0.f;
#pragma unroll
    for (int b=0;b<8;b++){ y[b]=red[b][0]+bs; m+=y[b]; }
    m *= 0.125f;
    float v=0.f;
#pragma unroll
    for (int b=0;b<8;b++){ float d=y[b]-m; v += d*d; }
    v *= 0.125f;
    float a=ldin(g,o,bf)*rsqrtf(fmaxf(v,0.f)+EPSB), c0=ldin(bb,o,bf)-m*a;
#pragma unroll
    for (int b=0;b<8;b++) y7[b*256+o]=lrelu(fmaf(a,y[b],c0));
  }
}

__global__ __launch_bounds__(256) void fc8_kernel(
    const float* __restrict__ y7, const void* __restrict__ W, const void* __restrict__ bias,
    void* __restrict__ out, const int* __restrict__ flagp){
  __shared__ float red[8][256];
  int o = blockIdx.x, tid = threadIdx.x;
  const int bf = *flagp;
  float wv = ldin(W,o*256+tid,bf);
#pragma unroll
  for (int b=0;b<8;b++) red[b][tid] = y7[b*256+tid]*wv;
  __syncthreads();
  for (int s=128;s;s>>=1){
    if (tid<s){
#pragma unroll
      for (int b=0;b<8;b++) red[b][tid]+=red[b][tid+s];
    }
    __syncthreads();
  }
  if (tid==0){
    float bs = ldin(bias,o,bf);
#pragma unroll
    for (int b=0;b<8;b++){
      float r = red[b][0]+bs;
      if (bf) ((bf16*)out)[b*40+o] = __float2bfloat16(r);
      else    ((float*)out)[b*40+o] = r;
    }
  }
}

extern "C" void kernel_launch(void* const* d_in, const int* in_sizes, int n_in,
                              void* d_out, int out_size, void* d_ws, size_t ws_size,
                              hipStream_t stream){
  const void* x    = d_in[0];
  const void* w00  = d_in[1];
  const void* g00  = d_in[2];
  const void* b00  = d_in[3];
  const void* w01  = d_in[4];
  const void* g01  = d_in[5];
  const void* b01  = d_in[6];
  const void* w1   = d_in[7];  const void* g1 = d_in[8];  const void* b1 = d_in[9];
  const void* w2   = d_in[10]; const void* g2 = d_in[11]; const void* b2 = d_in[12];
  const void* w3   = d_in[13]; const void* g3 = d_in[14]; const void* b3 = d_in[15];
  const void* w4   = d_in[16]; const void* g4 = d_in[17]; const void* b4 = d_in[18];
  const void* w5   = d_in[19]; const void* g5 = d_in[20]; const void* b5 = d_in[21];
  const void* w6   = d_in[22]; const void* g6 = d_in[23]; const void* b6 = d_in[24];
  const void* w7   = d_in[25]; const void* bias7 = d_in[26];
  const void* g7   = d_in[27]; const void* b7 = d_in[28];
  const void* w8   = d_in[29]; const void* bias8 = d_in[30];

  float* ws = (float*)d_ws;
  // workspace layout (float offsets)
  size_t o_xc0  = 0;                              // B*N*16
  size_t o_xcat = o_xc0  + (size_t)BB*NN*16;      // B*N*512
  size_t o_negd = o_xcat + (size_t)BB*NN*512;     // B*N*N (u/v/hmax/hmin, then h5)
  size_t o_xx   = o_negd + (size_t)BB*NN*NN;      // B*N (unused now)
  size_t o_w1d  = o_xx   + (size_t)BB*NN;         // 12*64
  size_t o_w1c  = o_w1d  + 12*64;
  size_t o_w2d  = o_w1c  + 12*64;                 // 64*64
  size_t o_w2c  = o_w2d  + 64*64;
  size_t o_w3d  = o_w2c  + 64*64;                 // 64*128
  size_t o_w3c  = o_w3d  + 64*128;
  size_t o_w4d  = o_w3c  + 64*128;                // 128*256
  size_t o_w4c  = o_w4d  + 128*256;
  size_t o_wb5  = o_w4c  + 128*256;               // 1024*512 bf16 = 262144 floats
  size_t o_st1  = o_wb5  + 262144;                // 128
  size_t o_st2  = o_st1  + 128;                   // 128
  size_t o_st3  = o_st2  + 128;                   // 256
  size_t o_st4  = o_st3  + 256;                   // 512
  size_t o_st5  = o_st4  + 512;                   // 2048
  size_t o_pmax = o_st5  + 2048;                  // 8*1024 (uint)
  size_t o_psum = o_pmax + 8192;                  // 8*1024
  size_t o_pool = o_psum + 8192;                  // 8*2048
  size_t o_y6   = o_pool + 16384;                 // 8*512
  size_t o_y7   = o_y6   + 4096;                  // 8*256
  size_t o_idx  = o_y7   + 2048;                  // B*N*20 ints
  size_t o_flag = o_idx  + (size_t)BB*NN*KK;      // 1 int

  // overlays on the negD region (dead after topk):
  size_t o_u    = o_negd;
  size_t o_v    = o_negd + (size_t)BB*NN*256;
  size_t o_hmax = o_negd + (size_t)2*BB*NN*256;
  size_t o_hmin = o_negd + (size_t)3*BB*NN*256;
  size_t o_h5   = o_negd;                         // B*N*1024 (after eb4 apply)

  int* idxp = (int*)(ws + o_idx);
  int* flagp = (int*)(ws + o_flag);
  float* negD = ws + o_negd;
  float* xc0  = ws + o_xc0;
  float* xcat = ws + o_xcat;
  float* up   = ws + o_u;
  float* vp   = ws + o_v;
  float* hxp  = ws + o_hmax;
  float* hnp  = ws + o_hmin;
  unsigned short* wb5 = (unsigned short*)(ws + o_wb5);

  detect_kernel<<<1,64,0,stream>>>((const unsigned*)x, flagp);

  int nz = 128+128+256+512+2048+8192+8192;
  zero_kernel<<<(nz+255)/256, 256, 0, stream>>>((unsigned*)(ws + o_st1), nz);

  conv0_kernel<<<1,256,0,stream>>>(x, w00,g00,b00, w01,g01,b01, xc0, flagp);

  wuv_kernel<<<(12*64+255)/256,  256,0,stream>>>(w1, ws+o_w1d, ws+o_w1c,   9,  12,  64, flagp);
  wuv_kernel<<<(64*64+255)/256,  256,0,stream>>>(w2, ws+o_w2d, ws+o_w2c,  64,  64,  64, flagp);
  wuv_kernel<<<(64*128+255)/256, 256,0,stream>>>(w3, ws+o_w3d, ws+o_w3c,  64,  64, 128, flagp);
  wuv_kernel<<<(128*256+255)/256,256,0,stream>>>(w4, ws+o_w4d, ws+o_w4c, 128, 128, 256, flagp);
  wb5prep_kernel<<<(1024*512+255)/256,256,0,stream>>>(w5, wb5, flagp);

  dim3 kgrid(NN/128, NN/128, BB);               // 512 blocks
  const size_t KLDS16 = (2*128*16 + 256)*4;     // CR=12 (KCH=16)
  const size_t KLDS64 = (2*128*64 + 256)*4;     // CR=64/128 (KCH=64)
  const int UVG = BB*NN/16;    // 512 blocks
  const int GG  = BB*NN/16;    // 512 blocks (4 waves x 4 points)

  // ---- edge block 1: src=xc0 (ld16, C=9), Cout=64 -> xcat[:,0:64)
  knndist_kernel<<<kgrid,256, KLDS16, stream>>>(xc0, 16, 0, 12, negD);
  topk_kernel<<<BB*NN/4,256,0,stream>>>(negD, idxp);
  uvgemm_kernel<12,64><<<UVG,256,0,stream>>>(xc0, 16, 0, ws+o_w1d, ws+o_w1c, up, vp);
  ebgather_kernel<64><<<GG,256,0,stream>>>(idxp, up, vp, hxp, hnp, ws+o_st1);
  finalize_kernel<<<1,256,0,stream>>>(ws+o_st1, g1, b1, 1.f/(BB*NN*KK), 64, flagp);
  ebapply_kernel<64><<<BB*NN*64/256,256,0,stream>>>(hxp, hnp, ws+o_st1, xcat, 0);

  // ---- edge block 2: src=x1, Cout=64 -> xcat[:,64:128)
  knndist_kernel<<<kgrid,256, KLDS64, stream>>>(xcat, 512, 0, 64, negD);
  topk_kernel<<<BB*NN/4,256,0,stream>>>(negD, idxp);
  uvgemm_kernel<64,64><<<UVG,256,0,stream>>>(xcat, 512, 0, ws+o_w2d, ws+o_w2c, up, vp);
  ebgather_kernel<64><<<GG,256,0,stream>>>(idxp, up, vp, hxp, hnp, ws+o_st2);
  finalize_kernel<<<1,256,0,stream>>>(ws+o_st2, g2, b2, 1.f/(BB*NN*KK), 64, flagp);
  ebapply_kernel<64><<<BB*NN*64/256,256,0,stream>>>(hxp, hnp, ws+o_st2, xcat, 64);

  // ---- edge block 3: src=x2, Cout=128 -> xcat[:,128:256)
  knndist_kernel<<<kgrid,256, KLDS64, stream>>>(xcat, 512, 64, 64, negD);
  topk_kernel<<<BB*NN/4,256,0,stream>>>(negD, idxp);
  uvgemm_kernel<64,128><<<UVG,256,0,stream>>>(xcat, 512, 64, ws+o_w3d, ws+o_w3c, up, vp);
  ebgather_kernel<128><<<GG,256,0,stream>>>(idxp, up, vp, hxp, hnp, ws+o_st3);
  finalize_kernel<<<1,256,0,stream>>>(ws+o_st3, g3, b3, 1.f/(BB*NN*KK), 128, flagp);
  ebapply_kernel<128><<<BB*NN*128/256,256,0,stream>>>(hxp, hnp, ws+o_st3, xcat, 128);

  // ---- edge block 4: src=x3, Cout=256 -> xcat[:,256:512)
  knndist_kernel<<<kgrid,256, KLDS64, stream>>>(xcat, 512, 128, 128, negD);
  topk_kernel<<<BB*NN/4,256,0,stream>>>(negD, idxp);
  uvgemm_kernel<128,256><<<UVG,256,0,stream>>>(xcat, 512, 128, ws+o_w4d, ws+o_w4c, up, vp);
  ebgather_kernel<256><<<GG,256,0,stream>>>(idxp, up, vp, hxp, hnp, ws+o_st4);
  finalize_kernel<<<1,256,0,stream>>>(ws+o_st4, g4, b4, 1.f/(BB*NN*KK), 256, flagp);
  ebapply_kernel<256><<<BB*NN*256/256,256,0,stream>>>(hxp, hnp, ws+o_st4, xcat, 256);

  // ---- conv5 (512 -> 1024) MFMA single pass + BN + lrelu + pool
  fc5_mfma<<<BB*NN/16,256,0,stream>>>(xcat, wb5, ws+o_st5, ws+o_h5);
  finalize_kernel<<<4,256,0,stream>>>(ws+o_st5, g5, b5, 1.f/(BB*NN), 1024, flagp);
  pool5_kernel<<<BB*32,256,0,stream>>>(ws+o_h5, ws+o_st5, (unsigned*)(ws+o_pmax), ws+o_psum);
  pool_finalize_kernel<<<(BB*2048+255)/256,256,0,stream>>>((unsigned*)(ws+o_pmax), ws+o_psum, ws+o_pool);

  // ---- FC head
  fc6_kernel<<<512,256,0,stream>>>(ws+o_pool, w6, g6, b6, ws+o_y6, flagp);
  fc7_kernel<<<256,256,0,stream>>>(ws+o_y6, w7, bias7, g7, b7, ws+o_y7, flagp);
  fc8_kernel<<<40,256,0,stream>>>(ws+o_y7, w8, bias8, d_out, flagp);
}

// Round 8
// 837.784 us; speedup vs baseline: 14.1620x; 1.0315x over previous
//
#include <hip/hip_runtime.h>
#include <hip/hip_bf16.h>

#define BB 8
#define NN 1024
#define KK 20
#define EPSB 1e-5f

typedef __hip_bfloat16 bf16;
typedef __attribute__((ext_vector_type(8))) short sbf8;   // 8 bf16 = 4 VGPRs
typedef __attribute__((ext_vector_type(4))) float f32x4;

__device__ __forceinline__ float lrelu(float t){ return t >= 0.f ? t : 0.2f*t; }
// dtype-flag-aware input load: flag=1 -> bf16, flag=0 -> fp32
__device__ __forceinline__ float ldin(const void* p, int i, int bf){
  return bf ? __bfloat162float(((const bf16*)p)[i]) : ((const float*)p)[i];
}
__device__ __forceinline__ unsigned short f2bf(float f){   // RNE fp32->bf16 bits
  unsigned u = __float_as_uint(f);
  return (unsigned short)((u + 0x7FFFu + ((u>>16)&1u)) >> 16);
}
__device__ __forceinline__ unsigned f2u_ord(float f){
  unsigned u = __float_as_uint(f);
  return (u & 0x80000000u) ? ~u : (u | 0x80000000u);
}
__device__ __forceinline__ float u2f_ord(unsigned u){
  return (u & 0x80000000u) ? __uint_as_float(u & 0x7fffffffu) : __uint_as_float(~u);
}

// ---------------- dtype detection (fp32 words of N(0,1) data never have exp>=0xD0)
__global__ void detect_kernel(const unsigned* __restrict__ xw, int* __restrict__ flag){
  int t = threadIdx.x;
  unsigned w = xw[t];
  unsigned e = (w >> 23) & 0xFFu;
  unsigned long long m = __ballot(e >= 0xD0u);
  if (t == 0) *flag = (__popcll(m) >= 32) ? 1 : 0;
}

__global__ void zero_kernel(unsigned* __restrict__ p, int n){
  int i = blockIdx.x*256 + threadIdx.x;
  if (i < n) p[i] = 0u;
}

// ---------------- conv0 stats: 32 blocks, 1 point/thread, shuffle-reduce + atomics
__global__ __launch_bounds__(256) void conv0_stats_kernel(
    const void* __restrict__ x,
    const void* __restrict__ w00, const void* __restrict__ w01,
    float* __restrict__ cstat, const int* __restrict__ flagp){
  const int bf = *flagp;
  int i = blockIdx.x*256 + threadIdx.x;
  int b = i >> 10, n = i & 1023;
  float wz[4], wy[4];
#pragma unroll
  for (int j=0;j<4;j++){ wz[j]=ldin(w00,j,bf); wy[j]=ldin(w01,j,bf); }
  float x0 = ldin(x,(b*3+0)*NN + n,bf);
  float x1 = ldin(x,(b*3+1)*NN + n,bf);
  float x2 = ldin(x,(b*3+2)*NN + n,bf);
  float vals[6];
  vals[0] = wz[0]*x0 + wz[1]*x1;  vals[1] = wz[2]*x0 + wz[3]*x1;   // z (w00, ch 0,1)
  vals[2] = wy[0]*x0 + wy[1]*x2;  vals[3] = wy[2]*x0 + wy[3]*x2;   // y (w01, ch 0,2)
  vals[4] = wy[0]*x1 + wy[1]*x2;  vals[5] = wy[2]*x1 + wy[3]*x2;   // u (w01, ch 1,2)
  int lane = threadIdx.x & 63;
#pragma unroll
  for (int j=0;j<6;j++){
    float s1 = vals[j], s2 = vals[j]*vals[j];
#pragma unroll
    for (int off=32; off; off>>=1){
      s1 += __shfl_xor(s1, off, 64);
      s2 += __shfl_xor(s2, off, 64);
    }
    if (lane == 0){
      atomicAdd(&cstat[2*j], s1);
      atomicAdd(&cstat[2*j+1], s2);
    }
  }
}

// ---------------- conv0 apply: BN+lrelu+gate, writes xc0 rows (16 floats, padded)
__global__ __launch_bounds__(256) void conv0_apply_kernel(
    const void* __restrict__ x,
    const void* __restrict__ w00, const void* __restrict__ g00, const void* __restrict__ b00,
    const void* __restrict__ w01, const void* __restrict__ g01, const void* __restrict__ b01,
    const float* __restrict__ cstat, float* __restrict__ xc0,
    const int* __restrict__ flagp){
  const int bf = *flagp;
  int i = blockIdx.x*256 + threadIdx.x;
  int b = i >> 10, n = i & 1023;
  float wz[4], wy[4];
#pragma unroll
  for (int j=0;j<4;j++){ wz[j]=ldin(w00,j,bf); wy[j]=ldin(w01,j,bf); }
  float sA[6], sC[6];
#pragma unroll
  for (int j=0;j<6;j++){
    float m = cstat[2*j] * (1.f/(BB*NN));
    float v = cstat[2*j+1] * (1.f/(BB*NN)) - m*m;
    float g, bv;
    if (j<2){ g=ldin(g00,j,bf); bv=ldin(b00,j,bf); }
    else if (j<4){ g=ldin(g01,j-2,bf); bv=ldin(b01,j-2,bf); }
    else { g=ldin(g01,j-4,bf); bv=ldin(b01,j-4,bf); }
    float a = g * rsqrtf(fmaxf(v,0.f) + EPSB);
    sA[j]=a; sC[j]=bv - m*a;
  }
  float x0 = ldin(x,(b*3+0)*NN + n,bf);
  float x1 = ldin(x,(b*3+1)*NN + n,bf);
  float x2 = ldin(x,(b*3+2)*NN + n,bf);
  float z0 = wz[0]*x0 + wz[1]*x1, z1 = wz[2]*x0 + wz[3]*x1;
  float y0 = wy[0]*x0 + wy[1]*x2, y1 = wy[2]*x0 + wy[3]*x2;
  float u0 = wy[0]*x1 + wy[1]*x2, u1 = wy[2]*x1 + wy[3]*x2;
  float* row = xc0 + (size_t)i*16;
  float4 r0, r1, r2, r3;
  r0.x=x0; r0.y=x1; r0.z=x2;
  r0.w=lrelu(sA[4]*u0+sC[4])*x0;
  r1.x=lrelu(sA[5]*u1+sC[5])*x0;
  r1.y=lrelu(sA[2]*y0+sC[2])*x1;
  r1.z=lrelu(sA[3]*y1+sC[3])*x1;
  r1.w=lrelu(sA[0]*z0+sC[0])*x2;
  r2.x=lrelu(sA[1]*z1+sC[1])*x2;
  r2.y=0.f; r2.z=0.f; r2.w=0.f;
  r3.x=0.f; r3.y=0.f; r3.z=0.f; r3.w=0.f;
  *(float4*)&row[0]  = r0;
  *(float4*)&row[4]  = r1;
  *(float4*)&row[8]  = r2;
  *(float4*)&row[12] = r3;
}

// ---------------- build WdT[c][o] = W[o][c], WcdT[c][o] = W[o][CIN+c]-W[o][c]; pad c<CINP
__global__ void wuv_kernel(const void* __restrict__ W, float* __restrict__ WdT,
                           float* __restrict__ WcdT, int CIN, int CINP, int COUT,
                           const int* __restrict__ flagp){
  int t = blockIdx.x*256 + threadIdx.x;
  if (t >= CINP*COUT) return;
  const int bf = *flagp;
  int c = t / COUT, o = t % COUT;
  if (c < CIN){
    float wd = ldin(W, o*(2*CIN)+c, bf);
    float wc = ldin(W, o*(2*CIN)+CIN+c, bf);
    WdT[t] = wd; WcdT[t] = wc - wd;
  } else {
    WdT[t] = 0.f; WcdT[t] = 0.f;
  }
}

// ---------------- pack w5 (1024,512) -> bf16 same layout [o][c]
__global__ void wb5prep_kernel(const void* __restrict__ W, unsigned short* __restrict__ wb,
                               const int* __restrict__ flagp){
  int t = blockIdx.x*256 + threadIdx.x;
  if (t >= 1024*512) return;
  wb[t] = f2bf(ldin(W, t, *flagp));
}

// ---------------- fused negdist (with on-the-fly row norms): 128x128 tiles, 8x8 acc
__global__ __launch_bounds__(256) void knndist_kernel(
    const float* __restrict__ src, int ld, int coff, int CR,
    float* __restrict__ negD){
  extern __shared__ float lds[];
  const int KCH = (CR >= 64) ? 64 : 16;     // CR=12 -> 16 (xc0 cols 9..15 are zero)
  const int NG  = KCH >> 2;                 // 16B groups per row
  const int GM  = NG - 1;
  float* At = lds;
  float* Bt = lds + 128*KCH;
  float* xn = Bt + 128*KCH;                 // [0..127]=A norms, [128..255]=B norms
  int b = blockIdx.z, i0 = blockIdx.y*128, j0 = blockIdx.x*128;
  int tid = threadIdx.x;
  int ti = tid >> 4, tj = tid & 15;
  int gsa = ti & GM, gsb = tj & GM;
  float acc[8][8];
#pragma unroll
  for (int u=0;u<8;u++)
#pragma unroll
    for (int v=0;v<8;v++) acc[u][v]=0.f;
  float mynorm = 0.f;
  int nch = (CR + KCH - 1)/KCH;             // 1 (CR<=64) or 2 (CR=128)
  for (int ch=0; ch<nch; ch++){
    int c0 = ch*KCH;
    __syncthreads();
    for (int t = tid; t < 2*128*NG; t += 256){
      int half = (t >= 128*NG);
      int tt = half ? t - 128*NG : t;
      int r = tt / NG, g = tt % NG;
      int base = half ? j0 : i0;
      float4 f = *(const float4*)&src[(size_t)(b*NN + base + r)*ld + coff + c0 + g*4];
      int gs = g ^ ((r>>3) & GM);
      float* dst = (half ? Bt : At) + r*KCH + gs*4;
      *(float4*)dst = f;
    }
    __syncthreads();
    {
      int r = tid & 127;
      const float* rowp = ((tid < 128) ? At : Bt) + r*KCH;
      float s = 0.f;
      for (int g=0; g<NG; g++){
        float4 f = *(const float4*)&rowp[g*4];
        s += f.x*f.x + f.y*f.y + f.z*f.z + f.w*f.w;
      }
      mynorm += s;
    }
    for (int g=0; g<NG; g++){
      float4 av[8];
#pragma unroll
      for (int u=0;u<8;u++)
        av[u] = *(const float4*)&At[(ti*8+u)*KCH + ((g ^ gsa)<<2)];
#pragma unroll
      for (int v=0;v<8;v++){
        float4 bv = *(const float4*)&Bt[(tj*8+v)*KCH + ((g ^ gsb)<<2)];
#pragma unroll
        for (int u=0;u<8;u++)
          acc[u][v] += av[u].x*bv.x + av[u].y*bv.y + av[u].z*bv.z + av[u].w*bv.w;
      }
    }
  }
  __syncthreads();
  xn[(tid < 128 ? 0 : 128) + (tid & 127)] = mynorm;
  __syncthreads();
  float xi[8], xj[8];
#pragma unroll
  for (int u=0;u<8;u++){ xi[u] = xn[ti*8+u]; xj[u] = xn[128 + tj*8+u]; }
#pragma unroll
  for (int u=0;u<8;u++){
    float* orow = &negD[((size_t)(b*NN + i0 + ti*8 + u))*NN + j0 + tj*8];
#pragma unroll
    for (int vg=0; vg<2; vg++){
      float4 ov;
      ov.x = 2.f*acc[u][vg*4+0] - xi[u] - xj[vg*4+0];
      ov.y = 2.f*acc[u][vg*4+1] - xi[u] - xj[vg*4+1];
      ov.z = 2.f*acc[u][vg*4+2] - xi[u] - xj[vg*4+2];
      ov.w = 2.f*acc[u][vg*4+3] - xi[u] - xj[vg*4+3];
      *(float4*)&orow[vg*4] = ov;
    }
  }
}

// ---------------- top-20: one wave per row; registers + 64-lane butterfly argmax
__global__ __launch_bounds__(256) void topk_kernel(const float* __restrict__ negD,
                                                   int* __restrict__ idx){
  int row_id = (blockIdx.x*256 + threadIdx.x) >> 6;
  int lane = threadIdx.x & 63;
  if (row_id >= BB*NN) return;
  const float* row = negD + (size_t)row_id*NN;
  float v[16];
#pragma unroll
  for (int j=0;j<4;j++){
    float4 f = *(const float4*)&row[j*256 + lane*4];
    v[j*4+0]=f.x; v[j*4+1]=f.y; v[j*4+2]=f.z; v[j*4+3]=f.w;
  }
  int* orow = idx + (size_t)row_id*KK;
  for (int k=0;k<KK;k++){
    float bv = v[0]; int bs = 0;
#pragma unroll
    for (int s=1;s<16;s++){ if (v[s] > bv){ bv = v[s]; bs = s; } }
    int bidx = (bs>>2)*256 + lane*4 + (bs&3);
    unsigned long long key = ((unsigned long long)f2u_ord(bv) << 32) | (unsigned)(1023 - bidx);
#pragma unroll
    for (int off=32; off; off>>=1){
      unsigned long long o = __shfl_xor(key, off, 64);
      if (o > key) key = o;
    }
    int widx = 1023 - (int)(key & 0xFFFFFFFFu);
    if (lane == 0) orow[k] = widx;
    bool mine = (((widx >> 2) & 63) == lane);
    int wslot = ((widx >> 8) << 2) | (widx & 3);
#pragma unroll
    for (int s=0;s<16;s++){
      if (mine && s == wslot) v[s] = -1e30f;
    }
  }
}

// ---------------- u/v GEMM: ut[n][o]=Wd.x[n], vt[n][o]=(Wc-Wd).x[n]  (fp32 exact)
template<int CINP,int COUT>
__global__ __launch_bounds__(256) void uvgemm_kernel(
    const float* __restrict__ srcT, int ld, int coff,
    const float* __restrict__ WdT, const float* __restrict__ WcdT,
    float* __restrict__ ut, float* __restrict__ vt){
  constexpr int PT=16, G = 256/COUT, NP = PT/G;
  __shared__ float xs[PT*CINP];
  int tid = threadIdx.x;
  int base = blockIdx.x*PT;                 // global point index
  for (int t=tid; t<PT*CINP; t+=256){
    int p = t / CINP, c = t % CINP;
    xs[t] = srcT[(size_t)(base+p)*ld + coff + c];
  }
  __syncthreads();
  int o = tid % COUT, grp = tid / COUT;
  float u[NP], v[NP];
#pragma unroll
  for (int pp=0;pp<NP;pp++){ u[pp]=0.f; v[pp]=0.f; }
  for (int c=0;c<CINP;c+=4){
    float wd0 = WdT[(c+0)*COUT+o], wc0 = WcdT[(c+0)*COUT+o];
    float wd1 = WdT[(c+1)*COUT+o], wc1 = WcdT[(c+1)*COUT+o];
    float wd2 = WdT[(c+2)*COUT+o], wc2 = WcdT[(c+2)*COUT+o];
    float wd3 = WdT[(c+3)*COUT+o], wc3 = WcdT[(c+3)*COUT+o];
#pragma unroll
    for (int pp=0;pp<NP;pp++){
      float4 xv = *(const float4*)&xs[(grp+pp*G)*CINP + c];
      u[pp] = fmaf(xv.x,wd0,fmaf(xv.y,wd1,fmaf(xv.z,wd2,fmaf(xv.w,wd3,u[pp]))));
      v[pp] = fmaf(xv.x,wc0,fmaf(xv.y,wc1,fmaf(xv.z,wc2,fmaf(xv.w,wc3,v[pp]))));
    }
  }
#pragma unroll
  for (int pp=0;pp<NP;pp++){
    int p = grp + pp*G;
    ut[(size_t)(base+p)*COUT + o] = u[pp];
    vt[(size_t)(base+p)*COUT + o] = v[pp];
  }
}

// ---------------- gather pass: h[n,k,o] = ut[m(n,k)][o] + vt[n][o]
template<int COUT>
__global__ __launch_bounds__(256) void ebgather_kernel(
    const int* __restrict__ idx, const float* __restrict__ ut, const float* __restrict__ vt,
    float* __restrict__ hmaxb, float* __restrict__ hminb, float* __restrict__ stats){
  constexpr int CH = COUT/64, NPG = 4;
  int w = threadIdx.x >> 6, lane = threadIdx.x & 63;
  int n0 = (blockIdx.x*4 + w)*NPG;          // global point index
  float s1[CH], s2[CH];
#pragma unroll
  for (int ch=0;ch<CH;ch++){ s1[ch]=0.f; s2[ch]=0.f; }
  for (int pp=0;pp<NPG;pp++){
    int n = n0 + pp;
    int b = n >> 10;
    const int* irow = idx + (size_t)n*KK;
    float vr[CH], hx[CH], hn[CH];
#pragma unroll
    for (int ch=0;ch<CH;ch++){
      vr[ch] = vt[(size_t)n*COUT + ch*64 + lane];
      hx[ch] = -1e30f; hn[ch] = 1e30f;
    }
    for (int k=0;k<KK;k++){
      int m = irow[k];
      const float* urow = ut + (size_t)(b*NN + m)*COUT;
#pragma unroll
      for (int ch=0;ch<CH;ch++){
        float h = urow[ch*64+lane] + vr[ch];
        hx[ch] = fmaxf(hx[ch], h);
        hn[ch] = fminf(hn[ch], h);
        s1[ch] += h;
        s2[ch] = fmaf(h,h,s2[ch]);
      }
    }
#pragma unroll
    for (int ch=0;ch<CH;ch++){
      hmaxb[(size_t)n*COUT + ch*64 + lane] = hx[ch];
      hminb[(size_t)n*COUT + ch*64 + lane] = hn[ch];
    }
  }
#pragma unroll
  for (int ch=0;ch<CH;ch++){
    atomicAdd(&stats[ch*64+lane], s1[ch]);
    atomicAdd(&stats[COUT + ch*64+lane], s2[ch]);
  }
}

// ---------------- apply (finalize folded in): out = lrelu(a*(a>=0?hmax:hmin)+c)
template<int COUT>
__global__ __launch_bounds__(256) void ebapply_kernel(
    const float* __restrict__ hmaxb, const float* __restrict__ hminb,
    const float* __restrict__ stats, const void* __restrict__ g, const void* __restrict__ bb,
    float* __restrict__ outp, int outoff, const int* __restrict__ flagp){
  int t = blockIdx.x*256 + threadIdx.x;
  if (t >= BB*NN*COUT) return;
  const int bf = *flagp;
  int n = t / COUT, o = t % COUT;
  const float inv_count = 1.f/(BB*NN*KK);
  float m = stats[o]*inv_count;
  float var = stats[COUT+o]*inv_count - m*m;
  float a = ldin(g,o,bf)*rsqrtf(fmaxf(var,0.f) + EPSB);
  float c = ldin(bb,o,bf) - m*a;
  float h = (a >= 0.f) ? hmaxb[t] : hminb[t];
  outp[(size_t)n*512 + outoff + o] = lrelu(fmaf(a,h,c));
}

// ---------------- conv5 via MFMA bf16: single pass, writes h fp32 [B*N][1024] + BN stats.
// grid: (B*N/16) x 4 channel segments -> 2048 blocks (8 blocks/CU).
__global__ __launch_bounds__(256) void fc5_mfma(
    const float* __restrict__ xcat, const unsigned short* __restrict__ wb5,
    float* __restrict__ st5, float* __restrict__ hbuf){
  __shared__ unsigned As[16*256];            // 16 rows x 512 bf16
  int tid = threadIdx.x;
  int pblk = blockIdx.x >> 2;
  int seg  = blockIdx.x & 3;
  int n0g = pblk*16;                         // global point row in [0, B*N)
  for (int t = tid; t < 16*256; t += 256){
    int r = t >> 8, d = t & 255;             // d: u32 col (2 bf16)
    float2 xv = *(const float2*)&xcat[(size_t)(n0g + r)*512 + d*2];
    unsigned pk = (unsigned)f2bf(xv.x) | ((unsigned)f2bf(xv.y) << 16);
    int gs = (d >> 2) ^ r;                   // 16B-group swizzle
    As[r*256 + (gs<<2) + (d&3)] = pk;
  }
  __syncthreads();
  int w = tid>>6, lane = tid&63, col = lane&15, quad = lane>>4;
  sbf8 afr[16];
#pragma unroll
  for (int ks=0; ks<16; ks++){
    int gs = (ks*4 + quad) ^ col;
    afr[ks] = *(const sbf8*)((const unsigned short*)As + col*512 + gs*8);
  }
#pragma unroll 1
  for (int i=0;i<4;i++){
    int obase = seg*256 + w*64 + i*16;
    f32x4 acc = {0.f,0.f,0.f,0.f};
#pragma unroll
    for (int ks=0; ks<16; ks++){
      sbf8 bfr = *(const sbf8*)(wb5 + (size_t)(obase+col)*512 + ks*32 + quad*8);
      acc = __builtin_amdgcn_mfma_f32_16x16x32_bf16(afr[ks], bfr, acc, 0, 0, 0);
    }
    float s1 = acc.x+acc.y+acc.z+acc.w;
    float s2 = acc.x*acc.x + acc.y*acc.y + acc.z*acc.z + acc.w*acc.w;
    s1 += __shfl_xor(s1,16,64); s2 += __shfl_xor(s2,16,64);
    s1 += __shfl_xor(s1,32,64); s2 += __shfl_xor(s2,32,64);
    if (lane < 16){
      atomicAdd(&st5[obase+lane], s1);
      atomicAdd(&st5[1024+obase+lane], s2);
    }
    float vr[4] = {acc.x, acc.y, acc.z, acc.w};
#pragma unroll
    for (int r=0;r<4;r++)
      hbuf[(size_t)(n0g + quad*4 + r)*1024 + obase + col] = vr[r];
  }
}

// ---------------- pool over n (finalize folded in): max & mean of lrelu(a*h+c)
__global__ __launch_bounds__(256) void pool5_kernel(
    const float* __restrict__ hbuf, const float* __restrict__ st5,
    const void* __restrict__ g5, const void* __restrict__ b5,
    unsigned* __restrict__ pmax, float* __restrict__ psum,
    const int* __restrict__ flagp){
  const int bf = *flagp;
  int b = blockIdx.x >> 5;                   // 8 batches x 32 n-splits
  int ns = blockIdx.x & 31;
  int o4 = threadIdx.x*4;
  const float inv_count = 1.f/(BB*NN);
  float a[4], c[4];
#pragma unroll
  for (int j=0;j<4;j++){
    int o = o4+j;
    float m = st5[o]*inv_count;
    float var = st5[1024+o]*inv_count - m*m;
    a[j] = ldin(g5,o,bf)*rsqrtf(fmaxf(var,0.f)+EPSB);
    c[j] = ldin(b5,o,bf) - m*a[j];
  }
  float mx0=-1e30f,mx1=-1e30f,mx2=-1e30f,mx3=-1e30f;
  float sm0=0.f,sm1=0.f,sm2=0.f,sm3=0.f;
  for (int n = ns*32; n < ns*32+32; n++){
    float4 h = *(const float4*)&hbuf[(size_t)(b*NN + n)*1024 + o4];
    float t0 = lrelu(fmaf(a[0],h.x,c[0]));
    float t1 = lrelu(fmaf(a[1],h.y,c[1]));
    float t2 = lrelu(fmaf(a[2],h.z,c[2]));
    float t3 = lrelu(fmaf(a[3],h.w,c[3]));
    mx0=fmaxf(mx0,t0); mx1=fmaxf(mx1,t1); mx2=fmaxf(mx2,t2); mx3=fmaxf(mx3,t3);
    sm0+=t0; sm1+=t1; sm2+=t2; sm3+=t3;
  }
  atomicMax(&pmax[b*1024+o4+0], f2u_ord(mx0));
  atomicMax(&pmax[b*1024+o4+1], f2u_ord(mx1));
  atomicMax(&pmax[b*1024+o4+2], f2u_ord(mx2));
  atomicMax(&pmax[b*1024+o4+3], f2u_ord(mx3));
  atomicAdd(&psum[b*1024+o4+0], sm0);
  atomicAdd(&psum[b*1024+o4+1], sm1);
  atomicAdd(&psum[b*1024+o4+2], sm2);
  atomicAdd(&psum[b*1024+o4+3], sm3);
}

__global__ void pool_finalize_kernel(const unsigned* __restrict__ pmax,
                                     const float* __restrict__ psum,
                                     float* __restrict__ pooled){
  int t = blockIdx.x*256+threadIdx.x;
  if (t >= BB*2048) return;
  int b = t >> 11, j = t & 2047;
  pooled[t] = (j < 1024) ? u2f_ord(pmax[b*1024+j]) : psum[b*1024 + (j-1024)] * (1.f/1024.f);
}

// ---------------- FC head
__global__ __launch_bounds__(256) void fc6_kernel(
    const float* __restrict__ pooled, const void* __restrict__ W,
    const void* __restrict__ g, const void* __restrict__ bb, float* __restrict__ y6,
    const int* __restrict__ flagp){
  __shared__ float red[8][256];
  int o = blockIdx.x, tid = threadIdx.x;
  const int bf = *flagp;
  float part[8];
#pragma unroll
  for (int b=0;b<8;b++) part[b]=0.f;
  for (int c=tid;c<2048;c+=256){
    float wv = ldin(W,o*2048+c,bf);
#pragma unroll
    for (int b=0;b<8;b++) part[b] = fmaf(pooled[b*2048+c], wv, part[b]);
  }
#pragma unroll
  for (int b=0;b<8;b++) red[b][tid]=part[b];
  __syncthreads();
  for (int s=128;s;s>>=1){
    if (tid<s){
#pragma unroll
      for (int b=0;b<8;b++) red[b][tid]+=red[b][tid+s];
    }
    __syncthreads();
  }
  if (tid==0){
    float y[8], m=0.f;
#pragma unroll
    for (int b=0;b<8;b++){ y[b]=red[b][0]; m+=y[b]; }
    m *= 0.125f;
    float v=0.f;
#pragma unroll
    for (int b=0;b<8;b++){ float d=y[b]-m; v += d*d; }
    v *= 0.125f;
    float a=ldin(g,o,bf)*rsqrtf(fmaxf(v,0.f)+EPSB), c0=ldin(bb,o,bf)-m*a;
#pragma unroll
    for (int b=0;b<8;b++) y6[b*512+o]=lrelu(fmaf(a,y[b],c0));
  }
}

__global__ __launch_bounds__(256) void fc7_kernel(
    const float* __restrict__ y6, const void* __restrict__ W, const void* __restrict__ bias,
    const void* __restrict__ g, const void* __restrict__ bb, float* __restrict__ y7,
    const int* __restrict__ flagp){
  __shared__ float red[8][256];
  int o = blockIdx.x, tid = threadIdx.x;
  const int bf = *flagp;
  float part[8];
#pragma unroll
  for (int b=0;b<8;b++) part[b]=0.f;
  for (int c=tid;c<512;c+=256){
    float wv = ldin(W,o*512+c,bf);
#pragma unroll
    for (int b=0;b<8;b++) part[b] = fmaf(y6[b*512+c], wv, part[b]);
  }
#pragma unroll
  for (int b=0;b<8;b++) red[b][tid]=part[b];
  __syncthreads();
  for (int s=128;s;s>>=1){
    if (tid<s){
#pragma unroll
      for (int b=0;b<8;b++) red[b][tid]+=red[b][tid+s];
    }
    __syncthreads();
  }
  if (tid==0){
    float bs = ldin(bias,o,bf);
    float y[8], m=0.f;
#pragma unroll
    for (int b=0;b<8;b++){ y[b]=red[b][0]+bs; m+=y[b]; }
    m *= 0.125f;
    float v=0.f;
#pragma unroll
    for (int b=0;b<8;b++){ float d=y[b]-m; v += d*d; }
    v *= 0.125f;
    float a=ldin(g,o,bf)*rsqrtf(fmaxf(v,0.f)+EPSB), c0=ldin(bb,o,bf)-m*a;
#pragma unroll
    for (int b=0;b<8;b++) y7[b*256+o]=lrelu(fmaf(a,y[b],c0));
  }
}

__global__ __launch_bounds__(256) void fc8_kernel(
    const float* __restrict__ y7, const void* __restrict__ W, const void* __restrict__ bias,
    void* __restrict__ out, const int* __restrict__ flagp){
  __shared__ float red[8][256];
  int o = blockIdx.x, tid = threadIdx.x;
  const int bf = *flagp;
  float wv = ldin(W,o*256+tid,bf);
#pragma unroll
  for (int b=0;b<8;b++) red[b][tid] = y7[b*256+tid]*wv;
  __syncthreads();
  for (int s=128;s;s>>=1){
    if (tid<s){
#pragma unroll
      for (int b=0;b<8;b++) red[b][tid]+=red[b][tid+s];
    }
    __syncthreads();
  }
  if (tid==0){
    float bs = ldin(bias,o,bf);
#pragma unroll
    for (int b=0;b<8;b++){
      float r = red[b][0]+bs;
      if (bf) ((bf16*)out)[b*40+o] = __float2bfloat16(r);
      else    ((float*)out)[b*40+o] = r;
    }
  }
}

extern "C" void kernel_launch(void* const* d_in, const int* in_sizes, int n_in,
                              void* d_out, int out_size, void* d_ws, size_t ws_size,
                              hipStream_t stream){
  const void* x    = d_in[0];
  const void* w00  = d_in[1];
  const void* g00  = d_in[2];
  const void* b00  = d_in[3];
  const void* w01  = d_in[4];
  const void* g01  = d_in[5];
  const void* b01  = d_in[6];
  const void* w1   = d_in[7];  const void* g1 = d_in[8];  const void* b1 = d_in[9];
  const void* w2   = d_in[10]; const void* g2 = d_in[11]; const void* b2 = d_in[12];
  const void* w3   = d_in[13]; const void* g3 = d_in[14]; const void* b3 = d_in[15];
  const void* w4   = d_in[16]; const void* g4 = d_in[17]; const void* b4 = d_in[18];
  const void* w5   = d_in[19]; const void* g5 = d_in[20]; const void* b5 = d_in[21];
  const void* w6   = d_in[22]; const void* g6 = d_in[23]; const void* b6 = d_in[24];
  const void* w7   = d_in[25]; const void* bias7 = d_in[26];
  const void* g7   = d_in[27]; const void* b7 = d_in[28];
  const void* w8   = d_in[29]; const void* bias8 = d_in[30];

  float* ws = (float*)d_ws;
  // workspace layout (float offsets)
  size_t o_xc0  = 0;                              // B*N*16
  size_t o_xcat = o_xc0  + (size_t)BB*NN*16;      // B*N*512
  size_t o_negd = o_xcat + (size_t)BB*NN*512;     // B*N*N (u/v/hmax/hmin, then h5)
  size_t o_xx   = o_negd + (size_t)BB*NN*NN;      // B*N (unused)
  size_t o_w1d  = o_xx   + (size_t)BB*NN;         // 12*64
  size_t o_w1c  = o_w1d  + 12*64;
  size_t o_w2d  = o_w1c  + 12*64;                 // 64*64
  size_t o_w2c  = o_w2d  + 64*64;
  size_t o_w3d  = o_w2c  + 64*64;                 // 64*128
  size_t o_w3c  = o_w3d  + 64*128;
  size_t o_w4d  = o_w3c  + 64*128;                // 128*256
  size_t o_w4c  = o_w4d  + 128*256;
  size_t o_wb5  = o_w4c  + 128*256;               // 1024*512 bf16 = 262144 floats
  size_t o_st1  = o_wb5  + 262144;                // 128  (zero region starts here)
  size_t o_st2  = o_st1  + 128;                   // 128
  size_t o_st3  = o_st2  + 128;                   // 256
  size_t o_st4  = o_st3  + 256;                   // 512
  size_t o_st5  = o_st4  + 512;                   // 2048
  size_t o_pmax = o_st5  + 2048;                  // 8*1024 (uint)
  size_t o_psum = o_pmax + 8192;                  // 8*1024
  size_t o_cst  = o_psum + 8192;                  // 16 (conv0 stats; zero region ends)
  size_t o_pool = o_cst  + 16;                    // 8*2048
  size_t o_y6   = o_pool + 16384;                 // 8*512
  size_t o_y7   = o_y6   + 4096;                  // 8*256
  size_t o_idx  = o_y7   + 2048;                  // B*N*20 ints
  size_t o_flag = o_idx  + (size_t)BB*NN*KK;      // 1 int

  // overlays on the negD region (dead after topk):
  size_t o_u    = o_negd;
  size_t o_v    = o_negd + (size_t)BB*NN*256;
  size_t o_hmax = o_negd + (size_t)2*BB*NN*256;
  size_t o_hmin = o_negd + (size_t)3*BB*NN*256;
  size_t o_h5   = o_negd;                         // B*N*1024 (after eb4 apply)

  int* idxp = (int*)(ws + o_idx);
  int* flagp = (int*)(ws + o_flag);
  float* negD = ws + o_negd;
  float* xc0  = ws + o_xc0;
  float* xcat = ws + o_xcat;
  float* up   = ws + o_u;
  float* vp   = ws + o_v;
  float* hxp  = ws + o_hmax;
  float* hnp  = ws + o_hmin;
  unsigned short* wb5 = (unsigned short*)(ws + o_wb5);

  detect_kernel<<<1,64,0,stream>>>((const unsigned*)x, flagp);

  int nz = 128+128+256+512+2048+8192+8192+16;
  zero_kernel<<<(nz+255)/256, 256, 0, stream>>>((unsigned*)(ws + o_st1), nz);

  conv0_stats_kernel<<<32,256,0,stream>>>(x, w00, w01, ws+o_cst, flagp);
  conv0_apply_kernel<<<32,256,0,stream>>>(x, w00,g00,b00, w01,g01,b01, ws+o_cst, xc0, flagp);

  wuv_kernel<<<(12*64+255)/256,  256,0,stream>>>(w1, ws+o_w1d, ws+o_w1c,   9,  12,  64, flagp);
  wuv_kernel<<<(64*64+255)/256,  256,0,stream>>>(w2, ws+o_w2d, ws+o_w2c,  64,  64,  64, flagp);
  wuv_kernel<<<(64*128+255)/256, 256,0,stream>>>(w3, ws+o_w3d, ws+o_w3c,  64,  64, 128, flagp);
  wuv_kernel<<<(128*256+255)/256,256,0,stream>>>(w4, ws+o_w4d, ws+o_w4c, 128, 128, 256, flagp);
  wb5prep_kernel<<<(1024*512+255)/256,256,0,stream>>>(w5, wb5, flagp);

  dim3 kgrid(NN/128, NN/128, BB);               // 512 blocks
  const size_t KLDS16 = (2*128*16 + 256)*4;     // CR=12 (KCH=16)
  const size_t KLDS64 = (2*128*64 + 256)*4;     // CR=64/128 (KCH=64)
  const int UVG = BB*NN/16;    // 512 blocks
  const int GG  = BB*NN/16;    // 512 blocks (4 waves x 4 points)

  // ---- edge block 1: src=xc0 (ld16, C=9), Cout=64 -> xcat[:,0:64)
  knndist_kernel<<<kgrid,256, KLDS16, stream>>>(xc0, 16, 0, 12, negD);
  topk_kernel<<<BB*NN/4,256,0,stream>>>(negD, idxp);
  uvgemm_kernel<12,64><<<UVG,256,0,stream>>>(xc0, 16, 0, ws+o_w1d, ws+o_w1c, up, vp);
  ebgather_kernel<64><<<GG,256,0,stream>>>(idxp, up, vp, hxp, hnp, ws+o_st1);
  ebapply_kernel<64><<<BB*NN*64/256,256,0,stream>>>(hxp, hnp, ws+o_st1, g1, b1, xcat, 0, flagp);

  // ---- edge block 2: src=x1, Cout=64 -> xcat[:,64:128)
  knndist_kernel<<<kgrid,256, KLDS64, stream>>>(xcat, 512, 0, 64, negD);
  topk_kernel<<<BB*NN/4,256,0,stream>>>(negD, idxp);
  uvgemm_kernel<64,64><<<UVG,256,0,stream>>>(xcat, 512, 0, ws+o_w2d, ws+o_w2c, up, vp);
  ebgather_kernel<64><<<GG,256,0,stream>>>(idxp, up, vp, hxp, hnp, ws+o_st2);
  ebapply_kernel<64><<<BB*NN*64/256,256,0,stream>>>(hxp, hnp, ws+o_st2, g2, b2, xcat, 64, flagp);

  // ---- edge block 3: src=x2, Cout=128 -> xcat[:,128:256)
  knndist_kernel<<<kgrid,256, KLDS64, stream>>>(xcat, 512, 64, 64, negD);
  topk_kernel<<<BB*NN/4,256,0,stream>>>(negD, idxp);
  uvgemm_kernel<64,128><<<UVG,256,0,stream>>>(xcat, 512, 64, ws+o_w3d, ws+o_w3c, up, vp);
  ebgather_kernel<128><<<GG,256,0,stream>>>(idxp, up, vp, hxp, hnp, ws+o_st3);
  ebapply_kernel<128><<<BB*NN*128/256,256,0,stream>>>(hxp, hnp, ws+o_st3, g3, b3, xcat, 128, flagp);

  // ---- edge block 4: src=x3, Cout=256 -> xcat[:,256:512)
  knndist_kernel<<<kgrid,256, KLDS64, stream>>>(xcat, 512, 128, 128, negD);
  topk_kernel<<<BB*NN/4,256,0,stream>>>(negD, idxp);
  uvgemm_kernel<128,256><<<UVG,256,0,stream>>>(xcat, 512, 128, ws+o_w4d, ws+o_w4c, up, vp);
  ebgather_kernel<256><<<GG,256,0,stream>>>(idxp, up, vp, hxp, hnp, ws+o_st4);
  ebapply_kernel<256><<<BB*NN*256/256,256,0,stream>>>(hxp, hnp, ws+o_st4, g4, b4, xcat, 256, flagp);

  // ---- conv5 (512 -> 1024) MFMA single pass + BN + lrelu + pool
  fc5_mfma<<<(BB*NN/16)*4,256,0,stream>>>(xcat, wb5, ws+o_st5, ws+o_h5);
  pool5_kernel<<<BB*32,256,0,stream>>>(ws+o_h5, ws+o_st5, g5, b5,
                                       (unsigned*)(ws+o_pmax), ws+o_psum, flagp);
  pool_finalize_kernel<<<(BB*2048+255)/256,256,0,stream>>>((unsigned*)(ws+o_pmax), ws+o_psum, ws+o_pool);

  // ---- FC head
  fc6_kernel<<<512,256,0,stream>>>(ws+o_pool, w6, g6, b6, ws+o_y6, flagp);
  fc7_kernel<<<256,256,0,stream>>>(ws+o_y6, w7, bias7, g7, b7, ws+o_y7, flagp);
  fc8_kernel<<<40,256,0,stream>>>(ws+o_y7, w8, bias8, d_out, flagp);
}

// Round 9
// 821.185 us; speedup vs baseline: 14.4483x; 1.0202x over previous
//
#include <hip/hip_runtime.h>
#include <hip/hip_bf16.h>

#define BB 8
#define NN 1024
#define KK 20
#define EPSB 1e-5f

typedef __hip_bfloat16 bf16;
typedef __attribute__((ext_vector_type(8))) short sbf8;   // 8 bf16 = 4 VGPRs
typedef __attribute__((ext_vector_type(4))) float f32x4;

__device__ __forceinline__ float lrelu(float t){ return t >= 0.f ? t : 0.2f*t; }
// dtype-flag-aware input load: flag=1 -> bf16, flag=0 -> fp32
__device__ __forceinline__ float ldin(const void* p, int i, int bf){
  return bf ? __bfloat162float(((const bf16*)p)[i]) : ((const float*)p)[i];
}
__device__ __forceinline__ unsigned short f2bf(float f){   // RNE fp32->bf16 bits
  unsigned u = __float_as_uint(f);
  return (unsigned short)((u + 0x7FFFu + ((u>>16)&1u)) >> 16);
}
__device__ __forceinline__ unsigned f2u_ord(float f){
  unsigned u = __float_as_uint(f);
  return (u & 0x80000000u) ? ~u : (u | 0x80000000u);
}
__device__ __forceinline__ float u2f_ord(unsigned u){
  return (u & 0x80000000u) ? __uint_as_float(u & 0x7fffffffu) : __uint_as_float(~u);
}

// ---------------- dtype detection (fp32 words of N(0,1) data never have exp>=0xD0)
__global__ void detect_kernel(const unsigned* __restrict__ xw, int* __restrict__ flag){
  int t = threadIdx.x;
  unsigned w = xw[t];
  unsigned e = (w >> 23) & 0xFFu;
  unsigned long long m = __ballot(e >= 0xD0u);
  if (t == 0) *flag = (__popcll(m) >= 32) ? 1 : 0;
}

__global__ void zero_kernel(unsigned* __restrict__ p, int n){
  int i = blockIdx.x*256 + threadIdx.x;
  if (i < n) p[i] = 0u;
}

// ---------------- conv0 stats: 32 blocks, 1 point/thread, shuffle-reduce + atomics
__global__ __launch_bounds__(256) void conv0_stats_kernel(
    const void* __restrict__ x,
    const void* __restrict__ w00, const void* __restrict__ w01,
    float* __restrict__ cstat, const int* __restrict__ flagp){
  const int bf = *flagp;
  int i = blockIdx.x*256 + threadIdx.x;
  int b = i >> 10, n = i & 1023;
  float wz[4], wy[4];
#pragma unroll
  for (int j=0;j<4;j++){ wz[j]=ldin(w00,j,bf); wy[j]=ldin(w01,j,bf); }
  float x0 = ldin(x,(b*3+0)*NN + n,bf);
  float x1 = ldin(x,(b*3+1)*NN + n,bf);
  float x2 = ldin(x,(b*3+2)*NN + n,bf);
  float vals[6];
  vals[0] = wz[0]*x0 + wz[1]*x1;  vals[1] = wz[2]*x0 + wz[3]*x1;   // z (w00, ch 0,1)
  vals[2] = wy[0]*x0 + wy[1]*x2;  vals[3] = wy[2]*x0 + wy[3]*x2;   // y (w01, ch 0,2)
  vals[4] = wy[0]*x1 + wy[1]*x2;  vals[5] = wy[2]*x1 + wy[3]*x2;   // u (w01, ch 1,2)
  int lane = threadIdx.x & 63;
#pragma unroll
  for (int j=0;j<6;j++){
    float s1 = vals[j], s2 = vals[j]*vals[j];
#pragma unroll
    for (int off=32; off; off>>=1){
      s1 += __shfl_xor(s1, off, 64);
      s2 += __shfl_xor(s2, off, 64);
    }
    if (lane == 0){
      atomicAdd(&cstat[2*j], s1);
      atomicAdd(&cstat[2*j+1], s2);
    }
  }
}

// ---------------- conv0 apply: BN+lrelu+gate, writes xc0 rows (16 floats, padded)
__global__ __launch_bounds__(256) void conv0_apply_kernel(
    const void* __restrict__ x,
    const void* __restrict__ w00, const void* __restrict__ g00, const void* __restrict__ b00,
    const void* __restrict__ w01, const void* __restrict__ g01, const void* __restrict__ b01,
    const float* __restrict__ cstat, float* __restrict__ xc0,
    const int* __restrict__ flagp){
  const int bf = *flagp;
  int i = blockIdx.x*256 + threadIdx.x;
  int b = i >> 10, n = i & 1023;
  float wz[4], wy[4];
#pragma unroll
  for (int j=0;j<4;j++){ wz[j]=ldin(w00,j,bf); wy[j]=ldin(w01,j,bf); }
  float sA[6], sC[6];
#pragma unroll
  for (int j=0;j<6;j++){
    float m = cstat[2*j] * (1.f/(BB*NN));
    float v = cstat[2*j+1] * (1.f/(BB*NN)) - m*m;
    float g, bv;
    if (j<2){ g=ldin(g00,j,bf); bv=ldin(b00,j,bf); }
    else if (j<4){ g=ldin(g01,j-2,bf); bv=ldin(b01,j-2,bf); }
    else { g=ldin(g01,j-4,bf); bv=ldin(b01,j-4,bf); }
    float a = g * rsqrtf(fmaxf(v,0.f) + EPSB);
    sA[j]=a; sC[j]=bv - m*a;
  }
  float x0 = ldin(x,(b*3+0)*NN + n,bf);
  float x1 = ldin(x,(b*3+1)*NN + n,bf);
  float x2 = ldin(x,(b*3+2)*NN + n,bf);
  float z0 = wz[0]*x0 + wz[1]*x1, z1 = wz[2]*x0 + wz[3]*x1;
  float y0 = wy[0]*x0 + wy[1]*x2, y1 = wy[2]*x0 + wy[3]*x2;
  float u0 = wy[0]*x1 + wy[1]*x2, u1 = wy[2]*x1 + wy[3]*x2;
  float* row = xc0 + (size_t)i*16;
  float4 r0, r1, r2, r3;
  r0.x=x0; r0.y=x1; r0.z=x2;
  r0.w=lrelu(sA[4]*u0+sC[4])*x0;
  r1.x=lrelu(sA[5]*u1+sC[5])*x0;
  r1.y=lrelu(sA[2]*y0+sC[2])*x1;
  r1.z=lrelu(sA[3]*y1+sC[3])*x1;
  r1.w=lrelu(sA[0]*z0+sC[0])*x2;
  r2.x=lrelu(sA[1]*z1+sC[1])*x2;
  r2.y=0.f; r2.z=0.f; r2.w=0.f;
  r3.x=0.f; r3.y=0.f; r3.z=0.f; r3.w=0.f;
  *(float4*)&row[0]  = r0;
  *(float4*)&row[4]  = r1;
  *(float4*)&row[8]  = r2;
  *(float4*)&row[12] = r3;
}

// ---------------- weight prep element: WdT[c][o]=W[o][c], WcdT[c][o]=W[o][CIN+c]-W[o][c]
__device__ __forceinline__ void wuv_elem(const void* W, float* WdT, float* WcdT,
                                         int CIN, int COUT, int t, int bf){
  int c = t / COUT, o = t % COUT;
  if (c < CIN){
    float wd = ldin(W, o*(2*CIN)+c, bf);
    float wc = ldin(W, o*(2*CIN)+CIN+c, bf);
    WdT[t] = wd; WcdT[t] = wc - wd;
  } else {
    WdT[t] = 0.f; WcdT[t] = 0.f;
  }
}

// ---------------- single fused weight-prep launch (4x wuv + wb5 pack)
__global__ __launch_bounds__(256) void prep_kernel(
    const void* __restrict__ w1, const void* __restrict__ w2,
    const void* __restrict__ w3, const void* __restrict__ w4,
    const void* __restrict__ w5,
    float* __restrict__ w1d, float* __restrict__ w1c,
    float* __restrict__ w2d, float* __restrict__ w2c,
    float* __restrict__ w3d, float* __restrict__ w3c,
    float* __restrict__ w4d, float* __restrict__ w4c,
    unsigned short* __restrict__ wb5, const int* __restrict__ flagp){
  int t = blockIdx.x*256 + threadIdx.x;
  const int bf = *flagp;
  if (t < 768){ wuv_elem(w1, w1d, w1c, 9, 64, t, bf); return; }
  t -= 768;
  if (t < 4096){ wuv_elem(w2, w2d, w2c, 64, 64, t, bf); return; }
  t -= 4096;
  if (t < 8192){ wuv_elem(w3, w3d, w3c, 64, 128, t, bf); return; }
  t -= 8192;
  if (t < 32768){ wuv_elem(w4, w4d, w4c, 128, 256, t, bf); return; }
  t -= 32768;
  if (t < 1024*512) wb5[t] = f2bf(ldin(w5, t, bf));
}

// ---------------- fused negdist (with on-the-fly row norms): 128x128 tiles, 8x8 acc
// launch_bounds(256,2): ~150 live VGPRs (acc64+av32+stage) — default cap spilled.
__global__ __launch_bounds__(256, 2) void knndist_kernel(
    const float* __restrict__ src, int ld, int coff, int CR,
    float* __restrict__ negD){
  extern __shared__ float lds[];
  const int KCH = (CR >= 64) ? 64 : 16;     // CR=12 -> 16 (xc0 cols 9..15 are zero)
  const int NG  = KCH >> 2;                 // 16B groups per row
  const int GM  = NG - 1;
  float* At = lds;
  float* Bt = lds + 128*KCH;
  float* xn = Bt + 128*KCH;                 // [0..127]=A norms, [128..255]=B norms
  int b = blockIdx.z, i0 = blockIdx.y*128, j0 = blockIdx.x*128;
  int tid = threadIdx.x;
  int ti = tid >> 4, tj = tid & 15;
  int gsa = ti & GM, gsb = tj & GM;
  float acc[8][8];
#pragma unroll
  for (int u=0;u<8;u++)
#pragma unroll
    for (int v=0;v<8;v++) acc[u][v]=0.f;
  float mynorm = 0.f;
  int nch = (CR + KCH - 1)/KCH;             // 1 (CR<=64) or 2 (CR=128)
  for (int ch=0; ch<nch; ch++){
    int c0 = ch*KCH;
    __syncthreads();
    for (int t = tid; t < 2*128*NG; t += 256){
      int half = (t >= 128*NG);
      int tt = half ? t - 128*NG : t;
      int r = tt / NG, g = tt % NG;
      int base = half ? j0 : i0;
      float4 f = *(const float4*)&src[(size_t)(b*NN + base + r)*ld + coff + c0 + g*4];
      int gs = g ^ ((r>>3) & GM);
      float* dst = (half ? Bt : At) + r*KCH + gs*4;
      *(float4*)dst = f;
    }
    __syncthreads();
    {
      int r = tid & 127;
      const float* rowp = ((tid < 128) ? At : Bt) + r*KCH;
      float s = 0.f;
      for (int g=0; g<NG; g++){
        float4 f = *(const float4*)&rowp[g*4];
        s += f.x*f.x + f.y*f.y + f.z*f.z + f.w*f.w;
      }
      mynorm += s;
    }
    for (int g=0; g<NG; g++){
      float4 av[8];
#pragma unroll
      for (int u=0;u<8;u++)
        av[u] = *(const float4*)&At[(ti*8+u)*KCH + ((g ^ gsa)<<2)];
#pragma unroll
      for (int v=0;v<8;v++){
        float4 bv = *(const float4*)&Bt[(tj*8+v)*KCH + ((g ^ gsb)<<2)];
#pragma unroll
        for (int u=0;u<8;u++)
          acc[u][v] += av[u].x*bv.x + av[u].y*bv.y + av[u].z*bv.z + av[u].w*bv.w;
      }
    }
  }
  __syncthreads();
  xn[(tid < 128 ? 0 : 128) + (tid & 127)] = mynorm;
  __syncthreads();
  float xi[8], xj[8];
#pragma unroll
  for (int u=0;u<8;u++){ xi[u] = xn[ti*8+u]; xj[u] = xn[128 + tj*8+u]; }
#pragma unroll
  for (int u=0;u<8;u++){
    float* orow = &negD[((size_t)(b*NN + i0 + ti*8 + u))*NN + j0 + tj*8];
#pragma unroll
    for (int vg=0; vg<2; vg++){
      float4 ov;
      ov.x = 2.f*acc[u][vg*4+0] - xi[u] - xj[vg*4+0];
      ov.y = 2.f*acc[u][vg*4+1] - xi[u] - xj[vg*4+1];
      ov.z = 2.f*acc[u][vg*4+2] - xi[u] - xj[vg*4+2];
      ov.w = 2.f*acc[u][vg*4+3] - xi[u] - xj[vg*4+3];
      *(float4*)&orow[vg*4] = ov;
    }
  }
}

// ---------------- top-20: one wave per row; registers + 64-lane butterfly argmax
__global__ __launch_bounds__(256, 4) void topk_kernel(const float* __restrict__ negD,
                                                      int* __restrict__ idx){
  int row_id = (blockIdx.x*256 + threadIdx.x) >> 6;
  int lane = threadIdx.x & 63;
  if (row_id >= BB*NN) return;
  const float* row = negD + (size_t)row_id*NN;
  float v[16];
#pragma unroll
  for (int j=0;j<4;j++){
    float4 f = *(const float4*)&row[j*256 + lane*4];
    v[j*4+0]=f.x; v[j*4+1]=f.y; v[j*4+2]=f.z; v[j*4+3]=f.w;
  }
  int* orow = idx + (size_t)row_id*KK;
  for (int k=0;k<KK;k++){
    float bv = v[0]; int bs = 0;
#pragma unroll
    for (int s=1;s<16;s++){ if (v[s] > bv){ bv = v[s]; bs = s; } }
    int bidx = (bs>>2)*256 + lane*4 + (bs&3);
    unsigned long long key = ((unsigned long long)f2u_ord(bv) << 32) | (unsigned)(1023 - bidx);
#pragma unroll
    for (int off=32; off; off>>=1){
      unsigned long long o = __shfl_xor(key, off, 64);
      if (o > key) key = o;
    }
    int widx = 1023 - (int)(key & 0xFFFFFFFFu);
    if (lane == 0) orow[k] = widx;
    bool mine = (((widx >> 2) & 63) == lane);
    int wslot = ((widx >> 8) << 2) | (widx & 3);
#pragma unroll
    for (int s=0;s<16;s++){
      if (mine && s == wslot) v[s] = -1e30f;
    }
  }
}

// ---------------- u/v GEMM: ut[n][o]=Wd.x[n], vt[n][o]=(Wc-Wd).x[n]  (fp32 exact)
template<int CINP,int COUT>
__global__ __launch_bounds__(256, 4) void uvgemm_kernel(
    const float* __restrict__ srcT, int ld, int coff,
    const float* __restrict__ WdT, const float* __restrict__ WcdT,
    float* __restrict__ ut, float* __restrict__ vt){
  constexpr int PT=16, G = 256/COUT, NP = PT/G;
  __shared__ float xs[PT*CINP];
  int tid = threadIdx.x;
  int base = blockIdx.x*PT;                 // global point index
  for (int t=tid; t<PT*CINP; t+=256){
    int p = t / CINP, c = t % CINP;
    xs[t] = srcT[(size_t)(base+p)*ld + coff + c];
  }
  __syncthreads();
  int o = tid % COUT, grp = tid / COUT;
  float u[NP], v[NP];
#pragma unroll
  for (int pp=0;pp<NP;pp++){ u[pp]=0.f; v[pp]=0.f; }
  for (int c=0;c<CINP;c+=4){
    float wd0 = WdT[(c+0)*COUT+o], wc0 = WcdT[(c+0)*COUT+o];
    float wd1 = WdT[(c+1)*COUT+o], wc1 = WcdT[(c+1)*COUT+o];
    float wd2 = WdT[(c+2)*COUT+o], wc2 = WcdT[(c+2)*COUT+o];
    float wd3 = WdT[(c+3)*COUT+o], wc3 = WcdT[(c+3)*COUT+o];
#pragma unroll
    for (int pp=0;pp<NP;pp++){
      float4 xv = *(const float4*)&xs[(grp+pp*G)*CINP + c];
      u[pp] = fmaf(xv.x,wd0,fmaf(xv.y,wd1,fmaf(xv.z,wd2,fmaf(xv.w,wd3,u[pp]))));
      v[pp] = fmaf(xv.x,wc0,fmaf(xv.y,wc1,fmaf(xv.z,wc2,fmaf(xv.w,wc3,v[pp]))));
    }
  }
#pragma unroll
  for (int pp=0;pp<NP;pp++){
    int p = grp + pp*G;
    ut[(size_t)(base+p)*COUT + o] = u[pp];
    vt[(size_t)(base+p)*COUT + o] = v[pp];
  }
}

// ---------------- gather pass: h[n,k,o] = ut[m(n,k)][o] + vt[n][o]
template<int COUT>
__global__ __launch_bounds__(256, 4) void ebgather_kernel(
    const int* __restrict__ idx, const float* __restrict__ ut, const float* __restrict__ vt,
    float* __restrict__ hmaxb, float* __restrict__ hminb, float* __restrict__ stats){
  constexpr int CH = COUT/64, NPG = 4;
  int w = threadIdx.x >> 6, lane = threadIdx.x & 63;
  int n0 = (blockIdx.x*4 + w)*NPG;          // global point index
  float s1[CH], s2[CH];
#pragma unroll
  for (int ch=0;ch<CH;ch++){ s1[ch]=0.f; s2[ch]=0.f; }
  for (int pp=0;pp<NPG;pp++){
    int n = n0 + pp;
    int b = n >> 10;
    const int* irow = idx + (size_t)n*KK;
    float vr[CH], hx[CH], hn[CH];
#pragma unroll
    for (int ch=0;ch<CH;ch++){
      vr[ch] = vt[(size_t)n*COUT + ch*64 + lane];
      hx[ch] = -1e30f; hn[ch] = 1e30f;
    }
    for (int k=0;k<KK;k++){
      int m = irow[k];
      const float* urow = ut + (size_t)(b*NN + m)*COUT;
#pragma unroll
      for (int ch=0;ch<CH;ch++){
        float h = urow[ch*64+lane] + vr[ch];
        hx[ch] = fmaxf(hx[ch], h);
        hn[ch] = fminf(hn[ch], h);
        s1[ch] += h;
        s2[ch] = fmaf(h,h,s2[ch]);
      }
    }
#pragma unroll
    for (int ch=0;ch<CH;ch++){
      hmaxb[(size_t)n*COUT + ch*64 + lane] = hx[ch];
      hminb[(size_t)n*COUT + ch*64 + lane] = hn[ch];
    }
  }
#pragma unroll
  for (int ch=0;ch<CH;ch++){
    atomicAdd(&stats[ch*64+lane], s1[ch]);
    atomicAdd(&stats[COUT + ch*64+lane], s2[ch]);
  }
}

// ---------------- apply (finalize folded in): out = lrelu(a*(a>=0?hmax:hmin)+c)
template<int COUT>
__global__ __launch_bounds__(256) void ebapply_kernel(
    const float* __restrict__ hmaxb, const float* __restrict__ hminb,
    const float* __restrict__ stats, const void* __restrict__ g, const void* __restrict__ bb,
    float* __restrict__ outp, int outoff, const int* __restrict__ flagp){
  int t = blockIdx.x*256 + threadIdx.x;
  if (t >= BB*NN*COUT) return;
  const int bf = *flagp;
  int n = t / COUT, o = t % COUT;
  const float inv_count = 1.f/(BB*NN*KK);
  float m = stats[o]*inv_count;
  float var = stats[COUT+o]*inv_count - m*m;
  float a = ldin(g,o,bf)*rsqrtf(fmaxf(var,0.f) + EPSB);
  float c = ldin(bb,o,bf) - m*a;
  float h = (a >= 0.f) ? hmaxb[t] : hminb[t];
  outp[(size_t)n*512 + outoff + o] = lrelu(fmaf(a,h,c));
}

// ---------------- conv5 via MFMA bf16: single pass, writes h fp32 [B*N][1024] + BN stats.
// launch_bounds(256,3): afr[16]=64 VGPRs + bfr batch — default cap (48) spilled afr.
__global__ __launch_bounds__(256, 3) void fc5_mfma(
    const float* __restrict__ xcat, const unsigned short* __restrict__ wb5,
    float* __restrict__ st5, float* __restrict__ hbuf){
  __shared__ unsigned As[16*256];            // 16 rows x 512 bf16
  int tid = threadIdx.x;
  int pblk = blockIdx.x >> 2;
  int seg  = blockIdx.x & 3;
  int n0g = pblk*16;                         // global point row in [0, B*N)
  for (int t = tid; t < 16*256; t += 256){
    int r = t >> 8, d = t & 255;             // d: u32 col (2 bf16)
    float2 xv = *(const float2*)&xcat[(size_t)(n0g + r)*512 + d*2];
    unsigned pk = (unsigned)f2bf(xv.x) | ((unsigned)f2bf(xv.y) << 16);
    int gs = (d >> 2) ^ r;                   // 16B-group swizzle
    As[r*256 + (gs<<2) + (d&3)] = pk;
  }
  __syncthreads();
  int w = tid>>6, lane = tid&63, col = lane&15, quad = lane>>4;
  sbf8 afr[16];
#pragma unroll
  for (int ks=0; ks<16; ks++){
    int gs = (ks*4 + quad) ^ col;
    afr[ks] = *(const sbf8*)((const unsigned short*)As + col*512 + gs*8);
  }
#pragma unroll 1
  for (int i=0;i<4;i++){
    int obase = seg*256 + w*64 + i*16;
    f32x4 acc = {0.f,0.f,0.f,0.f};
#pragma unroll
    for (int ks=0; ks<16; ks++){
      sbf8 bfr = *(const sbf8*)(wb5 + (size_t)(obase+col)*512 + ks*32 + quad*8);
      acc = __builtin_amdgcn_mfma_f32_16x16x32_bf16(afr[ks], bfr, acc, 0, 0, 0);
    }
    float s1 = acc.x+acc.y+acc.z+acc.w;
    float s2 = acc.x*acc.x + acc.y*acc.y + acc.z*acc.z + acc.w*acc.w;
    s1 += __shfl_xor(s1,16,64); s2 += __shfl_xor(s2,16,64);
    s1 += __shfl_xor(s1,32,64); s2 += __shfl_xor(s2,32,64);
    if (lane < 16){
      atomicAdd(&st5[obase+lane], s1);
      atomicAdd(&st5[1024+obase+lane], s2);
    }
    float vr[4] = {acc.x, acc.y, acc.z, acc.w};
#pragma unroll
    for (int r=0;r<4;r++)
      hbuf[(size_t)(n0g + quad*4 + r)*1024 + obase + col] = vr[r];
  }
}

// ---------------- pool over n (finalize folded in): max & mean of lrelu(a*h+c)
__global__ __launch_bounds__(256) void pool5_kernel(
    const float* __restrict__ hbuf, const float* __restrict__ st5,
    const void* __restrict__ g5, const void* __restrict__ b5,
    unsigned* __restrict__ pmax, float* __restrict__ psum,
    const int* __restrict__ flagp){
  const int bf = *flagp;
  int b = blockIdx.x >> 5;                   // 8 batches x 32 n-splits
  int ns = blockIdx.x & 31;
  int o4 = threadIdx.x*4;
  const float inv_count = 1.f/(BB*NN);
  float a[4], c[4];
#pragma unroll
  for (int j=0;j<4;j++){
    int o = o4+j;
    float m = st5[o]*inv_count;
    float var = st5[1024+o]*inv_count - m*m;
    a[j] = ldin(g5,o,bf)*rsqrtf(fmaxf(var,0.f)+EPSB);
    c[j] = ldin(b5,o,bf) - m*a[j];
  }
  float mx0=-1e30f,mx1=-1e30f,mx2=-1e30f,mx3=-1e30f;
  float sm0=0.f,sm1=0.f,sm2=0.f,sm3=0.f;
  for (int n = ns*32; n < ns*32+32; n++){
    float4 h = *(const float4*)&hbuf[(size_t)(b*NN + n)*1024 + o4];
    float t0 = lrelu(fmaf(a[0],h.x,c[0]));
    float t1 = lrelu(fmaf(a[1],h.y,c[1]));
    float t2 = lrelu(fmaf(a[2],h.z,c[2]));
    float t3 = lrelu(fmaf(a[3],h.w,c[3]));
    mx0=fmaxf(mx0,t0); mx1=fmaxf(mx1,t1); mx2=fmaxf(mx2,t2); mx3=fmaxf(mx3,t3);
    sm0+=t0; sm1+=t1; sm2+=t2; sm3+=t3;
  }
  atomicMax(&pmax[b*1024+o4+0], f2u_ord(mx0));
  atomicMax(&pmax[b*1024+o4+1], f2u_ord(mx1));
  atomicMax(&pmax[b*1024+o4+2], f2u_ord(mx2));
  atomicMax(&pmax[b*1024+o4+3], f2u_ord(mx3));
  atomicAdd(&psum[b*1024+o4+0], sm0);
  atomicAdd(&psum[b*1024+o4+1], sm1);
  atomicAdd(&psum[b*1024+o4+2], sm2);
  atomicAdd(&psum[b*1024+o4+3], sm3);
}

__global__ void pool_finalize_kernel(const unsigned* __restrict__ pmax,
                                     const float* __restrict__ psum,
                                     float* __restrict__ pooled){
  int t = blockIdx.x*256+threadIdx.x;
  if (t >= BB*2048) return;
  int b = t >> 11, j = t & 2047;
  pooled[t] = (j < 1024) ? u2f_ord(pmax[b*1024+j]) : psum[b*1024 + (j-1024)] * (1.f/1024.f);
}

// ---------------- FC head
__global__ __launch_bounds__(256) void fc6_kernel(
    const float* __restrict__ pooled, const void* __restrict__ W,
    const void* __restrict__ g, const void* __restrict__ bb, float* __restrict__ y6,
    const int* __restrict__ flagp){
  __shared__ float red[8][256];
  int o = blockIdx.x, tid = threadIdx.x;
  const int bf = *flagp;
  float part[8];
#pragma unroll
  for (int b=0;b<8;b++) part[b]=0.f;
  for (int c=tid;c<2048;c+=256){
    float wv = ldin(W,o*2048+c,bf);
#pragma unroll
    for (int b=0;b<8;b++) part[b] = fmaf(pooled[b*2048+c], wv, part[b]);
  }
#pragma unroll
  for (int b=0;b<8;b++) red[b][tid]=part[b];
  __syncthreads();
  for (int s=128;s;s>>=1){
    if (tid<s){
#pragma unroll
      for (int b=0;b<8;b++) red[b][tid]+=red[b][tid+s];
    }
    __syncthreads();
  }
  if (tid==0){
    float y[8], m=0.f;
#pragma unroll
    for (int b=0;b<8;b++){ y[b]=red[b][0]; m+=y[b]; }
    m *= 0.125f;
    float v=0.f;
#pragma unroll
    for (int b=0;b<8;b++){ float d=y[b]-m; v += d*d; }
    v *= 0.125f;
    float a=ldin(g,o,bf)*rsqrtf(fmaxf(v,0.f)+EPSB), c0=ldin(bb,o,bf)-m*a;
#pragma unroll
    for (int b=0;b<8;b++) y6[b*512+o]=lrelu(fmaf(a,y[b],c0));
  }
}

__global__ __launch_bounds__(256) void fc7_kernel(
    const float* __restrict__ y6, const void* __restrict__ W, const void* __restrict__ bias,
    const void* __restrict__ g, const void* __restrict__ bb, float* __restrict__ y7,
    const int* __restrict__ flagp){
  __shared__ float red[8][256];
  int o = blockIdx.x, tid = threadIdx.x;
  const int bf = *flagp;
  float part[8];
#pragma unroll
  for (int b=0;b<8;b++) part[b]=0.f;
  for (int c=tid;c<512;c+=256){
    float wv = ldin(W,o*512+c,bf);
#pragma unroll
    for (int b=0;b<8;b++) part[b] = fmaf(y6[b*512+c], wv, part[b]);
  }
#pragma unroll
  for (int b=0;b<8;b++) red[b][tid]=part[b];
  __syncthreads();
  for (int s=128;s;s>>=1){
    if (tid<s){
#pragma unroll
      for (int b=0;b<8;b++) red[b][tid]+=red[b][tid+s];
    }
    __syncthreads();
  }
  if (tid==0){
    float bs = ldin(bias,o,bf);
    float y[8], m=0.f;
#pragma unroll
    for (int b=0;b<8;b++){ y[b]=red[b][0]+bs; m+=y[b]; }
    m *= 0.125f;
    float v=0.f;
#pragma unroll
    for (int b=0;b<8;b++){ float d=y[b]-m; v += d*d; }
    v *= 0.125f;
    float a=ldin(g,o,bf)*rsqrtf(fmaxf(v,0.f)+EPSB), c0=ldin(bb,o,bf)-m*a;
#pragma unroll
    for (int b=0;b<8;b++) y7[b*256+o]=lrelu(fmaf(a,y[b],c0));
  }
}

__global__ __launch_bounds__(256) void fc8_kernel(
    const float* __restrict__ y7, const void* __restrict__ W, const void* __restrict__ bias,
    void* __restrict__ out, const int* __restrict__ flagp){
  __shared__ float red[8][256];
  int o = blockIdx.x, tid = threadIdx.x;
  const int bf = *flagp;
  float wv = ldin(W,o*256+tid,bf);
#pragma unroll
  for (int b=0;b<8;b++) red[b][tid] = y7[b*256+tid]*wv;
  __syncthreads();
  for (int s=128;s;s>>=1){
    if (tid<s){
#pragma unroll
      for (int b=0;b<8;b++) red[b][tid]+=red[b][tid+s];
    }
    __syncthreads();
  }
  if (tid==0){
    float bs = ldin(bias,o,bf);
#pragma unroll
    for (int b=0;b<8;b++){
      float r = red[b][0]+bs;
      if (bf) ((bf16*)out)[b*40+o] = __float2bfloat16(r);
      else    ((float*)out)[b*40+o] = r;
    }
  }
}

extern "C" void kernel_launch(void* const* d_in, const int* in_sizes, int n_in,
                              void* d_out, int out_size, void* d_ws, size_t ws_size,
                              hipStream_t stream){
  const void* x    = d_in[0];
  const void* w00  = d_in[1];
  const void* g00  = d_in[2];
  const void* b00  = d_in[3];
  const void* w01  = d_in[4];
  const void* g01  = d_in[5];
  const void* b01  = d_in[6];
  const void* w1   = d_in[7];  const void* g1 = d_in[8];  const void* b1 = d_in[9];
  const void* w2   = d_in[10]; const void* g2 = d_in[11]; const void* b2 = d_in[12];
  const void* w3   = d_in[13]; const void* g3 = d_in[14]; const void* b3 = d_in[15];
  const void* w4   = d_in[16]; const void* g4 = d_in[17]; const void* b4 = d_in[18];
  const void* w5   = d_in[19]; const void* g5 = d_in[20]; const void* b5 = d_in[21];
  const void* w6   = d_in[22]; const void* g6 = d_in[23]; const void* b6 = d_in[24];
  const void* w7   = d_in[25]; const void* bias7 = d_in[26];
  const void* g7   = d_in[27]; const void* b7 = d_in[28];
  const void* w8   = d_in[29]; const void* bias8 = d_in[30];

  float* ws = (float*)d_ws;
  // workspace layout (float offsets)
  size_t o_xc0  = 0;                              // B*N*16
  size_t o_xcat = o_xc0  + (size_t)BB*NN*16;      // B*N*512
  size_t o_negd = o_xcat + (size_t)BB*NN*512;     // B*N*N (u/v/hmax/hmin, then h5)
  size_t o_xx   = o_negd + (size_t)BB*NN*NN;      // B*N (unused)
  size_t o_w1d  = o_xx   + (size_t)BB*NN;         // 12*64
  size_t o_w1c  = o_w1d  + 12*64;
  size_t o_w2d  = o_w1c  + 12*64;                 // 64*64
  size_t o_w2c  = o_w2d  + 64*64;
  size_t o_w3d  = o_w2c  + 64*64;                 // 64*128
  size_t o_w3c  = o_w3d  + 64*128;
  size_t o_w4d  = o_w3c  + 64*128;                // 128*256
  size_t o_w4c  = o_w4d  + 128*256;
  size_t o_wb5  = o_w4c  + 128*256;               // 1024*512 bf16 = 262144 floats
  size_t o_st1  = o_wb5  + 262144;                // 128  (zero region starts here)
  size_t o_st2  = o_st1  + 128;                   // 128
  size_t o_st3  = o_st2  + 128;                   // 256
  size_t o_st4  = o_st3  + 256;                   // 512
  size_t o_st5  = o_st4  + 512;                   // 2048
  size_t o_pmax = o_st5  + 2048;                  // 8*1024 (uint)
  size_t o_psum = o_pmax + 8192;                  // 8*1024
  size_t o_cst  = o_psum + 8192;                  // 16 (conv0 stats; zero region ends)
  size_t o_pool = o_cst  + 16;                    // 8*2048
  size_t o_y6   = o_pool + 16384;                 // 8*512
  size_t o_y7   = o_y6   + 4096;                  // 8*256
  size_t o_idx  = o_y7   + 2048;                  // B*N*20 ints
  size_t o_flag = o_idx  + (size_t)BB*NN*KK;      // 1 int

  // overlays on the negD region (dead after topk):
  size_t o_u    = o_negd;
  size_t o_v    = o_negd + (size_t)BB*NN*256;
  size_t o_hmax = o_negd + (size_t)2*BB*NN*256;
  size_t o_hmin = o_negd + (size_t)3*BB*NN*256;
  size_t o_h5   = o_negd;                         // B*N*1024 (after eb4 apply)

  int* idxp = (int*)(ws + o_idx);
  int* flagp = (int*)(ws + o_flag);
  float* negD = ws + o_negd;
  float* xc0  = ws + o_xc0;
  float* xcat = ws + o_xcat;
  float* up   = ws + o_u;
  float* vp   = ws + o_v;
  float* hxp  = ws + o_hmax;
  float* hnp  = ws + o_hmin;
  unsigned short* wb5 = (unsigned short*)(ws + o_wb5);

  detect_kernel<<<1,64,0,stream>>>((const unsigned*)x, flagp);

  int nz = 128+128+256+512+2048+8192+8192+16;
  zero_kernel<<<(nz+255)/256, 256, 0, stream>>>((unsigned*)(ws + o_st1), nz);

  conv0_stats_kernel<<<32,256,0,stream>>>(x, w00, w01, ws+o_cst, flagp);
  conv0_apply_kernel<<<32,256,0,stream>>>(x, w00,g00,b00, w01,g01,b01, ws+o_cst, xc0, flagp);

  // fused weight prep: 4x wuv + wb5 pack (768+4096+8192+32768+524288 = 570112 elems)
  prep_kernel<<<(570112+255)/256,256,0,stream>>>(
      w1,w2,w3,w4,w5,
      ws+o_w1d, ws+o_w1c, ws+o_w2d, ws+o_w2c,
      ws+o_w3d, ws+o_w3c, ws+o_w4d, ws+o_w4c, wb5, flagp);

  dim3 kgrid(NN/128, NN/128, BB);               // 512 blocks
  const size_t KLDS16 = (2*128*16 + 256)*4;     // CR=12 (KCH=16)
  const size_t KLDS64 = (2*128*64 + 256)*4;     // CR=64/128 (KCH=64)
  const int UVG = BB*NN/16;    // 512 blocks
  const int GG  = BB*NN/16;    // 512 blocks (4 waves x 4 points)

  // ---- edge block 1: src=xc0 (ld16, C=9), Cout=64 -> xcat[:,0:64)
  knndist_kernel<<<kgrid,256, KLDS16, stream>>>(xc0, 16, 0, 12, negD);
  topk_kernel<<<BB*NN/4,256,0,stream>>>(negD, idxp);
  uvgemm_kernel<12,64><<<UVG,256,0,stream>>>(xc0, 16, 0, ws+o_w1d, ws+o_w1c, up, vp);
  ebgather_kernel<64><<<GG,256,0,stream>>>(idxp, up, vp, hxp, hnp, ws+o_st1);
  ebapply_kernel<64><<<BB*NN*64/256,256,0,stream>>>(hxp, hnp, ws+o_st1, g1, b1, xcat, 0, flagp);

  // ---- edge block 2: src=x1, Cout=64 -> xcat[:,64:128)
  knndist_kernel<<<kgrid,256, KLDS64, stream>>>(xcat, 512, 0, 64, negD);
  topk_kernel<<<BB*NN/4,256,0,stream>>>(negD, idxp);
  uvgemm_kernel<64,64><<<UVG,256,0,stream>>>(xcat, 512, 0, ws+o_w2d, ws+o_w2c, up, vp);
  ebgather_kernel<64><<<GG,256,0,stream>>>(idxp, up, vp, hxp, hnp, ws+o_st2);
  ebapply_kernel<64><<<BB*NN*64/256,256,0,stream>>>(hxp, hnp, ws+o_st2, g2, b2, xcat, 64, flagp);

  // ---- edge block 3: src=x2, Cout=128 -> xcat[:,128:256)
  knndist_kernel<<<kgrid,256, KLDS64, stream>>>(xcat, 512, 64, 64, negD);
  topk_kernel<<<BB*NN/4,256,0,stream>>>(negD, idxp);
  uvgemm_kernel<64,128><<<UVG,256,0,stream>>>(xcat, 512, 64, ws+o_w3d, ws+o_w3c, up, vp);
  ebgather_kernel<128><<<GG,256,0,stream>>>(idxp, up, vp, hxp, hnp, ws+o_st3);
  ebapply_kernel<128><<<BB*NN*128/256,256,0,stream>>>(hxp, hnp, ws+o_st3, g3, b3, xcat, 128, flagp);

  // ---- edge block 4: src=x3, Cout=256 -> xcat[:,256:512)
  knndist_kernel<<<kgrid,256, KLDS64, stream>>>(xcat, 512, 128, 128, negD);
  topk_kernel<<<BB*NN/4,256,0,stream>>>(negD, idxp);
  uvgemm_kernel<128,256><<<UVG,256,0,stream>>>(xcat, 512, 128, ws+o_w4d, ws+o_w4c, up, vp);
  ebgather_kernel<256><<<GG,256,0,stream>>>(idxp, up, vp, hxp, hnp, ws+o_st4);
  ebapply_kernel<256><<<BB*NN*256/256,256,0,stream>>>(hxp, hnp, ws+o_st4, g4, b4, xcat, 256, flagp);

  // ---- conv5 (512 -> 1024) MFMA single pass + BN + lrelu + pool
  fc5_mfma<<<(BB*NN/16)*4,256,0,stream>>>(xcat, wb5, ws+o_st5, ws+o_h5);
  pool5_kernel<<<BB*32,256,0,stream>>>(ws+o_h5, ws+o_st5, g5, b5,
                                       (unsigned*)(ws+o_pmax), ws+o_psum, flagp);
  pool_finalize_kernel<<<(BB*2048+255)/256,256,0,stream>>>((unsigned*)(ws+o_pmax), ws+o_psum, ws+o_pool);

  // ---- FC head
  fc6_kernel<<<512,256,0,stream>>>(ws+o_pool, w6, g6, b6, ws+o_y6, flagp);
  fc7_kernel<<<256,256,0,stream>>>(ws+o_y6, w7, bias7, g7, b7, ws+o_y7, flagp);
  fc8_kernel<<<40,256,0,stream>>>(ws+o_y7, w8, bias8, d_out, flagp);
}

// Round 10
// 800.132 us; speedup vs baseline: 14.8285x; 1.0263x over previous
//
#include <hip/hip_runtime.h>
#include <hip/hip_bf16.h>

#define BB 8
#define NN 1024
#define KK 20
#define EPSB 1e-5f

typedef __hip_bfloat16 bf16;
typedef __attribute__((ext_vector_type(8))) short sbf8;   // 8 bf16 = 4 VGPRs
typedef __attribute__((ext_vector_type(4))) float f32x4;

__device__ __forceinline__ float lrelu(float t){ return t >= 0.f ? t : 0.2f*t; }
// dtype-flag-aware input load: flag=1 -> bf16, flag=0 -> fp32
__device__ __forceinline__ float ldin(const void* p, int i, int bf){
  return bf ? __bfloat162float(((const bf16*)p)[i]) : ((const float*)p)[i];
}
__device__ __forceinline__ unsigned short f2bf(float f){   // RNE fp32->bf16 bits
  unsigned u = __float_as_uint(f);
  return (unsigned short)((u + 0x7FFFu + ((u>>16)&1u)) >> 16);
}
__device__ __forceinline__ unsigned f2u_ord(float f){
  unsigned u = __float_as_uint(f);
  return (u & 0x80000000u) ? ~u : (u | 0x80000000u);
}
__device__ __forceinline__ float u2f_ord(unsigned u){
  return (u & 0x80000000u) ? __uint_as_float(u & 0x7fffffffu) : __uint_as_float(~u);
}

// ---------------- dtype detection (fp32 words of N(0,1) data never have exp>=0xD0)
__global__ void detect_kernel(const unsigned* __restrict__ xw, int* __restrict__ flag){
  int t = threadIdx.x;
  unsigned w = xw[t];
  unsigned e = (w >> 23) & 0xFFu;
  unsigned long long m = __ballot(e >= 0xD0u);
  if (t == 0) *flag = (__popcll(m) >= 32) ? 1 : 0;
}

__global__ void zero_kernel(unsigned* __restrict__ p, int n){
  int i = blockIdx.x*256 + threadIdx.x;
  if (i < n) p[i] = 0u;
}

// ---------------- conv0 stats: 32 blocks, 1 point/thread, shuffle-reduce + atomics
__global__ __launch_bounds__(256) void conv0_stats_kernel(
    const void* __restrict__ x,
    const void* __restrict__ w00, const void* __restrict__ w01,
    float* __restrict__ cstat, const int* __restrict__ flagp){
  const int bf = *flagp;
  int i = blockIdx.x*256 + threadIdx.x;
  int b = i >> 10, n = i & 1023;
  float wz[4], wy[4];
#pragma unroll
  for (int j=0;j<4;j++){ wz[j]=ldin(w00,j,bf); wy[j]=ldin(w01,j,bf); }
  float x0 = ldin(x,(b*3+0)*NN + n,bf);
  float x1 = ldin(x,(b*3+1)*NN + n,bf);
  float x2 = ldin(x,(b*3+2)*NN + n,bf);
  float vals[6];
  vals[0] = wz[0]*x0 + wz[1]*x1;  vals[1] = wz[2]*x0 + wz[3]*x1;   // z (w00, ch 0,1)
  vals[2] = wy[0]*x0 + wy[1]*x2;  vals[3] = wy[2]*x0 + wy[3]*x2;   // y (w01, ch 0,2)
  vals[4] = wy[0]*x1 + wy[1]*x2;  vals[5] = wy[2]*x1 + wy[3]*x2;   // u (w01, ch 1,2)
  int lane = threadIdx.x & 63;
#pragma unroll
  for (int j=0;j<6;j++){
    float s1 = vals[j], s2 = vals[j]*vals[j];
#pragma unroll
    for (int off=32; off; off>>=1){
      s1 += __shfl_xor(s1, off, 64);
      s2 += __shfl_xor(s2, off, 64);
    }
    if (lane == 0){
      atomicAdd(&cstat[2*j], s1);
      atomicAdd(&cstat[2*j+1], s2);
    }
  }
}

// ---------------- conv0 apply: BN+lrelu+gate, writes xc0 rows (16 floats, padded)
__global__ __launch_bounds__(256) void conv0_apply_kernel(
    const void* __restrict__ x,
    const void* __restrict__ w00, const void* __restrict__ g00, const void* __restrict__ b00,
    const void* __restrict__ w01, const void* __restrict__ g01, const void* __restrict__ b01,
    const float* __restrict__ cstat, float* __restrict__ xc0,
    const int* __restrict__ flagp){
  const int bf = *flagp;
  int i = blockIdx.x*256 + threadIdx.x;
  int b = i >> 10, n = i & 1023;
  float wz[4], wy[4];
#pragma unroll
  for (int j=0;j<4;j++){ wz[j]=ldin(w00,j,bf); wy[j]=ldin(w01,j,bf); }
  float sA[6], sC[6];
#pragma unroll
  for (int j=0;j<6;j++){
    float m = cstat[2*j] * (1.f/(BB*NN));
    float v = cstat[2*j+1] * (1.f/(BB*NN)) - m*m;
    float g, bv;
    if (j<2){ g=ldin(g00,j,bf); bv=ldin(b00,j,bf); }
    else if (j<4){ g=ldin(g01,j-2,bf); bv=ldin(b01,j-2,bf); }
    else { g=ldin(g01,j-4,bf); bv=ldin(b01,j-4,bf); }
    float a = g * rsqrtf(fmaxf(v,0.f) + EPSB);
    sA[j]=a; sC[j]=bv - m*a;
  }
  float x0 = ldin(x,(b*3+0)*NN + n,bf);
  float x1 = ldin(x,(b*3+1)*NN + n,bf);
  float x2 = ldin(x,(b*3+2)*NN + n,bf);
  float z0 = wz[0]*x0 + wz[1]*x1, z1 = wz[2]*x0 + wz[3]*x1;
  float y0 = wy[0]*x0 + wy[1]*x2, y1 = wy[2]*x0 + wy[3]*x2;
  float u0 = wy[0]*x1 + wy[1]*x2, u1 = wy[2]*x1 + wy[3]*x2;
  float* row = xc0 + (size_t)i*16;
  float4 r0, r1, r2, r3;
  r0.x=x0; r0.y=x1; r0.z=x2;
  r0.w=lrelu(sA[4]*u0+sC[4])*x0;
  r1.x=lrelu(sA[5]*u1+sC[5])*x0;
  r1.y=lrelu(sA[2]*y0+sC[2])*x1;
  r1.z=lrelu(sA[3]*y1+sC[3])*x1;
  r1.w=lrelu(sA[0]*z0+sC[0])*x2;
  r2.x=lrelu(sA[1]*z1+sC[1])*x2;
  r2.y=0.f; r2.z=0.f; r2.w=0.f;
  r3.x=0.f; r3.y=0.f; r3.z=0.f; r3.w=0.f;
  *(float4*)&row[0]  = r0;
  *(float4*)&row[4]  = r1;
  *(float4*)&row[8]  = r2;
  *(float4*)&row[12] = r3;
}

// ---------------- weight prep element: WdT[c][o]=W[o][c], WcdT[c][o]=W[o][CIN+c]-W[o][c]
__device__ __forceinline__ void wuv_elem(const void* W, float* WdT, float* WcdT,
                                         int CIN, int COUT, int t, int bf){
  int c = t / COUT, o = t % COUT;
  if (c < CIN){
    float wd = ldin(W, o*(2*CIN)+c, bf);
    float wc = ldin(W, o*(2*CIN)+CIN+c, bf);
    WdT[t] = wd; WcdT[t] = wc - wd;
  } else {
    WdT[t] = 0.f; WcdT[t] = 0.f;
  }
}

// ---------------- single fused weight-prep launch (4x wuv + wb5 pack)
__global__ __launch_bounds__(256) void prep_kernel(
    const void* __restrict__ w1, const void* __restrict__ w2,
    const void* __restrict__ w3, const void* __restrict__ w4,
    const void* __restrict__ w5,
    float* __restrict__ w1d, float* __restrict__ w1c,
    float* __restrict__ w2d, float* __restrict__ w2c,
    float* __restrict__ w3d, float* __restrict__ w3c,
    float* __restrict__ w4d, float* __restrict__ w4c,
    unsigned short* __restrict__ wb5, const int* __restrict__ flagp){
  int t = blockIdx.x*256 + threadIdx.x;
  const int bf = *flagp;
  if (t < 768){ wuv_elem(w1, w1d, w1c, 9, 64, t, bf); return; }
  t -= 768;
  if (t < 4096){ wuv_elem(w2, w2d, w2c, 64, 64, t, bf); return; }
  t -= 4096;
  if (t < 8192){ wuv_elem(w3, w3d, w3c, 64, 128, t, bf); return; }
  t -= 8192;
  if (t < 32768){ wuv_elem(w4, w4d, w4c, 128, 256, t, bf); return; }
  t -= 32768;
  if (t < 1024*512) wb5[t] = f2bf(ldin(w5, t, bf));
}

// ---------------- fused negdist (with on-the-fly row norms): 128x128 tiles, 8x8 acc
__global__ __launch_bounds__(256, 2) void knndist_kernel(
    const float* __restrict__ src, int ld, int coff, int CR,
    float* __restrict__ negD){
  extern __shared__ float lds[];
  const int KCH = (CR >= 64) ? 64 : 16;     // CR=12 -> 16 (xc0 cols 9..15 are zero)
  const int NG  = KCH >> 2;                 // 16B groups per row
  const int GM  = NG - 1;
  float* At = lds;
  float* Bt = lds + 128*KCH;
  float* xn = Bt + 128*KCH;                 // [0..127]=A norms, [128..255]=B norms
  int b = blockIdx.z, i0 = blockIdx.y*128, j0 = blockIdx.x*128;
  int tid = threadIdx.x;
  int ti = tid >> 4, tj = tid & 15;
  int gsa = ti & GM, gsb = tj & GM;
  float acc[8][8];
#pragma unroll
  for (int u=0;u<8;u++)
#pragma unroll
    for (int v=0;v<8;v++) acc[u][v]=0.f;
  float mynorm = 0.f;
  int nch = (CR + KCH - 1)/KCH;             // 1 (CR<=64) or 2 (CR=128)
  for (int ch=0; ch<nch; ch++){
    int c0 = ch*KCH;
    __syncthreads();
    for (int t = tid; t < 2*128*NG; t += 256){
      int half = (t >= 128*NG);
      int tt = half ? t - 128*NG : t;
      int r = tt / NG, g = tt % NG;
      int base = half ? j0 : i0;
      float4 f = *(const float4*)&src[(size_t)(b*NN + base + r)*ld + coff + c0 + g*4];
      int gs = g ^ ((r>>3) & GM);
      float* dst = (half ? Bt : At) + r*KCH + gs*4;
      *(float4*)dst = f;
    }
    __syncthreads();
    {
      int r = tid & 127;
      const float* rowp = ((tid < 128) ? At : Bt) + r*KCH;
      float s = 0.f;
      for (int g=0; g<NG; g++){
        float4 f = *(const float4*)&rowp[g*4];
        s += f.x*f.x + f.y*f.y + f.z*f.z + f.w*f.w;
      }
      mynorm += s;
    }
    for (int g=0; g<NG; g++){
      float4 av[8];
#pragma unroll
      for (int u=0;u<8;u++)
        av[u] = *(const float4*)&At[(ti*8+u)*KCH + ((g ^ gsa)<<2)];
#pragma unroll
      for (int v=0;v<8;v++){
        float4 bv = *(const float4*)&Bt[(tj*8+v)*KCH + ((g ^ gsb)<<2)];
#pragma unroll
        for (int u=0;u<8;u++)
          acc[u][v] += av[u].x*bv.x + av[u].y*bv.y + av[u].z*bv.z + av[u].w*bv.w;
      }
    }
  }
  __syncthreads();
  xn[(tid < 128 ? 0 : 128) + (tid & 127)] = mynorm;
  __syncthreads();
  float xi[8], xj[8];
#pragma unroll
  for (int u=0;u<8;u++){ xi[u] = xn[ti*8+u]; xj[u] = xn[128 + tj*8+u]; }
#pragma unroll
  for (int u=0;u<8;u++){
    float* orow = &negD[((size_t)(b*NN + i0 + ti*8 + u))*NN + j0 + tj*8];
#pragma unroll
    for (int vg=0; vg<2; vg++){
      float4 ov;
      ov.x = 2.f*acc[u][vg*4+0] - xi[u] - xj[vg*4+0];
      ov.y = 2.f*acc[u][vg*4+1] - xi[u] - xj[vg*4+1];
      ov.z = 2.f*acc[u][vg*4+2] - xi[u] - xj[vg*4+2];
      ov.w = 2.f*acc[u][vg*4+3] - xi[u] - xj[vg*4+3];
      *(float4*)&orow[vg*4] = ov;
    }
  }
}

// ---------------- top-20: one wave per row; registers + 64-lane butterfly argmax
__global__ __launch_bounds__(256, 4) void topk_kernel(const float* __restrict__ negD,
                                                      int* __restrict__ idx){
  int row_id = (blockIdx.x*256 + threadIdx.x) >> 6;
  int lane = threadIdx.x & 63;
  if (row_id >= BB*NN) return;
  const float* row = negD + (size_t)row_id*NN;
  float v[16];
#pragma unroll
  for (int j=0;j<4;j++){
    float4 f = *(const float4*)&row[j*256 + lane*4];
    v[j*4+0]=f.x; v[j*4+1]=f.y; v[j*4+2]=f.z; v[j*4+3]=f.w;
  }
  int* orow = idx + (size_t)row_id*KK;
  for (int k=0;k<KK;k++){
    float bv = v[0]; int bs = 0;
#pragma unroll
    for (int s=1;s<16;s++){ if (v[s] > bv){ bv = v[s]; bs = s; } }
    int bidx = (bs>>2)*256 + lane*4 + (bs&3);
    unsigned long long key = ((unsigned long long)f2u_ord(bv) << 32) | (unsigned)(1023 - bidx);
#pragma unroll
    for (int off=32; off; off>>=1){
      unsigned long long o = __shfl_xor(key, off, 64);
      if (o > key) key = o;
    }
    int widx = 1023 - (int)(key & 0xFFFFFFFFu);
    if (lane == 0) orow[k] = widx;
    bool mine = (((widx >> 2) & 63) == lane);
    int wslot = ((widx >> 8) << 2) | (widx & 3);
#pragma unroll
    for (int s=0;s<16;s++){
      if (mine && s == wslot) v[s] = -1e30f;
    }
  }
}

// ---------------- u/v GEMM: ut[n][o]=Wd.x[n], vt[n][o]=(Wc-Wd).x[n]  (fp32 exact)
template<int CINP,int COUT>
__global__ __launch_bounds__(256, 4) void uvgemm_kernel(
    const float* __restrict__ srcT, int ld, int coff,
    const float* __restrict__ WdT, const float* __restrict__ WcdT,
    float* __restrict__ ut, float* __restrict__ vt){
  constexpr int PT=16, G = 256/COUT, NP = PT/G;
  __shared__ float xs[PT*CINP];
  int tid = threadIdx.x;
  int base = blockIdx.x*PT;                 // global point index
  for (int t=tid; t<PT*CINP; t+=256){
    int p = t / CINP, c = t % CINP;
    xs[t] = srcT[(size_t)(base+p)*ld + coff + c];
  }
  __syncthreads();
  int o = tid % COUT, grp = tid / COUT;
  float u[NP], v[NP];
#pragma unroll
  for (int pp=0;pp<NP;pp++){ u[pp]=0.f; v[pp]=0.f; }
  for (int c=0;c<CINP;c+=4){
    float wd0 = WdT[(c+0)*COUT+o], wc0 = WcdT[(c+0)*COUT+o];
    float wd1 = WdT[(c+1)*COUT+o], wc1 = WcdT[(c+1)*COUT+o];
    float wd2 = WdT[(c+2)*COUT+o], wc2 = WcdT[(c+2)*COUT+o];
    float wd3 = WdT[(c+3)*COUT+o], wc3 = WcdT[(c+3)*COUT+o];
#pragma unroll
    for (int pp=0;pp<NP;pp++){
      float4 xv = *(const float4*)&xs[(grp+pp*G)*CINP + c];
      u[pp] = fmaf(xv.x,wd0,fmaf(xv.y,wd1,fmaf(xv.z,wd2,fmaf(xv.w,wd3,u[pp]))));
      v[pp] = fmaf(xv.x,wc0,fmaf(xv.y,wc1,fmaf(xv.z,wc2,fmaf(xv.w,wc3,v[pp]))));
    }
  }
#pragma unroll
  for (int pp=0;pp<NP;pp++){
    int p = grp + pp*G;
    ut[(size_t)(base+p)*COUT + o] = u[pp];
    vt[(size_t)(base+p)*COUT + o] = v[pp];
  }
}

// ---------------- gather pass: h[n,k,o] = ut[m(n,k)][o] + vt[n][o]
// One wave per (point, 64-ch group); block = 4 points x same ch-group.
// All 20 gathers issued independently (full unroll) -> ~20 outstanding vmem/wave.
template<int COUT>
__global__ __launch_bounds__(256, 4) void ebgather_kernel(
    const int* __restrict__ idx, const float* __restrict__ ut, const float* __restrict__ vt,
    float* __restrict__ hmaxb, float* __restrict__ hminb, float* __restrict__ stats){
  constexpr int CHG = COUT/64;
  __shared__ float sred[128];               // [s1|s2][64] block accumulators
  int w = threadIdx.x >> 6, lane = threadIdx.x & 63;
  int pb  = blockIdx.x / CHG;
  int chg = blockIdx.x % CHG;
  int n = pb*4 + w;
  int b = n >> 10;
  if (threadIdx.x < 128) sred[threadIdx.x] = 0.f;
  __syncthreads();
  const int* irow = idx + (size_t)n*KK;
  int m[KK];
#pragma unroll
  for (int k=0;k<KK;k++) m[k] = irow[k];
  int co = chg*64 + lane;
  float vr = vt[(size_t)n*COUT + co];
  float h[KK];
#pragma unroll
  for (int k=0;k<KK;k++)
    h[k] = ut[(size_t)(b*NN + m[k])*COUT + co] + vr;
  float hx=-1e30f, hn=1e30f, s1=0.f, s2=0.f;
#pragma unroll
  for (int k=0;k<KK;k++){
    hx = fmaxf(hx, h[k]);
    hn = fminf(hn, h[k]);
    s1 += h[k];
    s2 = fmaf(h[k], h[k], s2);
  }
  hmaxb[(size_t)n*COUT + co] = hx;
  hminb[(size_t)n*COUT + co] = hn;
  atomicAdd(&sred[lane], s1);
  atomicAdd(&sred[64+lane], s2);
  __syncthreads();
  if (threadIdx.x < 128){
    int which = threadIdx.x >> 6, l = threadIdx.x & 63;
    atomicAdd(&stats[which*COUT + chg*64 + l], sred[which*64 + l]);
  }
}

// ---------------- apply (finalize folded in): out = lrelu(a*(a>=0?hmax:hmin)+c)
template<int COUT>
__global__ __launch_bounds__(256) void ebapply_kernel(
    const float* __restrict__ hmaxb, const float* __restrict__ hminb,
    const float* __restrict__ stats, const void* __restrict__ g, const void* __restrict__ bb,
    float* __restrict__ outp, int outoff, const int* __restrict__ flagp){
  int t = blockIdx.x*256 + threadIdx.x;
  if (t >= BB*NN*COUT) return;
  const int bf = *flagp;
  int n = t / COUT, o = t % COUT;
  const float inv_count = 1.f/(BB*NN*KK);
  float m = stats[o]*inv_count;
  float var = stats[COUT+o]*inv_count - m*m;
  float a = ldin(g,o,bf)*rsqrtf(fmaxf(var,0.f) + EPSB);
  float c = ldin(bb,o,bf) - m*a;
  float h = (a >= 0.f) ? hmaxb[t] : hminb[t];
  outp[(size_t)n*512 + outoff + o] = lrelu(fmaf(a,h,c));
}

// ---------------- conv5 via MFMA bf16: single pass, writes h fp32 [B*N][1024] + BN stats.
__global__ __launch_bounds__(256, 3) void fc5_mfma(
    const float* __restrict__ xcat, const unsigned short* __restrict__ wb5,
    float* __restrict__ st5, float* __restrict__ hbuf){
  __shared__ unsigned As[16*256];            // 16 rows x 512 bf16
  int tid = threadIdx.x;
  int pblk = blockIdx.x >> 2;
  int seg  = blockIdx.x & 3;
  int n0g = pblk*16;                         // global point row in [0, B*N)
  for (int t = tid; t < 16*256; t += 256){
    int r = t >> 8, d = t & 255;             // d: u32 col (2 bf16)
    float2 xv = *(const float2*)&xcat[(size_t)(n0g + r)*512 + d*2];
    unsigned pk = (unsigned)f2bf(xv.x) | ((unsigned)f2bf(xv.y) << 16);
    int gs = (d >> 2) ^ r;                   // 16B-group swizzle
    As[r*256 + (gs<<2) + (d&3)] = pk;
  }
  __syncthreads();
  int w = tid>>6, lane = tid&63, col = lane&15, quad = lane>>4;
  sbf8 afr[16];
#pragma unroll
  for (int ks=0; ks<16; ks++){
    int gs = (ks*4 + quad) ^ col;
    afr[ks] = *(const sbf8*)((const unsigned short*)As + col*512 + gs*8);
  }
#pragma unroll 1
  for (int i=0;i<4;i++){
    int obase = seg*256 + w*64 + i*16;
    f32x4 acc = {0.f,0.f,0.f,0.f};
#pragma unroll
    for (int ks=0; ks<16; ks++){
      sbf8 bfr = *(const sbf8*)(wb5 + (size_t)(obase+col)*512 + ks*32 + quad*8);
      acc = __builtin_amdgcn_mfma_f32_16x16x32_bf16(afr[ks], bfr, acc, 0, 0, 0);
    }
    float s1 = acc.x+acc.y+acc.z+acc.w;
    float s2 = acc.x*acc.x + acc.y*acc.y + acc.z*acc.z + acc.w*acc.w;
    s1 += __shfl_xor(s1,16,64); s2 += __shfl_xor(s2,16,64);
    s1 += __shfl_xor(s1,32,64); s2 += __shfl_xor(s2,32,64);
    if (lane < 16){
      atomicAdd(&st5[obase+lane], s1);
      atomicAdd(&st5[1024+obase+lane], s2);
    }
    float vr[4] = {acc.x, acc.y, acc.z, acc.w};
#pragma unroll
    for (int r=0;r<4;r++)
      hbuf[(size_t)(n0g + quad*4 + r)*1024 + obase + col] = vr[r];
  }
}

// ---------------- pool over n (finalize folded in): max & mean of lrelu(a*h+c)
__global__ __launch_bounds__(256) void pool5_kernel(
    const float* __restrict__ hbuf, const float* __restrict__ st5,
    const void* __restrict__ g5, const void* __restrict__ b5,
    unsigned* __restrict__ pmax, float* __restrict__ psum,
    const int* __restrict__ flagp){
  const int bf = *flagp;
  int b = blockIdx.x >> 5;                   // 8 batches x 32 n-splits
  int ns = blockIdx.x & 31;
  int o4 = threadIdx.x*4;
  const float inv_count = 1.f/(BB*NN);
  float a[4], c[4];
#pragma unroll
  for (int j=0;j<4;j++){
    int o = o4+j;
    float m = st5[o]*inv_count;
    float var = st5[1024+o]*inv_count - m*m;
    a[j] = ldin(g5,o,bf)*rsqrtf(fmaxf(var,0.f)+EPSB);
    c[j] = ldin(b5,o,bf) - m*a[j];
  }
  float mx0=-1e30f,mx1=-1e30f,mx2=-1e30f,mx3=-1e30f;
  float sm0=0.f,sm1=0.f,sm2=0.f,sm3=0.f;
  for (int n = ns*32; n < ns*32+32; n++){
    float4 h = *(const float4*)&hbuf[(size_t)(b*NN + n)*1024 + o4];
    float t0 = lrelu(fmaf(a[0],h.x,c[0]));
    float t1 = lrelu(fmaf(a[1],h.y,c[1]));
    float t2 = lrelu(fmaf(a[2],h.z,c[2]));
    float t3 = lrelu(fmaf(a[3],h.w,c[3]));
    mx0=fmaxf(mx0,t0); mx1=fmaxf(mx1,t1); mx2=fmaxf(mx2,t2); mx3=fmaxf(mx3,t3);
    sm0+=t0; sm1+=t1; sm2+=t2; sm3+=t3;
  }
  atomicMax(&pmax[b*1024+o4+0], f2u_ord(mx0));
  atomicMax(&pmax[b*1024+o4+1], f2u_ord(mx1));
  atomicMax(&pmax[b*1024+o4+2], f2u_ord(mx2));
  atomicMax(&pmax[b*1024+o4+3], f2u_ord(mx3));
  atomicAdd(&psum[b*1024+o4+0], sm0);
  atomicAdd(&psum[b*1024+o4+1], sm1);
  atomicAdd(&psum[b*1024+o4+2], sm2);
  atomicAdd(&psum[b*1024+o4+3], sm3);
}

__global__ void pool_finalize_kernel(const unsigned* __restrict__ pmax,
                                     const float* __restrict__ psum,
                                     float* __restrict__ pooled){
  int t = blockIdx.x*256+threadIdx.x;
  if (t >= BB*2048) return;
  int b = t >> 11, j = t & 2047;
  pooled[t] = (j < 1024) ? u2f_ord(pmax[b*1024+j]) : psum[b*1024 + (j-1024)] * (1.f/1024.f);
}

// ---------------- FC head
__global__ __launch_bounds__(256) void fc6_kernel(
    const float* __restrict__ pooled, const void* __restrict__ W,
    const void* __restrict__ g, const void* __restrict__ bb, float* __restrict__ y6,
    const int* __restrict__ flagp){
  __shared__ float red[8][256];
  int o = blockIdx.x, tid = threadIdx.x;
  const int bf = *flagp;
  float part[8];
#pragma unroll
  for (int b=0;b<8;b++) part[b]=0.f;
  for (int c=tid;c<2048;c+=256){
    float wv = ldin(W,o*2048+c,bf);
#pragma unroll
    for (int b=0;b<8;b++) part[b] = fmaf(pooled[b*2048+c], wv, part[b]);
  }
#pragma unroll
  for (int b=0;b<8;b++) red[b][tid]=part[b];
  __syncthreads();
  for (int s=128;s;s>>=1){
    if (tid<s){
#pragma unroll
      for (int b=0;b<8;b++) red[b][tid]+=red[b][tid+s];
    }
    __syncthreads();
  }
  if (tid==0){
    float y[8], m=0.f;
#pragma unroll
    for (int b=0;b<8;b++){ y[b]=red[b][0]; m+=y[b]; }
    m *= 0.125f;
    float v=0.f;
#pragma unroll
    for (int b=0;b<8;b++){ float d=y[b]-m; v += d*d; }
    v *= 0.125f;
    float a=ldin(g,o,bf)*rsqrtf(fmaxf(v,0.f)+EPSB), c0=ldin(bb,o,bf)-m*a;
#pragma unroll
    for (int b=0;b<8;b++) y6[b*512+o]=lrelu(fmaf(a,y[b],c0));
  }
}

__global__ __launch_bounds__(256) void fc7_kernel(
    const float* __restrict__ y6, const void* __restrict__ W, const void* __restrict__ bias,
    const void* __restrict__ g, const void* __restrict__ bb, float* __restrict__ y7,
    const int* __restrict__ flagp){
  __shared__ float red[8][256];
  int o = blockIdx.x, tid = threadIdx.x;
  const int bf = *flagp;
  float part[8];
#pragma unroll
  for (int b=0;b<8;b++) part[b]=0.f;
  for (int c=tid;c<512;c+=256){
    float wv = ldin(W,o*512+c,bf);
#pragma unroll
    for (int b=0;b<8;b++) part[b] = fmaf(y6[b*512+c], wv, part[b]);
  }
#pragma unroll
  for (int b=0;b<8;b++) red[b][tid]=part[b];
  __syncthreads();
  for (int s=128;s;s>>=1){
    if (tid<s){
#pragma unroll
      for (int b=0;b<8;b++) red[b][tid]+=red[b][tid+s];
    }
    __syncthreads();
  }
  if (tid==0){
    float bs = ldin(bias,o,bf);
    float y[8], m=0.f;
#pragma unroll
    for (int b=0;b<8;b++){ y[b]=red[b][0]+bs; m+=y[b]; }
    m *= 0.125f;
    float v=0.f;
#pragma unroll
    for (int b=0;b<8;b++){ float d=y[b]-m; v += d*d; }
    v *= 0.125f;
    float a=ldin(g,o,bf)*rsqrtf(fmaxf(v,0.f)+EPSB), c0=ldin(bb,o,bf)-m*a;
#pragma unroll
    for (int b=0;b<8;b++) y7[b*256+o]=lrelu(fmaf(a,y[b],c0));
  }
}

__global__ __launch_bounds__(256) void fc8_kernel(
    const float* __restrict__ y7, const void* __restrict__ W, const void* __restrict__ bias,
    void* __restrict__ out, const int* __restrict__ flagp){
  __shared__ float red[8][256];
  int o = blockIdx.x, tid = threadIdx.x;
  const int bf = *flagp;
  float wv = ldin(W,o*256+tid,bf);
#pragma unroll
  for (int b=0;b<8;b++) red[b][tid] = y7[b*256+tid]*wv;
  __syncthreads();
  for (int s=128;s;s>>=1){
    if (tid<s){
#pragma unroll
      for (int b=0;b<8;b++) red[b][tid]+=red[b][tid+s];
    }
    __syncthreads();
  }
  if (tid==0){
    float bs = ldin(bias,o,bf);
#pragma unroll
    for (int b=0;b<8;b++){
      float r = red[b][0]+bs;
      if (bf) ((bf16*)out)[b*40+o] = __float2bfloat16(r);
      else    ((float*)out)[b*40+o] = r;
    }
  }
}

extern "C" void kernel_launch(void* const* d_in, const int* in_sizes, int n_in,
                              void* d_out, int out_size, void* d_ws, size_t ws_size,
                              hipStream_t stream){
  const void* x    = d_in[0];
  const void* w00  = d_in[1];
  const void* g00  = d_in[2];
  const void* b00  = d_in[3];
  const void* w01  = d_in[4];
  const void* g01  = d_in[5];
  const void* b01  = d_in[6];
  const void* w1   = d_in[7];  const void* g1 = d_in[8];  const void* b1 = d_in[9];
  const void* w2   = d_in[10]; const void* g2 = d_in[11]; const void* b2 = d_in[12];
  const void* w3   = d_in[13]; const void* g3 = d_in[14]; const void* b3 = d_in[15];
  const void* w4   = d_in[16]; const void* g4 = d_in[17]; const void* b4 = d_in[18];
  const void* w5   = d_in[19]; const void* g5 = d_in[20]; const void* b5 = d_in[21];
  const void* w6   = d_in[22]; const void* g6 = d_in[23]; const void* b6 = d_in[24];
  const void* w7   = d_in[25]; const void* bias7 = d_in[26];
  const void* g7   = d_in[27]; const void* b7 = d_in[28];
  const void* w8   = d_in[29]; const void* bias8 = d_in[30];

  float* ws = (float*)d_ws;
  // workspace layout (float offsets)
  size_t o_xc0  = 0;                              // B*N*16
  size_t o_xcat = o_xc0  + (size_t)BB*NN*16;      // B*N*512
  size_t o_negd = o_xcat + (size_t)BB*NN*512;     // B*N*N (u/v/hmax/hmin, then h5)
  size_t o_xx   = o_negd + (size_t)BB*NN*NN;      // B*N (unused)
  size_t o_w1d  = o_xx   + (size_t)BB*NN;         // 12*64
  size_t o_w1c  = o_w1d  + 12*64;
  size_t o_w2d  = o_w1c  + 12*64;                 // 64*64
  size_t o_w2c  = o_w2d  + 64*64;
  size_t o_w3d  = o_w2c  + 64*64;                 // 64*128
  size_t o_w3c  = o_w3d  + 64*128;
  size_t o_w4d  = o_w3c  + 64*128;                // 128*256
  size_t o_w4c  = o_w4d  + 128*256;
  size_t o_wb5  = o_w4c  + 128*256;               // 1024*512 bf16 = 262144 floats
  size_t o_st1  = o_wb5  + 262144;                // 128  (zero region starts here)
  size_t o_st2  = o_st1  + 128;                   // 128
  size_t o_st3  = o_st2  + 128;                   // 256
  size_t o_st4  = o_st3  + 256;                   // 512
  size_t o_st5  = o_st4  + 512;                   // 2048
  size_t o_pmax = o_st5  + 2048;                  // 8*1024 (uint)
  size_t o_psum = o_pmax + 8192;                  // 8*1024
  size_t o_cst  = o_psum + 8192;                  // 16 (conv0 stats; zero region ends)
  size_t o_pool = o_cst  + 16;                    // 8*2048
  size_t o_y6   = o_pool + 16384;                 // 8*512
  size_t o_y7   = o_y6   + 4096;                  // 8*256
  size_t o_idx  = o_y7   + 2048;                  // B*N*20 ints
  size_t o_flag = o_idx  + (size_t)BB*NN*KK;      // 1 int

  // overlays on the negD region (dead after topk):
  size_t o_u    = o_negd;
  size_t o_v    = o_negd + (size_t)BB*NN*256;
  size_t o_hmax = o_negd + (size_t)2*BB*NN*256;
  size_t o_hmin = o_negd + (size_t)3*BB*NN*256;
  size_t o_h5   = o_negd;                         // B*N*1024 (after eb4 apply)

  int* idxp = (int*)(ws + o_idx);
  int* flagp = (int*)(ws + o_flag);
  float* negD = ws + o_negd;
  float* xc0  = ws + o_xc0;
  float* xcat = ws + o_xcat;
  float* up   = ws + o_u;
  float* vp   = ws + o_v;
  float* hxp  = ws + o_hmax;
  float* hnp  = ws + o_hmin;
  unsigned short* wb5 = (unsigned short*)(ws + o_wb5);

  detect_kernel<<<1,64,0,stream>>>((const unsigned*)x, flagp);

  int nz = 128+128+256+512+2048+8192+8192+16;
  zero_kernel<<<(nz+255)/256, 256, 0, stream>>>((unsigned*)(ws + o_st1), nz);

  conv0_stats_kernel<<<32,256,0,stream>>>(x, w00, w01, ws+o_cst, flagp);
  conv0_apply_kernel<<<32,256,0,stream>>>(x, w00,g00,b00, w01,g01,b01, ws+o_cst, xc0, flagp);

  // fused weight prep: 4x wuv + wb5 pack (768+4096+8192+32768+524288 = 570112 elems)
  prep_kernel<<<(570112+255)/256,256,0,stream>>>(
      w1,w2,w3,w4,w5,
      ws+o_w1d, ws+o_w1c, ws+o_w2d, ws+o_w2c,
      ws+o_w3d, ws+o_w3c, ws+o_w4d, ws+o_w4c, wb5, flagp);

  dim3 kgrid(NN/128, NN/128, BB);               // 512 blocks
  const size_t KLDS16 = (2*128*16 + 256)*4;     // CR=12 (KCH=16)
  const size_t KLDS64 = (2*128*64 + 256)*4;     // CR=64/128 (KCH=64)
  const int UVG = BB*NN/16;    // 512 blocks

  // ---- edge block 1: src=xc0 (ld16, C=9), Cout=64 -> xcat[:,0:64)
  knndist_kernel<<<kgrid,256, KLDS16, stream>>>(xc0, 16, 0, 12, negD);
  topk_kernel<<<BB*NN/4,256,0,stream>>>(negD, idxp);
  uvgemm_kernel<12,64><<<UVG,256,0,stream>>>(xc0, 16, 0, ws+o_w1d, ws+o_w1c, up, vp);
  ebgather_kernel<64><<<(BB*NN/4)*1,256,0,stream>>>(idxp, up, vp, hxp, hnp, ws+o_st1);
  ebapply_kernel<64><<<BB*NN*64/256,256,0,stream>>>(hxp, hnp, ws+o_st1, g1, b1, xcat, 0, flagp);

  // ---- edge block 2: src=x1, Cout=64 -> xcat[:,64:128)
  knndist_kernel<<<kgrid,256, KLDS64, stream>>>(xcat, 512, 0, 64, negD);
  topk_kernel<<<BB*NN/4,256,0,stream>>>(negD, idxp);
  uvgemm_kernel<64,64><<<UVG,256,0,stream>>>(xcat, 512, 0, ws+o_w2d, ws+o_w2c, up, vp);
  ebgather_kernel<64><<<(BB*NN/4)*1,256,0,stream>>>(idxp, up, vp, hxp, hnp, ws+o_st2);
  ebapply_kernel<64><<<BB*NN*64/256,256,0,stream>>>(hxp, hnp, ws+o_st2, g2, b2, xcat, 64, flagp);

  // ---- edge block 3: src=x2, Cout=128 -> xcat[:,128:256)
  knndist_kernel<<<kgrid,256, KLDS64, stream>>>(xcat, 512, 64, 64, negD);
  topk_kernel<<<BB*NN/4,256,0,stream>>>(negD, idxp);
  uvgemm_kernel<64,128><<<UVG,256,0,stream>>>(xcat, 512, 64, ws+o_w3d, ws+o_w3c, up, vp);
  ebgather_kernel<128><<<(BB*NN/4)*2,256,0,stream>>>(idxp, up, vp, hxp, hnp, ws+o_st3);
  ebapply_kernel<128><<<BB*NN*128/256,256,0,stream>>>(hxp, hnp, ws+o_st3, g3, b3, xcat, 128, flagp);

  // ---- edge block 4: src=x3, Cout=256 -> xcat[:,256:512)
  knndist_kernel<<<kgrid,256, KLDS64, stream>>>(xcat, 512, 128, 128, negD);
  topk_kernel<<<BB*NN/4,256,0,stream>>>(negD, idxp);
  uvgemm_kernel<128,256><<<UVG,256,0,stream>>>(xcat, 512, 128, ws+o_w4d, ws+o_w4c, up, vp);
  ebgather_kernel<256><<<(BB*NN/4)*4,256,0,stream>>>(idxp, up, vp, hxp, hnp, ws+o_st4);
  ebapply_kernel<256><<<BB*NN*256/256,256,0,stream>>>(hxp, hnp, ws+o_st4, g4, b4, xcat, 256, flagp);

  // ---- conv5 (512 -> 1024) MFMA single pass + BN + lrelu + pool
  fc5_mfma<<<(BB*NN/16)*4,256,0,stream>>>(xcat, wb5, ws+o_st5, ws+o_h5);
  pool5_kernel<<<BB*32,256,0,stream>>>(ws+o_h5, ws+o_st5, g5, b5,
                                       (unsigned*)(ws+o_pmax), ws+o_psum, flagp);
  pool_finalize_kernel<<<(BB*2048+255)/256,256,0,stream>>>((unsigned*)(ws+o_pmax), ws+o_psum, ws+o_pool);

  // ---- FC head
  fc6_kernel<<<512,256,0,stream>>>(ws+o_pool, w6, g6, b6, ws+o_y6, flagp);
  fc7_kernel<<<256,256,0,stream>>>(ws+o_y6, w7, bias7, g7, b7, ws+o_y7, flagp);
  fc8_kernel<<<40,256,0,stream>>>(ws+o_y7, w8, bias8, d_out, flagp);
}

// Round 11
// 798.738 us; speedup vs baseline: 14.8543x; 1.0017x over previous
//
#include <hip/hip_runtime.h>
#include <hip/hip_bf16.h>

#define BB 8
#define NN 1024
#define KK 20
#define EPSB 1e-5f

typedef __hip_bfloat16 bf16;
typedef __attribute__((ext_vector_type(8))) short sbf8;   // 8 bf16 = 4 VGPRs
typedef __attribute__((ext_vector_type(4))) float f32x4;

__device__ __forceinline__ float lrelu(float t){ return t >= 0.f ? t : 0.2f*t; }
// dtype-flag-aware input load: flag=1 -> bf16, flag=0 -> fp32
__device__ __forceinline__ float ldin(const void* p, int i, int bf){
  return bf ? __bfloat162float(((const bf16*)p)[i]) : ((const float*)p)[i];
}
__device__ __forceinline__ unsigned short f2bf(float f){   // RNE fp32->bf16 bits
  unsigned u = __float_as_uint(f);
  return (unsigned short)((u + 0x7FFFu + ((u>>16)&1u)) >> 16);
}
__device__ __forceinline__ float bf2f(unsigned short us){
  return __uint_as_float((unsigned)us << 16);
}
__device__ __forceinline__ unsigned f2u_ord(float f){
  unsigned u = __float_as_uint(f);
  return (u & 0x80000000u) ? ~u : (u | 0x80000000u);
}
__device__ __forceinline__ float u2f_ord(unsigned u){
  return (u & 0x80000000u) ? __uint_as_float(u & 0x7fffffffu) : __uint_as_float(~u);
}

// ---------------- dtype detection (fp32 words of N(0,1) data never have exp>=0xD0)
__global__ void detect_kernel(const unsigned* __restrict__ xw, int* __restrict__ flag){
  int t = threadIdx.x;
  unsigned w = xw[t];
  unsigned e = (w >> 23) & 0xFFu;
  unsigned long long m = __ballot(e >= 0xD0u);
  if (t == 0) *flag = (__popcll(m) >= 32) ? 1 : 0;
}

__global__ void zero_kernel(unsigned* __restrict__ p, int n){
  int i = blockIdx.x*256 + threadIdx.x;
  if (i < n) p[i] = 0u;
}

// ---------------- conv0 stats: 32 blocks, 1 point/thread, shuffle-reduce + atomics
__global__ __launch_bounds__(256) void conv0_stats_kernel(
    const void* __restrict__ x,
    const void* __restrict__ w00, const void* __restrict__ w01,
    float* __restrict__ cstat, const int* __restrict__ flagp){
  const int bf = *flagp;
  int i = blockIdx.x*256 + threadIdx.x;
  int b = i >> 10, n = i & 1023;
  float wz[4], wy[4];
#pragma unroll
  for (int j=0;j<4;j++){ wz[j]=ldin(w00,j,bf); wy[j]=ldin(w01,j,bf); }
  float x0 = ldin(x,(b*3+0)*NN + n,bf);
  float x1 = ldin(x,(b*3+1)*NN + n,bf);
  float x2 = ldin(x,(b*3+2)*NN + n,bf);
  float vals[6];
  vals[0] = wz[0]*x0 + wz[1]*x1;  vals[1] = wz[2]*x0 + wz[3]*x1;   // z (w00, ch 0,1)
  vals[2] = wy[0]*x0 + wy[1]*x2;  vals[3] = wy[2]*x0 + wy[3]*x2;   // y (w01, ch 0,2)
  vals[4] = wy[0]*x1 + wy[1]*x2;  vals[5] = wy[2]*x1 + wy[3]*x2;   // u (w01, ch 1,2)
  int lane = threadIdx.x & 63;
#pragma unroll
  for (int j=0;j<6;j++){
    float s1 = vals[j], s2 = vals[j]*vals[j];
#pragma unroll
    for (int off=32; off; off>>=1){
      s1 += __shfl_xor(s1, off, 64);
      s2 += __shfl_xor(s2, off, 64);
    }
    if (lane == 0){
      atomicAdd(&cstat[2*j], s1);
      atomicAdd(&cstat[2*j+1], s2);
    }
  }
}

// ---------------- conv0 apply: BN+lrelu+gate, writes xc0 rows (16 floats, padded)
__global__ __launch_bounds__(256) void conv0_apply_kernel(
    const void* __restrict__ x,
    const void* __restrict__ w00, const void* __restrict__ g00, const void* __restrict__ b00,
    const void* __restrict__ w01, const void* __restrict__ g01, const void* __restrict__ b01,
    const float* __restrict__ cstat, float* __restrict__ xc0,
    const int* __restrict__ flagp){
  const int bf = *flagp;
  int i = blockIdx.x*256 + threadIdx.x;
  int b = i >> 10, n = i & 1023;
  float wz[4], wy[4];
#pragma unroll
  for (int j=0;j<4;j++){ wz[j]=ldin(w00,j,bf); wy[j]=ldin(w01,j,bf); }
  float sA[6], sC[6];
#pragma unroll
  for (int j=0;j<6;j++){
    float m = cstat[2*j] * (1.f/(BB*NN));
    float v = cstat[2*j+1] * (1.f/(BB*NN)) - m*m;
    float g, bv;
    if (j<2){ g=ldin(g00,j,bf); bv=ldin(b00,j,bf); }
    else if (j<4){ g=ldin(g01,j-2,bf); bv=ldin(b01,j-2,bf); }
    else { g=ldin(g01,j-4,bf); bv=ldin(b01,j-4,bf); }
    float a = g * rsqrtf(fmaxf(v,0.f) + EPSB);
    sA[j]=a; sC[j]=bv - m*a;
  }
  float x0 = ldin(x,(b*3+0)*NN + n,bf);
  float x1 = ldin(x,(b*3+1)*NN + n,bf);
  float x2 = ldin(x,(b*3+2)*NN + n,bf);
  float z0 = wz[0]*x0 + wz[1]*x1, z1 = wz[2]*x0 + wz[3]*x1;
  float y0 = wy[0]*x0 + wy[1]*x2, y1 = wy[2]*x0 + wy[3]*x2;
  float u0 = wy[0]*x1 + wy[1]*x2, u1 = wy[2]*x1 + wy[3]*x2;
  float* row = xc0 + (size_t)i*16;
  float4 r0, r1, r2, r3;
  r0.x=x0; r0.y=x1; r0.z=x2;
  r0.w=lrelu(sA[4]*u0+sC[4])*x0;
  r1.x=lrelu(sA[5]*u1+sC[5])*x0;
  r1.y=lrelu(sA[2]*y0+sC[2])*x1;
  r1.z=lrelu(sA[3]*y1+sC[3])*x1;
  r1.w=lrelu(sA[0]*z0+sC[0])*x2;
  r2.x=lrelu(sA[1]*z1+sC[1])*x2;
  r2.y=0.f; r2.z=0.f; r2.w=0.f;
  r3.x=0.f; r3.y=0.f; r3.z=0.f; r3.w=0.f;
  *(float4*)&row[0]  = r0;
  *(float4*)&row[4]  = r1;
  *(float4*)&row[8]  = r2;
  *(float4*)&row[12] = r3;
}

// ---------------- weight prep element: WdT[c][o]=W[o][c], WcdT[c][o]=W[o][CIN+c]-W[o][c]
__device__ __forceinline__ void wuv_elem(const void* W, float* WdT, float* WcdT,
                                         int CIN, int COUT, int t, int bf){
  int c = t / COUT, o = t % COUT;
  if (c < CIN){
    float wd = ldin(W, o*(2*CIN)+c, bf);
    float wc = ldin(W, o*(2*CIN)+CIN+c, bf);
    WdT[t] = wd; WcdT[t] = wc - wd;
  } else {
    WdT[t] = 0.f; WcdT[t] = 0.f;
  }
}

// ---------------- single fused weight-prep launch (4x wuv + wb5 pack)
__global__ __launch_bounds__(256) void prep_kernel(
    const void* __restrict__ w1, const void* __restrict__ w2,
    const void* __restrict__ w3, const void* __restrict__ w4,
    const void* __restrict__ w5,
    float* __restrict__ w1d, float* __restrict__ w1c,
    float* __restrict__ w2d, float* __restrict__ w2c,
    float* __restrict__ w3d, float* __restrict__ w3c,
    float* __restrict__ w4d, float* __restrict__ w4c,
    unsigned short* __restrict__ wb5, const int* __restrict__ flagp){
  int t = blockIdx.x*256 + threadIdx.x;
  const int bf = *flagp;
  if (t < 768){ wuv_elem(w1, w1d, w1c, 9, 64, t, bf); return; }
  t -= 768;
  if (t < 4096){ wuv_elem(w2, w2d, w2c, 64, 64, t, bf); return; }
  t -= 4096;
  if (t < 8192){ wuv_elem(w3, w3d, w3c, 64, 128, t, bf); return; }
  t -= 8192;
  if (t < 32768){ wuv_elem(w4, w4d, w4c, 128, 256, t, bf); return; }
  t -= 32768;
  if (t < 1024*512) wb5[t] = f2bf(ldin(w5, t, bf));
}

// ---------------- fused negdist (with on-the-fly row norms): 128x128 tiles, 8x8 acc
__global__ __launch_bounds__(256, 2) void knndist_kernel(
    const float* __restrict__ src, int ld, int coff, int CR,
    float* __restrict__ negD){
  extern __shared__ float lds[];
  const int KCH = (CR >= 64) ? 64 : 16;     // CR=12 -> 16 (xc0 cols 9..15 are zero)
  const int NG  = KCH >> 2;                 // 16B groups per row
  const int GM  = NG - 1;
  float* At = lds;
  float* Bt = lds + 128*KCH;
  float* xn = Bt + 128*KCH;                 // [0..127]=A norms, [128..255]=B norms
  int b = blockIdx.z, i0 = blockIdx.y*128, j0 = blockIdx.x*128;
  int tid = threadIdx.x;
  int ti = tid >> 4, tj = tid & 15;
  int gsa = ti & GM, gsb = tj & GM;
  float acc[8][8];
#pragma unroll
  for (int u=0;u<8;u++)
#pragma unroll
    for (int v=0;v<8;v++) acc[u][v]=0.f;
  float mynorm = 0.f;
  int nch = (CR + KCH - 1)/KCH;             // 1 (CR<=64) or 2 (CR=128)
  for (int ch=0; ch<nch; ch++){
    int c0 = ch*KCH;
    __syncthreads();
    for (int t = tid; t < 2*128*NG; t += 256){
      int half = (t >= 128*NG);
      int tt = half ? t - 128*NG : t;
      int r = tt / NG, g = tt % NG;
      int base = half ? j0 : i0;
      float4 f = *(const float4*)&src[(size_t)(b*NN + base + r)*ld + coff + c0 + g*4];
      int gs = g ^ ((r>>3) & GM);
      float* dst = (half ? Bt : At) + r*KCH + gs*4;
      *(float4*)dst = f;
    }
    __syncthreads();
    {
      int r = tid & 127;
      const float* rowp = ((tid < 128) ? At : Bt) + r*KCH;
      float s = 0.f;
      for (int g=0; g<NG; g++){
        float4 f = *(const float4*)&rowp[g*4];
        s += f.x*f.x + f.y*f.y + f.z*f.z + f.w*f.w;
      }
      mynorm += s;
    }
    for (int g=0; g<NG; g++){
      float4 av[8];
#pragma unroll
      for (int u=0;u<8;u++)
        av[u] = *(const float4*)&At[(ti*8+u)*KCH + ((g ^ gsa)<<2)];
#pragma unroll
      for (int v=0;v<8;v++){
        float4 bv = *(const float4*)&Bt[(tj*8+v)*KCH + ((g ^ gsb)<<2)];
#pragma unroll
        for (int u=0;u<8;u++)
          acc[u][v] += av[u].x*bv.x + av[u].y*bv.y + av[u].z*bv.z + av[u].w*bv.w;
      }
    }
  }
  __syncthreads();
  xn[(tid < 128 ? 0 : 128) + (tid & 127)] = mynorm;
  __syncthreads();
  float xi[8], xj[8];
#pragma unroll
  for (int u=0;u<8;u++){ xi[u] = xn[ti*8+u]; xj[u] = xn[128 + tj*8+u]; }
#pragma unroll
  for (int u=0;u<8;u++){
    float* orow = &negD[((size_t)(b*NN + i0 + ti*8 + u))*NN + j0 + tj*8];
#pragma unroll
    for (int vg=0; vg<2; vg++){
      float4 ov;
      ov.x = 2.f*acc[u][vg*4+0] - xi[u] - xj[vg*4+0];
      ov.y = 2.f*acc[u][vg*4+1] - xi[u] - xj[vg*4+1];
      ov.z = 2.f*acc[u][vg*4+2] - xi[u] - xj[vg*4+2];
      ov.w = 2.f*acc[u][vg*4+3] - xi[u] - xj[vg*4+3];
      *(float4*)&orow[vg*4] = ov;
    }
  }
}

// ---------------- top-20: one wave per row; registers + 64-lane butterfly argmax
__global__ __launch_bounds__(256, 4) void topk_kernel(const float* __restrict__ negD,
                                                      int* __restrict__ idx){
  int row_id = (blockIdx.x*256 + threadIdx.x) >> 6;
  int lane = threadIdx.x & 63;
  if (row_id >= BB*NN) return;
  const float* row = negD + (size_t)row_id*NN;
  float v[16];
#pragma unroll
  for (int j=0;j<4;j++){
    float4 f = *(const float4*)&row[j*256 + lane*4];
    v[j*4+0]=f.x; v[j*4+1]=f.y; v[j*4+2]=f.z; v[j*4+3]=f.w;
  }
  int* orow = idx + (size_t)row_id*KK;
  for (int k=0;k<KK;k++){
    float bv = v[0]; int bs = 0;
#pragma unroll
    for (int s=1;s<16;s++){ if (v[s] > bv){ bv = v[s]; bs = s; } }
    int bidx = (bs>>2)*256 + lane*4 + (bs&3);
    unsigned long long key = ((unsigned long long)f2u_ord(bv) << 32) | (unsigned)(1023 - bidx);
#pragma unroll
    for (int off=32; off; off>>=1){
      unsigned long long o = __shfl_xor(key, off, 64);
      if (o > key) key = o;
    }
    int widx = 1023 - (int)(key & 0xFFFFFFFFu);
    if (lane == 0) orow[k] = widx;
    bool mine = (((widx >> 2) & 63) == lane);
    int wslot = ((widx >> 8) << 2) | (widx & 3);
#pragma unroll
    for (int s=0;s<16;s++){
      if (mine && s == wslot) v[s] = -1e30f;
    }
  }
}

// ---------------- u/v GEMM: ut[n][o]=Wd.x[n], vt[n][o]=(Wc-Wd).x[n]  (fp32 exact)
template<int CINP,int COUT>
__global__ __launch_bounds__(256, 4) void uvgemm_kernel(
    const float* __restrict__ srcT, int ld, int coff,
    const float* __restrict__ WdT, const float* __restrict__ WcdT,
    float* __restrict__ ut, float* __restrict__ vt){
  constexpr int PT=16, G = 256/COUT, NP = PT/G;
  __shared__ float xs[PT*CINP];
  int tid = threadIdx.x;
  int base = blockIdx.x*PT;                 // global point index
  for (int t=tid; t<PT*CINP; t+=256){
    int p = t / CINP, c = t % CINP;
    xs[t] = srcT[(size_t)(base+p)*ld + coff + c];
  }
  __syncthreads();
  int o = tid % COUT, grp = tid / COUT;
  float u[NP], v[NP];
#pragma unroll
  for (int pp=0;pp<NP;pp++){ u[pp]=0.f; v[pp]=0.f; }
  for (int c=0;c<CINP;c+=4){
    float wd0 = WdT[(c+0)*COUT+o], wc0 = WcdT[(c+0)*COUT+o];
    float wd1 = WdT[(c+1)*COUT+o], wc1 = WcdT[(c+1)*COUT+o];
    float wd2 = WdT[(c+2)*COUT+o], wc2 = WcdT[(c+2)*COUT+o];
    float wd3 = WdT[(c+3)*COUT+o], wc3 = WcdT[(c+3)*COUT+o];
#pragma unroll
    for (int pp=0;pp<NP;pp++){
      float4 xv = *(const float4*)&xs[(grp+pp*G)*CINP + c];
      u[pp] = fmaf(xv.x,wd0,fmaf(xv.y,wd1,fmaf(xv.z,wd2,fmaf(xv.w,wd3,u[pp]))));
      v[pp] = fmaf(xv.x,wc0,fmaf(xv.y,wc1,fmaf(xv.z,wc2,fmaf(xv.w,wc3,v[pp]))));
    }
  }
#pragma unroll
  for (int pp=0;pp<NP;pp++){
    int p = grp + pp*G;
    ut[(size_t)(base+p)*COUT + o] = u[pp];
    vt[(size_t)(base+p)*COUT + o] = v[pp];
  }
}

// ---------------- gather pass: h[n,k,o] = ut[m(n,k)][o] + vt[n][o]
// One wave per (point, 64-ch group); block = 4 points x same ch-group.
template<int COUT>
__global__ __launch_bounds__(256, 4) void ebgather_kernel(
    const int* __restrict__ idx, const float* __restrict__ ut, const float* __restrict__ vt,
    float* __restrict__ hmaxb, float* __restrict__ hminb, float* __restrict__ stats){
  constexpr int CHG = COUT/64;
  __shared__ float sred[128];               // [s1|s2][64] block accumulators
  int w = threadIdx.x >> 6, lane = threadIdx.x & 63;
  int pb  = blockIdx.x / CHG;
  int chg = blockIdx.x % CHG;
  int n = pb*4 + w;
  int b = n >> 10;
  if (threadIdx.x < 128) sred[threadIdx.x] = 0.f;
  __syncthreads();
  const int* irow = idx + (size_t)n*KK;
  int m[KK];
#pragma unroll
  for (int k=0;k<KK;k++) m[k] = irow[k];
  int co = chg*64 + lane;
  float vr = vt[(size_t)n*COUT + co];
  float h[KK];
#pragma unroll
  for (int k=0;k<KK;k++)
    h[k] = ut[(size_t)(b*NN + m[k])*COUT + co] + vr;
  float hx=-1e30f, hn=1e30f, s1=0.f, s2=0.f;
#pragma unroll
  for (int k=0;k<KK;k++){
    hx = fmaxf(hx, h[k]);
    hn = fminf(hn, h[k]);
    s1 += h[k];
    s2 = fmaf(h[k], h[k], s2);
  }
  hmaxb[(size_t)n*COUT + co] = hx;
  hminb[(size_t)n*COUT + co] = hn;
  atomicAdd(&sred[lane], s1);
  atomicAdd(&sred[64+lane], s2);
  __syncthreads();
  if (threadIdx.x < 128){
    int which = threadIdx.x >> 6, l = threadIdx.x & 63;
    atomicAdd(&stats[which*COUT + chg*64 + l], sred[which*64 + l]);
  }
}

// ---------------- apply (finalize folded in): out = lrelu(a*(a>=0?hmax:hmin)+c)
template<int COUT>
__global__ __launch_bounds__(256) void ebapply_kernel(
    const float* __restrict__ hmaxb, const float* __restrict__ hminb,
    const float* __restrict__ stats, const void* __restrict__ g, const void* __restrict__ bb,
    float* __restrict__ outp, int outoff, const int* __restrict__ flagp){
  int t = blockIdx.x*256 + threadIdx.x;
  if (t >= BB*NN*COUT) return;
  const int bf = *flagp;
  int n = t / COUT, o = t % COUT;
  const float inv_count = 1.f/(BB*NN*KK);
  float m = stats[o]*inv_count;
  float var = stats[COUT+o]*inv_count - m*m;
  float a = ldin(g,o,bf)*rsqrtf(fmaxf(var,0.f) + EPSB);
  float c = ldin(bb,o,bf) - m*a;
  float h = (a >= 0.f) ? hmaxb[t] : hminb[t];
  outp[(size_t)n*512 + outoff + o] = lrelu(fmaf(a,h,c));
}

// ---------------- conv5 via MFMA bf16: single pass, h -> bf16 hbuf + BN stats.
// 4 independent acc chains (ks%4) force >=4 outstanding B-frag loads (MLP).
__global__ __launch_bounds__(256, 3) void fc5_mfma(
    const float* __restrict__ xcat, const unsigned short* __restrict__ wb5,
    float* __restrict__ st5, unsigned short* __restrict__ hbufb){
  __shared__ unsigned As[16*256];            // 16 rows x 512 bf16
  int tid = threadIdx.x;
  int pblk = blockIdx.x >> 2;
  int seg  = blockIdx.x & 3;
  int n0g = pblk*16;                         // global point row in [0, B*N)
  for (int t = tid; t < 16*256; t += 256){
    int r = t >> 8, d = t & 255;             // d: u32 col (2 bf16)
    float2 xv = *(const float2*)&xcat[(size_t)(n0g + r)*512 + d*2];
    unsigned pk = (unsigned)f2bf(xv.x) | ((unsigned)f2bf(xv.y) << 16);
    int gs = (d >> 2) ^ r;                   // 16B-group swizzle
    As[r*256 + (gs<<2) + (d&3)] = pk;
  }
  __syncthreads();
  int w = tid>>6, lane = tid&63, col = lane&15, quad = lane>>4;
  sbf8 afr[16];
#pragma unroll
  for (int ks=0; ks<16; ks++){
    int gs = (ks*4 + quad) ^ col;
    afr[ks] = *(const sbf8*)((const unsigned short*)As + col*512 + gs*8);
  }
#pragma unroll 1
  for (int i=0;i<4;i++){
    int obase = seg*256 + w*64 + i*16;
    const unsigned short* wrow = wb5 + (size_t)(obase+col)*512 + quad*8;
    f32x4 a0 = {0.f,0.f,0.f,0.f}, a1 = {0.f,0.f,0.f,0.f};
    f32x4 a2 = {0.f,0.f,0.f,0.f}, a3 = {0.f,0.f,0.f,0.f};
#pragma unroll
    for (int ks=0; ks<4; ks++){
      sbf8 b0 = *(const sbf8*)(wrow + (ks*4+0)*32);
      sbf8 b1 = *(const sbf8*)(wrow + (ks*4+1)*32);
      sbf8 b2 = *(const sbf8*)(wrow + (ks*4+2)*32);
      sbf8 b3 = *(const sbf8*)(wrow + (ks*4+3)*32);
      a0 = __builtin_amdgcn_mfma_f32_16x16x32_bf16(afr[ks*4+0], b0, a0, 0, 0, 0);
      a1 = __builtin_amdgcn_mfma_f32_16x16x32_bf16(afr[ks*4+1], b1, a1, 0, 0, 0);
      a2 = __builtin_amdgcn_mfma_f32_16x16x32_bf16(afr[ks*4+2], b2, a2, 0, 0, 0);
      a3 = __builtin_amdgcn_mfma_f32_16x16x32_bf16(afr[ks*4+3], b3, a3, 0, 0, 0);
    }
    f32x4 acc = (a0 + a1) + (a2 + a3);
    float s1 = acc.x+acc.y+acc.z+acc.w;
    float s2 = acc.x*acc.x + acc.y*acc.y + acc.z*acc.z + acc.w*acc.w;
    s1 += __shfl_xor(s1,16,64); s2 += __shfl_xor(s2,16,64);
    s1 += __shfl_xor(s1,32,64); s2 += __shfl_xor(s2,32,64);
    if (lane < 16){
      atomicAdd(&st5[obase+lane], s1);
      atomicAdd(&st5[1024+obase+lane], s2);
    }
    unsigned short hv[4] = {f2bf(acc.x), f2bf(acc.y), f2bf(acc.z), f2bf(acc.w)};
#pragma unroll
    for (int r=0;r<4;r++)
      hbufb[(size_t)(n0g + quad*4 + r)*1024 + obase + col] = hv[r];
  }
}

// ---------------- pool over n (finalize folded in): max & mean of lrelu(a*h+c); h bf16
__global__ __launch_bounds__(256) void pool5_kernel(
    const unsigned short* __restrict__ hbufb, const float* __restrict__ st5,
    const void* __restrict__ g5, const void* __restrict__ b5,
    unsigned* __restrict__ pmax, float* __restrict__ psum,
    const int* __restrict__ flagp){
  const int bf = *flagp;
  int b = blockIdx.x >> 5;                   // 8 batches x 32 n-splits
  int ns = blockIdx.x & 31;
  int o4 = threadIdx.x*4;
  const float inv_count = 1.f/(BB*NN);
  float a[4], c[4];
#pragma unroll
  for (int j=0;j<4;j++){
    int o = o4+j;
    float m = st5[o]*inv_count;
    float var = st5[1024+o]*inv_count - m*m;
    a[j] = ldin(g5,o,bf)*rsqrtf(fmaxf(var,0.f)+EPSB);
    c[j] = ldin(b5,o,bf) - m*a[j];
  }
  float mx0=-1e30f,mx1=-1e30f,mx2=-1e30f,mx3=-1e30f;
  float sm0=0.f,sm1=0.f,sm2=0.f,sm3=0.f;
  for (int n = ns*32; n < ns*32+32; n++){
    ushort4 hu = *(const ushort4*)&hbufb[(size_t)(b*NN + n)*1024 + o4];
    float t0 = lrelu(fmaf(a[0],bf2f(hu.x),c[0]));
    float t1 = lrelu(fmaf(a[1],bf2f(hu.y),c[1]));
    float t2 = lrelu(fmaf(a[2],bf2f(hu.z),c[2]));
    float t3 = lrelu(fmaf(a[3],bf2f(hu.w),c[3]));
    mx0=fmaxf(mx0,t0); mx1=fmaxf(mx1,t1); mx2=fmaxf(mx2,t2); mx3=fmaxf(mx3,t3);
    sm0+=t0; sm1+=t1; sm2+=t2; sm3+=t3;
  }
  atomicMax(&pmax[b*1024+o4+0], f2u_ord(mx0));
  atomicMax(&pmax[b*1024+o4+1], f2u_ord(mx1));
  atomicMax(&pmax[b*1024+o4+2], f2u_ord(mx2));
  atomicMax(&pmax[b*1024+o4+3], f2u_ord(mx3));
  atomicAdd(&psum[b*1024+o4+0], sm0);
  atomicAdd(&psum[b*1024+o4+1], sm1);
  atomicAdd(&psum[b*1024+o4+2], sm2);
  atomicAdd(&psum[b*1024+o4+3], sm3);
}

__global__ void pool_finalize_kernel(const unsigned* __restrict__ pmax,
                                     const float* __restrict__ psum,
                                     float* __restrict__ pooled){
  int t = blockIdx.x*256+threadIdx.x;
  if (t >= BB*2048) return;
  int b = t >> 11, j = t & 2047;
  pooled[t] = (j < 1024) ? u2f_ord(pmax[b*1024+j]) : psum[b*1024 + (j-1024)] * (1.f/1024.f);
}

// ---------------- FC head
__global__ __launch_bounds__(256) void fc6_kernel(
    const float* __restrict__ pooled, const void* __restrict__ W,
    const void* __restrict__ g, const void* __restrict__ bb, float* __restrict__ y6,
    const int* __restrict__ flagp){
  __shared__ float red[8][256];
  int o = blockIdx.x, tid = threadIdx.x;
  const int bf = *flagp;
  float part[8];
#pragma unroll
  for (int b=0;b<8;b++) part[b]=0.f;
  for (int c=tid;c<2048;c+=256){
    float wv = ldin(W,o*2048+c,bf);
#pragma unroll
    for (int b=0;b<8;b++) part[b] = fmaf(pooled[b*2048+c], wv, part[b]);
  }
#pragma unroll
  for (int b=0;b<8;b++) red[b][tid]=part[b];
  __syncthreads();
  for (int s=128;s;s>>=1){
    if (tid<s){
#pragma unroll
      for (int b=0;b<8;b++) red[b][tid]+=red[b][tid+s];
    }
    __syncthreads();
  }
  if (tid==0){
    float y[8], m=0.f;
#pragma unroll
    for (int b=0;b<8;b++){ y[b]=red[b][0]; m+=y[b]; }
    m *= 0.125f;
    float v=0.f;
#pragma unroll
    for (int b=0;b<8;b++){ float d=y[b]-m; v += d*d; }
    v *= 0.125f;
    float a=ldin(g,o,bf)*rsqrtf(fmaxf(v,0.f)+EPSB), c0=ldin(bb,o,bf)-m*a;
#pragma unroll
    for (int b=0;b<8;b++) y6[b*512+o]=lrelu(fmaf(a,y[b],c0));
  }
}

__global__ __launch_bounds__(256) void fc7_kernel(
    const float* __restrict__ y6, const void* __restrict__ W, const void* __restrict__ bias,
    const void* __restrict__ g, const void* __restrict__ bb, float* __restrict__ y7,
    const int* __restrict__ flagp){
  __shared__ float red[8][256];
  int o = blockIdx.x, tid = threadIdx.x;
  const int bf = *flagp;
  float part[8];
#pragma unroll
  for (int b=0;b<8;b++) part[b]=0.f;
  for (int c=tid;c<512;c+=256){
    float wv = ldin(W,o*512+c,bf);
#pragma unroll
    for (int b=0;b<8;b++) part[b] = fmaf(y6[b*512+c], wv, part[b]);
  }
#pragma unroll
  for (int b=0;b<8;b++) red[b][tid]=part[b];
  __syncthreads();
  for (int s=128;s;s>>=1){
    if (tid<s){
#pragma unroll
      for (int b=0;b<8;b++) red[b][tid]+=red[b][tid+s];
    }
    __syncthreads();
  }
  if (tid==0){
    float bs = ldin(bias,o,bf);
    float y[8], m=0.f;
#pragma unroll
    for (int b=0;b<8;b++){ y[b]=red[b][0]+bs; m+=y[b]; }
    m *= 0.125f;
    float v=0.f;
#pragma unroll
    for (int b=0;b<8;b++){ float d=y[b]-m; v += d*d; }
    v *= 0.125f;
    float a=ldin(g,o,bf)*rsqrtf(fmaxf(v,0.f)+EPSB), c0=ldin(bb,o,bf)-m*a;
#pragma unroll
    for (int b=0;b<8;b++) y7[b*256+o]=lrelu(fmaf(a,y[b],c0));
  }
}

__global__ __launch_bounds__(256) void fc8_kernel(
    const float* __restrict__ y7, const void* __restrict__ W, const void* __restrict__ bias,
    void* __restrict__ out, const int* __restrict__ flagp){
  __shared__ float red[8][256];
  int o = blockIdx.x, tid = threadIdx.x;
  const int bf = *flagp;
  float wv = ldin(W,o*256+tid,bf);
#pragma unroll
  for (int b=0;b<8;b++) red[b][tid] = y7[b*256+tid]*wv;
  __syncthreads();
  for (int s=128;s;s>>=1){
    if (tid<s){
#pragma unroll
      for (int b=0;b<8;b++) red[b][tid]+=red[b][tid+s];
    }
    __syncthreads();
  }
  if (tid==0){
    float bs = ldin(bias,o,bf);
#pragma unroll
    for (int b=0;b<8;b++){
      float r = red[b][0]+bs;
      if (bf) ((bf16*)out)[b*40+o] = __float2bfloat16(r);
      else    ((float*)out)[b*40+o] = r;
    }
  }
}

extern "C" void kernel_launch(void* const* d_in, const int* in_sizes, int n_in,
                              void* d_out, int out_size, void* d_ws, size_t ws_size,
                              hipStream_t stream){
  const void* x    = d_in[0];
  const void* w00  = d_in[1];
  const void* g00  = d_in[2];
  const void* b00  = d_in[3];
  const void* w01  = d_in[4];
  const void* g01  = d_in[5];
  const void* b01  = d_in[6];
  const void* w1   = d_in[7];  const void* g1 = d_in[8];  const void* b1 = d_in[9];
  const void* w2   = d_in[10]; const void* g2 = d_in[11]; const void* b2 = d_in[12];
  const void* w3   = d_in[13]; const void* g3 = d_in[14]; const void* b3 = d_in[15];
  const void* w4   = d_in[16]; const void* g4 = d_in[17]; const void* b4 = d_in[18];
  const void* w5   = d_in[19]; const void* g5 = d_in[20]; const void* b5 = d_in[21];
  const void* w6   = d_in[22]; const void* g6 = d_in[23]; const void* b6 = d_in[24];
  const void* w7   = d_in[25]; const void* bias7 = d_in[26];
  const void* g7   = d_in[27]; const void* b7 = d_in[28];
  const void* w8   = d_in[29]; const void* bias8 = d_in[30];

  float* ws = (float*)d_ws;
  // workspace layout (float offsets)
  size_t o_xc0  = 0;                              // B*N*16
  size_t o_xcat = o_xc0  + (size_t)BB*NN*16;      // B*N*512
  size_t o_negd = o_xcat + (size_t)BB*NN*512;     // B*N*N (u/v/hmax/hmin, then h5)
  size_t o_xx   = o_negd + (size_t)BB*NN*NN;      // B*N (unused)
  size_t o_w1d  = o_xx   + (size_t)BB*NN;         // 12*64
  size_t o_w1c  = o_w1d  + 12*64;
  size_t o_w2d  = o_w1c  + 12*64;                 // 64*64
  size_t o_w2c  = o_w2d  + 64*64;
  size_t o_w3d  = o_w2c  + 64*64;                 // 64*128
  size_t o_w3c  = o_w3d  + 64*128;
  size_t o_w4d  = o_w3c  + 64*128;                // 128*256
  size_t o_w4c  = o_w4d  + 128*256;
  size_t o_wb5  = o_w4c  + 128*256;               // 1024*512 bf16 = 262144 floats
  size_t o_st1  = o_wb5  + 262144;                // 128  (zero region starts here)
  size_t o_st2  = o_st1  + 128;                   // 128
  size_t o_st3  = o_st2  + 128;                   // 256
  size_t o_st4  = o_st3  + 256;                   // 512
  size_t o_st5  = o_st4  + 512;                   // 2048
  size_t o_pmax = o_st5  + 2048;                  // 8*1024 (uint)
  size_t o_psum = o_pmax + 8192;                  // 8*1024
  size_t o_cst  = o_psum + 8192;                  // 16 (conv0 stats; zero region ends)
  size_t o_pool = o_cst  + 16;                    // 8*2048
  size_t o_y6   = o_pool + 16384;                 // 8*512
  size_t o_y7   = o_y6   + 4096;                  // 8*256
  size_t o_idx  = o_y7   + 2048;                  // B*N*20 ints
  size_t o_flag = o_idx  + (size_t)BB*NN*KK;      // 1 int

  // overlays on the negD region (dead after topk):
  size_t o_u    = o_negd;
  size_t o_v    = o_negd + (size_t)BB*NN*256;
  size_t o_hmax = o_negd + (size_t)2*BB*NN*256;
  size_t o_hmin = o_negd + (size_t)3*BB*NN*256;
  size_t o_h5   = o_negd;                         // B*N*1024 bf16 (after eb4 apply)

  int* idxp = (int*)(ws + o_idx);
  int* flagp = (int*)(ws + o_flag);
  float* negD = ws + o_negd;
  float* xc0  = ws + o_xc0;
  float* xcat = ws + o_xcat;
  float* up   = ws + o_u;
  float* vp   = ws + o_v;
  float* hxp  = ws + o_hmax;
  float* hnp  = ws + o_hmin;
  unsigned short* wb5 = (unsigned short*)(ws + o_wb5);
  unsigned short* h5b = (unsigned short*)(ws + o_h5);

  detect_kernel<<<1,64,0,stream>>>((const unsigned*)x, flagp);

  int nz = 128+128+256+512+2048+8192+8192+16;
  zero_kernel<<<(nz+255)/256, 256, 0, stream>>>((unsigned*)(ws + o_st1), nz);

  conv0_stats_kernel<<<32,256,0,stream>>>(x, w00, w01, ws+o_cst, flagp);
  conv0_apply_kernel<<<32,256,0,stream>>>(x, w00,g00,b00, w01,g01,b01, ws+o_cst, xc0, flagp);

  // fused weight prep: 4x wuv + wb5 pack (768+4096+8192+32768+524288 = 570112 elems)
  prep_kernel<<<(570112+255)/256,256,0,stream>>>(
      w1,w2,w3,w4,w5,
      ws+o_w1d, ws+o_w1c, ws+o_w2d, ws+o_w2c,
      ws+o_w3d, ws+o_w3c, ws+o_w4d, ws+o_w4c, wb5, flagp);

  dim3 kgrid(NN/128, NN/128, BB);               // 512 blocks
  const size_t KLDS16 = (2*128*16 + 256)*4;     // CR=12 (KCH=16)
  const size_t KLDS64 = (2*128*64 + 256)*4;     // CR=64/128 (KCH=64)
  const int UVG = BB*NN/16;    // 512 blocks

  // ---- edge block 1: src=xc0 (ld16, C=9), Cout=64 -> xcat[:,0:64)
  knndist_kernel<<<kgrid,256, KLDS16, stream>>>(xc0, 16, 0, 12, negD);
  topk_kernel<<<BB*NN/4,256,0,stream>>>(negD, idxp);
  uvgemm_kernel<12,64><<<UVG,256,0,stream>>>(xc0, 16, 0, ws+o_w1d, ws+o_w1c, up, vp);
  ebgather_kernel<64><<<(BB*NN/4)*1,256,0,stream>>>(idxp, up, vp, hxp, hnp, ws+o_st1);
  ebapply_kernel<64><<<BB*NN*64/256,256,0,stream>>>(hxp, hnp, ws+o_st1, g1, b1, xcat, 0, flagp);

  // ---- edge block 2: src=x1, Cout=64 -> xcat[:,64:128)
  knndist_kernel<<<kgrid,256, KLDS64, stream>>>(xcat, 512, 0, 64, negD);
  topk_kernel<<<BB*NN/4,256,0,stream>>>(negD, idxp);
  uvgemm_kernel<64,64><<<UVG,256,0,stream>>>(xcat, 512, 0, ws+o_w2d, ws+o_w2c, up, vp);
  ebgather_kernel<64><<<(BB*NN/4)*1,256,0,stream>>>(idxp, up, vp, hxp, hnp, ws+o_st2);
  ebapply_kernel<64><<<BB*NN*64/256,256,0,stream>>>(hxp, hnp, ws+o_st2, g2, b2, xcat, 64, flagp);

  // ---- edge block 3: src=x2, Cout=128 -> xcat[:,128:256)
  knndist_kernel<<<kgrid,256, KLDS64, stream>>>(xcat, 512, 64, 64, negD);
  topk_kernel<<<BB*NN/4,256,0,stream>>>(negD, idxp);
  uvgemm_kernel<64,128><<<UVG,256,0,stream>>>(xcat, 512, 64, ws+o_w3d, ws+o_w3c, up, vp);
  ebgather_kernel<128><<<(BB*NN/4)*2,256,0,stream>>>(idxp, up, vp, hxp, hnp, ws+o_st3);
  ebapply_kernel<128><<<BB*NN*128/256,256,0,stream>>>(hxp, hnp, ws+o_st3, g3, b3, xcat, 128, flagp);

  // ---- edge block 4: src=x3, Cout=256 -> xcat[:,256:512)
  knndist_kernel<<<kgrid,256, KLDS64, stream>>>(xcat, 512, 128, 128, negD);
  topk_kernel<<<BB*NN/4,256,0,stream>>>(negD, idxp);
  uvgemm_kernel<128,256><<<UVG,256,0,stream>>>(xcat, 512, 128, ws+o_w4d, ws+o_w4c, up, vp);
  ebgather_kernel<256><<<(BB*NN/4)*4,256,0,stream>>>(idxp, up, vp, hxp, hnp, ws+o_st4);
  ebapply_kernel<256><<<BB*NN*256/256,256,0,stream>>>(hxp, hnp, ws+o_st4, g4, b4, xcat, 256, flagp);

  // ---- conv5 (512 -> 1024) MFMA single pass + BN + lrelu + pool
  fc5_mfma<<<(BB*NN/16)*4,256,0,stream>>>(xcat, wb5, ws+o_st5, h5b);
  pool5_kernel<<<BB*32,256,0,stream>>>(h5b, ws+o_st5, g5, b5,
                                       (unsigned*)(ws+o_pmax), ws+o_psum, flagp);
  pool_finalize_kernel<<<(BB*2048+255)/256,256,0,stream>>>((unsigned*)(ws+o_pmax), ws+o_psum, ws+o_pool);

  // ---- FC head
  fc6_kernel<<<512,256,0,stream>>>(ws+o_pool, w6, g6, b6, ws+o_y6, flagp);
  fc7_kernel<<<256,256,0,stream>>>(ws+o_y6, w7, bias7, g7, b7, ws+o_y7, flagp);
  fc8_kernel<<<40,256,0,stream>>>(ws+o_y7, w8, bias8, d_out, flagp);
}